// Round 2
// baseline (4691.430 us; speedup 1.0000x reference)
//
#include <hip/hip_runtime.h>

// OmniMambaBlock — full HIP implementation (round 2).
// Inputs/outputs are FLOAT32 per the reference (setup_inputs uses jnp.float32).
// Internal compute fp32 with bf16/fp16 LDS staging in hot loops.

typedef unsigned short u16;
typedef unsigned int   u32;

#define LSEQ 32768   // 32*32*32
#define CDIM 128
#define NPROJ 644
#define CCH 384
#define DIN 256
#define NHD 4
#define CKL 128      // chunk length
#define NCHK 256     // num chunks

__device__ __forceinline__ float b2f(u16 u){ u32 x=((u32)u)<<16; float f; __builtin_memcpy(&f,&x,4); return f; }
__device__ __forceinline__ u16 f2b(float f){ u32 x; __builtin_memcpy(&x,&f,4); x += 0x7fffu + ((x>>16)&1u); return (u16)(x>>16); }
__device__ __forceinline__ float lo16f(u32 u){ u32 x=u<<16; float f; __builtin_memcpy(&f,&x,4); return f; }
__device__ __forceinline__ float hi16f(u32 u){ u32 x=u&0xffff0000u; float f; __builtin_memcpy(&f,&x,4); return f; }
__device__ __forceinline__ void unpack_h2(u32 u, float& a, float& b){
  union { u32 x; _Float16 h[2]; } v; v.x=u; a=(float)v.h[0]; b=(float)v.h[1];
}
__device__ __forceinline__ float sigmoidf_(float v){ return 1.f/(1.f+__expf(-v)); }
__device__ __forceinline__ float siluf_(float v){ return v*sigmoidf_(v); }
__device__ __forceinline__ float softplusf_(float v){ return (v>20.f)? v : log1pf(__expf(v)); }

// seq index t -> spatial index s for run r (dir=r>>1: 0=s,1=n,2=z; r&1 = flipped)
__device__ __forceinline__ int seq2sp(int t, int run){
  int te = (run&1) ? (LSEQ-1-t) : t;
  int a = te>>10, b=(te>>5)&31, c=te&31;
  int d,h,w;
  switch(run>>1){
    case 0: d=a; h=b; w=c; break;
    case 1: h=a; d=b; w=c; break;
    default: w=a; d=b; h=c; break;
  }
  return (d<<10)|(h<<5)|w;
}

// ---------------- K1: xn = rmsnorm(x, norm_w), layout (c,s) -----------------
__global__ void k_xn(const float* __restrict__ x, const float* __restrict__ nw, float* __restrict__ XN){
  int s = blockIdx.x*256 + threadIdx.x;
  float ss = 0.f;
  #pragma unroll 8
  for (int c=0;c<CDIM;c++){ float v=x[c*LSEQ+s]; ss += v*v; }
  float sc = rsqrtf(ss*(1.f/CDIM)+1e-6f);
  #pragma unroll 8
  for (int c=0;c<CDIM;c++){ XN[c*LSEQ+s] = x[c*LSEQ+s]*sc*nw[c]; }
}

// ---------------- K1b: gates softmax, layout (j,s) --------------------------
__global__ void k_gates(const float* __restrict__ XN, const float* __restrict__ gw, const float* __restrict__ gb, float* __restrict__ G){
  int s = blockIdx.x*256 + threadIdx.x;
  float a[6];
  #pragma unroll
  for (int j=0;j<6;j++) a[j]=gb[j];
  for (int c=0;c<CDIM;c++){
    float v = XN[c*LSEQ+s];
    #pragma unroll
    for (int j=0;j<6;j++) a[j] += v*gw[c*6+j];
  }
  float m=a[0];
  #pragma unroll
  for (int j=1;j<6;j++) m = fmaxf(m,a[j]);
  float e[6], ssum=0.f;
  #pragma unroll
  for (int j=0;j<6;j++){ e[j]=__expf(a[j]-m); ssum+=e[j]; }
  float inv = 1.f/ssum;
  #pragma unroll
  for (int j=0;j<6;j++) G[j*LSEQ+s] = e[j]*inv;
}

// ---------------- K2: ZX[t,j] = sum_k XN[k, sp(t)] * Win[k,j] ---------------
__global__ __launch_bounds__(256) void k_gemm_in(const float* __restrict__ XN, const float* __restrict__ Win,
                                                 float* __restrict__ ZX, int run){
  __shared__ float As[128*64];   // [k][t_local]
  __shared__ u16   Bs[128*64];   // [k][j_local] bf16
  int t0 = blockIdx.y*64, j0 = blockIdx.x*64;
  int tid = threadIdx.x;
  for (int idx=tid; idx<8192; idx+=256){
    int k = idx>>6, l = idx&63;
    int sp = seq2sp(t0+l, run);
    As[k*64+l] = XN[k*LSEQ + sp];
    int j = j0+l;
    Bs[k*64+l] = (j<NPROJ) ? f2b(Win[k*NPROJ+j]) : (u16)0;
  }
  __syncthreads();
  int tx = tid&15, ty = tid>>4;
  float acc[4][4]={};
  for (int k=0;k<128;k++){
    float4 av = *(const float4*)&As[k*64 + ty*4];
    float b0=b2f(Bs[k*64+tx*4]), b1=b2f(Bs[k*64+tx*4+1]), b2v=b2f(Bs[k*64+tx*4+2]), b3=b2f(Bs[k*64+tx*4+3]);
    acc[0][0]+=av.x*b0; acc[0][1]+=av.x*b1; acc[0][2]+=av.x*b2v; acc[0][3]+=av.x*b3;
    acc[1][0]+=av.y*b0; acc[1][1]+=av.y*b1; acc[1][2]+=av.y*b2v; acc[1][3]+=av.y*b3;
    acc[2][0]+=av.z*b0; acc[2][1]+=av.z*b1; acc[2][2]+=av.z*b2v; acc[2][3]+=av.z*b3;
    acc[3][0]+=av.w*b0; acc[3][1]+=av.w*b1; acc[3][2]+=av.w*b2v; acc[3][3]+=av.w*b3;
  }
  #pragma unroll
  for (int i=0;i<4;i++){
    int t = t0 + ty*4 + i;
    #pragma unroll
    for (int l=0;l<4;l++){
      int j = j0 + tx*4 + l;
      if (j<NPROJ) ZX[t*NPROJ + j] = acc[i][l];
    }
  }
}

// ---------------- K3a: causal depthwise conv1d K=4 + silu -------------------
__global__ void k_conv(const float* __restrict__ ZX, const float* __restrict__ cw, const float* __restrict__ cb,
                       float* __restrict__ XB){
  int t = blockIdx.x; int ch = threadIdx.x;
  const float* col = ZX + 256 + ch;
  float acc = 0.f;
  #pragma unroll
  for (int k=0;k<4;k++){
    int tt = t-3+k;
    if (tt>=0) acc += cw[ch*4+k] * col[tt*NPROJ];
  }
  acc += cb[ch];
  XB[t*CCH+ch] = siluf_(acc);
}

// ---------------- K3b: dt softplus + per-chunk cumsum of dt*A ---------------
__global__ void k_dtcum(const float* __restrict__ ZX, const float* __restrict__ dtb, const float* __restrict__ Alog,
                        float* __restrict__ DT, float* __restrict__ CUM, float* __restrict__ CDEC){
  int g = blockIdx.x*256 + threadIdx.x;   // 1024 = NCHK*NHD
  int c = g>>2, h = g&3;
  float A = -__expf(Alog[h]);
  float bias = dtb[h];
  float acc = 0.f;
  for (int i=0;i<CKL;i++){
    int t = c*CKL+i;
    float dt = softplusf_(ZX[t*NPROJ + 640 + h] + bias);
    DT[t*4+h] = dt;
    acc += dt*A;
    CUM[t*4+h] = acc;
  }
  CDEC[c*4+h] = __expf(acc);
}

// ---------------- K_cb: per-chunk CB[t,s] = Cm[t]·Bm[s] (head-indep) --------
__global__ __launch_bounds__(256) void k_cb(const float* __restrict__ XB, float* __restrict__ CBg){
  __shared__ u16 Cs[128*66];
  __shared__ u16 Bsm[128*66];
  int c = blockIdx.x; int tid = threadIdx.x;
  for (int idx=tid; idx<8192; idx+=256){
    int t = idx>>6, n = idx&63;
    int row = (c*CKL+t)*CCH;
    Cs[t*66+n]  = f2b(XB[row+320+n]);
    Bsm[t*66+n] = f2b(XB[row+256+n]);
  }
  __syncthreads();
  int tx = tid&15, ty = tid>>4;
  float acc[8][8]={};
  for (int k=0;k<64;k++){
    float a[8], b[8];
    #pragma unroll
    for (int j=0;j<8;j++) a[j] = b2f(Cs[(ty*8+j)*66 + k]);
    #pragma unroll
    for (int j=0;j<8;j++) b[j] = b2f(Bsm[(tx*8+j)*66 + k]);
    #pragma unroll
    for (int jj=0;jj<8;jj++)
      #pragma unroll
      for (int mm=0;mm<8;mm++) acc[jj][mm] += a[jj]*b[mm];
  }
  #pragma unroll
  for (int jj=0;jj<8;jj++){
    int t = ty*8+jj;
    float* dst = &CBg[(c*CKL+t)*CKL + tx*8];
    #pragma unroll
    for (int mm=0;mm<8;mm++) dst[mm] = acc[jj][mm];
  }
}

// ---------------- K4: per (chunk,head): Y_intra (+D*xh) and chunk state S ---
__global__ __launch_bounds__(256) void k_chunk(const float* __restrict__ XB, const float* __restrict__ DT,
                                               const float* __restrict__ CUM, const float* __restrict__ CBg,
                                               const float* __restrict__ Dp,
                                               float* __restrict__ Y, float* __restrict__ ST){
  __shared__ u16 Mh[128*128];     // fp16 bits; region reused for Bs[s][66] in S phase
  __shared__ u16 Xsh[64*136];     // bf16 xdt, layout [p][t], stride 136
  __shared__ float cum_s[128];
  __shared__ float de_s[128];
  int bid = blockIdx.x; int c = bid>>2, h = bid&3;
  int tid = threadIdx.x, lane = tid&63, wid = tid>>6;

  for (int idx=tid; idx<8192; idx+=256){
    int t = idx>>6, q = idx&63;
    int row = (c*CKL+t)*CCH;
    float xv = XB[row + h*64 + q] * DT[(c*CKL+t)*4 + h];
    Xsh[q*136 + t] = f2b(xv);
  }
  if (tid<128) cum_s[tid] = CUM[(c*CKL+tid)*4 + h];
  __syncthreads();
  if (tid<128) de_s[tid] = __expf(cum_s[127]-cum_s[tid]);
  // build M = CB * L (fp16), zero above diagonal
  for (int idx=tid; idx<16384; idx+=256){
    int t = idx>>7, s = idx&127;
    float m = 0.f;
    if (s<=t) m = CBg[(c*CKL+t)*CKL + s] * __expf(cum_s[t]-cum_s[s]);
    _Float16 hm = (_Float16)m; u16 bits; __builtin_memcpy(&bits,&hm,2);
    Mh[t*128+s] = bits;
  }
  __syncthreads();

  float dval = Dp[h];
  const u16* Xrow = &Xsh[lane*136];
  for (int i=0;i<8;i++){
    int tb = (wid<<2) + (i<<4);   // covers all multiples of 4 in [0,128)
    float y0=0.f,y1=0.f,y2=0.f,y3=0.f;
    const u16* M0=&Mh[(tb+0)<<7]; const u16* M1=&Mh[(tb+1)<<7];
    const u16* M2=&Mh[(tb+2)<<7]; const u16* M3=&Mh[(tb+3)<<7];
    int nq = (tb+3)>>2;
    for (int s4=0; s4<=nq; s4++){
      uint2 xp = *(const uint2*)(Xrow + (s4<<2));
      float x0=lo16f(xp.x), x1=hi16f(xp.x), x2=lo16f(xp.y), x3=hi16f(xp.y);
      uint2 ma=*(const uint2*)(M0+(s4<<2)); uint2 mb=*(const uint2*)(M1+(s4<<2));
      uint2 mc=*(const uint2*)(M2+(s4<<2)); uint2 md=*(const uint2*)(M3+(s4<<2));
      float p0,p1,p2,p3;
      unpack_h2(ma.x,p0,p1); unpack_h2(ma.y,p2,p3); y0 += p0*x0+p1*x1+p2*x2+p3*x3;
      unpack_h2(mb.x,p0,p1); unpack_h2(mb.y,p2,p3); y1 += p0*x0+p1*x1+p2*x2+p3*x3;
      unpack_h2(mc.x,p0,p1); unpack_h2(mc.y,p2,p3); y2 += p0*x0+p1*x1+p2*x2+p3*x3;
      unpack_h2(md.x,p0,p1); unpack_h2(md.y,p2,p3); y3 += p0*x0+p1*x1+p2*x2+p3*x3;
    }
    #pragma unroll
    for (int k=0;k<4;k++){
      int t = tb+k;
      float yv = (k==0)?y0:((k==1)?y1:((k==2)?y2:y3));
      float xhv = XB[(c*CKL+t)*CCH + (h<<6) + lane];
      Y[((c*CKL+t)<<8) + (h<<6) + lane] = yv + dval*xhv;
    }
  }
  __syncthreads();
  // restage Bm bf16 into Mh region: Bs[s][n], stride 66
  u16* Bs = Mh;
  for (int idx=tid; idx<8192; idx+=256){
    int t = idx>>6, n = idx&63;
    Bs[t*66+n] = f2b(XB[(c*CKL+t)*CCH + 256 + n]);
  }
  __syncthreads();
  // S[p][n] = sum_s xdt[s,p]*Bm[s,n]*decay_end[s]
  {
    int n = lane, pg = wid;
    float acc[16]={};
    for (int s=0;s<128;s++){
      float bn = b2f(Bs[s*66+n]) * de_s[s];
      #pragma unroll
      for (int j=0;j<16;j++) acc[j] += b2f(Xsh[(pg*16+j)*136 + s]) * bn;
    }
    #pragma unroll
    for (int j=0;j<16;j++) ST[((c*4+h)*64 + pg*16 + j)*64 + n] = acc[j];
  }
}

// ---------------- K5: sequential chunk-state scan (in place -> hprev) -------
__global__ void k_scan(float* __restrict__ ST, const float* __restrict__ CDEC){
  int g = blockIdx.x*256 + threadIdx.x;   // 16384 = NHD*64*64
  int h = g>>12;
  float hp = 0.f;
  #pragma unroll 4
  for (int c=0;c<NCHK;c++){
    float dec = CDEC[(c<<2)+h];
    float sv = ST[g + (c<<14)];
    ST[g + (c<<14)] = hp;
    hp = dec*hp + sv;
  }
}

// ---------------- K6: Y += exp(cum[t]) * Cm[t]·hprev[p,:] -------------------
__global__ __launch_bounds__(256) void k_inter(const float* __restrict__ XB, const float* __restrict__ CUM,
                                               const float* __restrict__ ST, float* __restrict__ Y){
  __shared__ float Hs[64*68];
  int bid = blockIdx.x; int c = bid>>2, h = bid&3;
  int tid = threadIdx.x, lane = tid&63, wid = tid>>6;
  for (int idx=tid; idx<4096; idx+=256){
    int p = idx>>6, n = idx&63;
    Hs[p*68+n] = ST[((c*4+h)*64+p)*64+n];
  }
  __syncthreads();
  const float4* H4 = (const float4*)&Hs[lane*68];
  for (int i=0;i<32;i++){
    int t = wid + i*4;
    const float4* C4 = (const float4*)(XB + (c*CKL+t)*CCH + 320);
    float acc = 0.f;
    #pragma unroll
    for (int n4=0;n4<16;n4++){
      float4 cc = C4[n4]; float4 hh = H4[n4];
      acc += cc.x*hh.x + cc.y*hh.y + cc.z*hh.z + cc.w*hh.w;
    }
    float et = __expf(CUM[(c*CKL+t)*4+h]);
    Y[((c*CKL+t)<<8) + (h<<6) + lane] += et*acc;
  }
}

// ---------------- K7a: y = rmsnorm(y*silu(z)) * normw (in place) ------------
__global__ void k_ynorm(float* __restrict__ Y, const float* __restrict__ ZX, const float* __restrict__ nw){
  __shared__ float red[4];
  int t = blockIdx.x, i = threadIdx.x;
  float u = Y[t*DIN+i];
  float z = ZX[t*NPROJ+i];
  u *= siluf_(z);
  float ss = u*u;
  #pragma unroll
  for (int off=32; off; off>>=1) ss += __shfl_down(ss, off, 64);
  int lane = i&63, w = i>>6;
  if (lane==0) red[w] = ss;
  __syncthreads();
  float tot = red[0]+red[1]+red[2]+red[3];
  float sc = rsqrtf(tot*(1.f/DIN)+1e-6f);
  Y[t*DIN+i] = u*sc*nw[i];
}

// ---------------- K7b: out GEMM + gate-weighted scatter into GACC(s,c) ------
__global__ __launch_bounds__(256) void k_gemm_out(const float* __restrict__ Y, const float* __restrict__ Wout,
                                                  const float* __restrict__ G, float* __restrict__ GACC, int run){
  __shared__ float As[64*65];    // [k][t]
  __shared__ float Bsf[64*128];  // [k][c]
  int t0 = blockIdx.x*64;
  int tid = threadIdx.x, tx = tid&15, ty = tid>>4;
  float acc[4][8]={};
  for (int k0=0;k0<256;k0+=64){
    __syncthreads();
    for (int idx=tid; idx<4096; idx+=256){
      int kl = idx&63, tl = idx>>6;
      As[kl*65+tl] = Y[(t0+tl)*DIN + k0+kl];
    }
    for (int idx=tid; idx<8192; idx+=256){
      int cl = idx&127, kl = idx>>7;
      Bsf[kl*128+cl] = Wout[(k0+kl)*CDIM + cl];
    }
    __syncthreads();
    for (int k=0;k<64;k++){
      float a[4];
      #pragma unroll
      for (int j=0;j<4;j++) a[j] = As[k*65 + ty*4 + j];
      float4 bb0 = *(const float4*)&Bsf[k*128 + tx*8];
      float4 bb1 = *(const float4*)&Bsf[k*128 + tx*8 + 4];
      #pragma unroll
      for (int j=0;j<4;j++){
        acc[j][0]+=a[j]*bb0.x; acc[j][1]+=a[j]*bb0.y; acc[j][2]+=a[j]*bb0.z; acc[j][3]+=a[j]*bb0.w;
        acc[j][4]+=a[j]*bb1.x; acc[j][5]+=a[j]*bb1.y; acc[j][6]+=a[j]*bb1.z; acc[j][7]+=a[j]*bb1.w;
      }
    }
  }
  #pragma unroll
  for (int j=0;j<4;j++){
    int t = t0 + ty*4 + j;
    int sp = seq2sp(t, run);
    float g = G[run*LSEQ + sp];
    float4* dst = (float4*)&GACC[sp*CDIM + tx*8];
    float4 c0 = dst[0], c1 = dst[1];
    c0.x += g*acc[j][0]; c0.y += g*acc[j][1]; c0.z += g*acc[j][2]; c0.w += g*acc[j][3];
    c1.x += g*acc[j][4]; c1.y += g*acc[j][5]; c1.z += g*acc[j][6]; c1.w += g*acc[j][7];
    dst[0]=c0; dst[1]=c1;
  }
}

// ---------------- K8: depthwise 3x3x3 conv (zero pad), layout (c,s) ---------
__global__ void k_dwconv(const float* __restrict__ XN, const float* __restrict__ w, const float* __restrict__ b,
                         float* __restrict__ LC1){
  int idx = blockIdx.x*256 + threadIdx.x;
  int cc = idx>>15, s = idx&32767;
  int d = s>>10, hh=(s>>5)&31, ww=s&31;
  float acc = 0.f;
  for (int dz=-1;dz<=1;dz++){
    int nd = d+dz; if ((unsigned)nd>31u) continue;
    for (int dy=-1;dy<=1;dy++){
      int nh = hh+dy; if ((unsigned)nh>31u) continue;
      for (int dx=-1;dx<=1;dx++){
        int nw = ww+dx; if ((unsigned)nw>31u) continue;
        acc += w[cc*27 + (dz+1)*9 + (dy+1)*3 + (dx+1)] * XN[cc*LSEQ + (nd<<10)+(nh<<5)+nw];
      }
    }
  }
  LC1[idx] = acc + b[cc];
}

// ---------------- K9: pointwise 128x128 + silu, (c,s) in -> (c,s) out -------
__global__ __launch_bounds__(256) void k_pw(const float* __restrict__ LC1, const float* __restrict__ pw,
                                            const float* __restrict__ pwb, float* __restrict__ LC2){
  __shared__ float sm[8320];   // stage 128x64, then out 64x130
  int s0 = blockIdx.x*64;
  int tid = threadIdx.x, sl = tid&63, og = tid>>6;
  for (int idx=tid; idx<8192; idx+=256){
    int cl = idx>>6, ssl = idx&63;
    sm[cl*64+ssl] = LC1[cl*LSEQ + s0 + ssl];
  }
  __syncthreads();
  float acc[32]={};
  for (int c=0;c<128;c++){
    float xv = sm[c*64+sl];
    #pragma unroll
    for (int j=0;j<32;j++) acc[j] += pw[(og*32+j)*128 + c] * xv;
  }
  __syncthreads();
  #pragma unroll
  for (int j=0;j<32;j++){
    int o = og*32+j;
    float v = acc[j] + pwb[o];
    sm[sl*130 + o] = siluf_(v);
  }
  __syncthreads();
  for (int idx=tid; idx<8192; idx+=256){
    int o = idx>>6, ssl = idx&63;
    LC2[o*LSEQ + s0 + ssl] = sm[ssl*130 + o];
  }
}

// ---------------- K10: fused = a*g + (1-a)*lc, transpose (s,c)->(c,s) -------
__global__ void k_fuse(const float* __restrict__ GACC, const float* __restrict__ LC2,
                       const float* __restrict__ alpha, float* __restrict__ FUSED){
  __shared__ float tile[64*65];
  int bs = blockIdx.x>>1, bc = blockIdx.x&1;
  int s0 = bs*64, c0 = bc*64;
  int tid = threadIdx.x;
  float a = alpha[0];
  for (int idx=tid; idx<4096; idx+=256){
    int i = idx>>6, j = idx&63;
    tile[i*65+j] = GACC[(s0+i)*CDIM + c0+j];
  }
  __syncthreads();
  for (int idx=tid; idx<4096; idx+=256){
    int j = idx>>6, i = idx&63;
    float g = tile[i*65+j];
    float l = LC2[(c0+j)*LSEQ + s0+i];
    FUSED[(c0+j)*LSEQ + s0+i] = a*g + (1.f-a)*l;
  }
}

// ---------------- K_mean: per-channel spatial mean of FUSED -----------------
__global__ void k_mean(const float* __restrict__ F, float* __restrict__ MEAN){
  __shared__ float red[4];
  int cc = blockIdx.x, tid = threadIdx.x;
  float acc = 0.f;
  for (int s=tid; s<LSEQ; s+=256) acc += F[cc*LSEQ + s];
  #pragma unroll
  for (int off=32; off; off>>=1) acc += __shfl_down(acc, off, 64);
  if ((tid&63)==0) red[tid>>6] = acc;
  __syncthreads();
  if (tid==0) MEAN[cc] = (red[0]+red[1]+red[2]+red[3])*(1.f/LSEQ);
}

// ---------------- K11: channel attention -> per-channel sigmoid -------------
__global__ void k_ca(const float* __restrict__ MEAN, const float* __restrict__ w1, const float* __restrict__ b1,
                     const float* __restrict__ w2, const float* __restrict__ b2, float* __restrict__ SIG){
  __shared__ float y1[8];
  int tid = threadIdx.x;
  if (tid<8){
    float acc = b1[tid];
    for (int c=0;c<128;c++) acc += w1[tid*128+c]*MEAN[c];
    y1[tid] = (acc>=0.f)? acc : 0.1f*acc;
  }
  __syncthreads();
  float acc = b2[tid];
  #pragma unroll
  for (int o=0;o<8;o++) acc += w2[tid*8+o]*y1[o];
  SIG[tid] = sigmoidf_(acc);
}

// ---------------- K12: out = x + fused * sigmoid(yc) ------------------------
__global__ void k_final(const float* __restrict__ x, const float* __restrict__ F, const float* __restrict__ SIG,
                        float* __restrict__ out){
  int idx = blockIdx.x*256 + threadIdx.x;
  int cc = idx>>15;
  out[idx] = x[idx] + F[idx]*SIG[cc];
}

extern "C" void kernel_launch(void* const* d_in, const int* in_sizes, int n_in,
                              void* d_out, int out_size, void* d_ws, size_t ws_size,
                              hipStream_t stream){
  (void)in_sizes; (void)n_in; (void)out_size; (void)ws_size;
  const float* x       = (const float*)d_in[0];
  const float* norm_w  = (const float*)d_in[1];
  const float* gate_w  = (const float*)d_in[2];
  const float* gate_b  = (const float*)d_in[3];
  const float* loc_dw_w= (const float*)d_in[28];
  const float* loc_dw_b= (const float*)d_in[29];
  const float* loc_pw_w= (const float*)d_in[30];
  const float* loc_pw_b= (const float*)d_in[31];
  const float* ca_w1   = (const float*)d_in[32];
  const float* ca_b1   = (const float*)d_in[33];
  const float* ca_w2   = (const float*)d_in[34];
  const float* ca_b2   = (const float*)d_in[35];
  const float* alpha   = (const float*)d_in[36];

  // workspace arena (floats); total ~254 MB
  float* W     = (float*)d_ws;
  float* XN    = W;                    // 4,194,304  (c,s)
  float* GATES = XN    + 4194304;      //   196,608  (j,s)
  float* GACC  = GATES + 196608;       // 4,194,304  (s,c)
  float* ZX    = GACC  + 4194304;      //21,102,592  (t,644)
  float* XB    = ZX    + 21102592;     //12,582,912  (t,384)
  float* DT    = XB    + 12582912;     //   131,072
  float* CUM   = DT    + 131072;       //   131,072
  float* CDEC  = CUM   + 131072;       //     1,024
  float* ST    = CDEC  + 1024;         // 4,194,304
  float* Y     = ST    + 4194304;      // 8,388,608  (t,256)
  float* LC1   = Y     + 8388608;      // 4,194,304  (c,s)   (aliased as CB during runs)
  float* LC2   = LC1   + 4194304;      // 4,194,304  (c,s)
  float* MEAN  = LC2   + 4194304;      //       128
  float* SIG   = MEAN  + 128;          //       128
  float* CB    = LC1;                  // alias: per-chunk CB scratch (dead before LC1 used)

  hipMemsetAsync(GACC, 0, 4194304*sizeof(float), stream);
  k_xn   <<<128,256,0,stream>>>(x, norm_w, XN);
  k_gates<<<128,256,0,stream>>>(XN, gate_w, gate_b, GATES);

  for (int r=0;r<6;r++){
    int m = r>>1;
    const float* Win   = (const float*)d_in[4 + m*8 + 0];
    const float* convw = (const float*)d_in[4 + m*8 + 1];
    const float* convb = (const float*)d_in[4 + m*8 + 2];
    const float* dtb   = (const float*)d_in[4 + m*8 + 3];
    const float* Alog  = (const float*)d_in[4 + m*8 + 4];
    const float* Dp    = (const float*)d_in[4 + m*8 + 5];
    const float* nw2   = (const float*)d_in[4 + m*8 + 6];
    const float* Wout  = (const float*)d_in[4 + m*8 + 7];
    k_gemm_in <<<dim3(11,512),256,0,stream>>>(XN, Win, ZX, r);
    k_conv    <<<32768,384,0,stream>>>(ZX, convw, convb, XB);
    k_dtcum   <<<4,256,0,stream>>>(ZX, dtb, Alog, DT, CUM, CDEC);
    k_cb      <<<256,256,0,stream>>>(XB, CB);
    k_chunk   <<<1024,256,0,stream>>>(XB, DT, CUM, CB, Dp, Y, ST);
    k_scan    <<<64,256,0,stream>>>(ST, CDEC);
    k_inter   <<<1024,256,0,stream>>>(XB, CUM, ST, Y);
    k_ynorm   <<<32768,256,0,stream>>>(Y, ZX, nw2);
    k_gemm_out<<<512,256,0,stream>>>(Y, Wout, GATES, GACC, r);
  }

  k_dwconv<<<16384,256,0,stream>>>(XN, loc_dw_w, loc_dw_b, LC1);
  k_pw    <<<512,256,0,stream>>>(LC1, loc_pw_w, loc_pw_b, LC2);
  k_fuse  <<<1024,256,0,stream>>>(GACC, LC2, alpha, LC1);   // FUSED -> LC1
  k_mean  <<<128,256,0,stream>>>(LC1, MEAN);
  k_ca    <<<1,128,0,stream>>>(MEAN, ca_w1, ca_b1, ca_w2, ca_b2, SIG);
  k_final <<<16384,256,0,stream>>>(x, LC1, SIG, (float*)d_out);
}

// Round 3
// 3268.781 us; speedup vs baseline: 1.4352x; 1.4352x over previous
//
#include <hip/hip_runtime.h>

// OmniMambaBlock — round 3: MFMA input-projection GEMM.
// Inputs/outputs FLOAT32 per reference. Internal: bf16 MFMA for the big
// input GEMM, fp32 vector elsewhere (to be converted in later rounds).

typedef unsigned short u16;
typedef unsigned int   u32;
typedef __attribute__((ext_vector_type(8))) short short8;   // bf16x8 frag (4 VGPRs)
typedef __attribute__((ext_vector_type(4))) float f32x4;    // C/D frag

#define LSEQ 32768   // 32*32*32
#define CDIM 128
#define NPROJ 644
#define CCH 384
#define DIN 256
#define NHD 4
#define CKL 128      // chunk length
#define NCHK 256     // num chunks

__device__ __forceinline__ float b2f(u16 u){ u32 x=((u32)u)<<16; float f; __builtin_memcpy(&f,&x,4); return f; }
__device__ __forceinline__ u16 f2b(float f){ u32 x; __builtin_memcpy(&x,&f,4); x += 0x7fffu + ((x>>16)&1u); return (u16)(x>>16); }
__device__ __forceinline__ float lo16f(u32 u){ u32 x=u<<16; float f; __builtin_memcpy(&f,&x,4); return f; }
__device__ __forceinline__ float hi16f(u32 u){ u32 x=u&0xffff0000u; float f; __builtin_memcpy(&f,&x,4); return f; }
__device__ __forceinline__ void unpack_h2(u32 u, float& a, float& b){
  union { u32 x; _Float16 h[2]; } v; v.x=u; a=(float)v.h[0]; b=(float)v.h[1];
}
__device__ __forceinline__ float sigmoidf_(float v){ return 1.f/(1.f+__expf(-v)); }
__device__ __forceinline__ float siluf_(float v){ return v*sigmoidf_(v); }
__device__ __forceinline__ float softplusf_(float v){ return (v>20.f)? v : log1pf(__expf(v)); }

// seq index t -> spatial index s for run r (dir=r>>1: 0=s,1=n,2=z; r&1 = flipped)
__device__ __forceinline__ int seq2sp(int t, int run){
  int te = (run&1) ? (LSEQ-1-t) : t;
  int a = te>>10, b=(te>>5)&31, c=te&31;
  int d,h,w;
  switch(run>>1){
    case 0: d=a; h=b; w=c; break;
    case 1: h=a; d=b; w=c; break;
    default: w=a; d=b; h=c; break;
  }
  return (d<<10)|(h<<5)|w;
}

// ---------------- K1: xn = rmsnorm(x, norm_w), layout (c,s) -----------------
__global__ void k_xn(const float* __restrict__ x, const float* __restrict__ nw, float* __restrict__ XN){
  int s = blockIdx.x*256 + threadIdx.x;
  float ss = 0.f;
  #pragma unroll 8
  for (int c=0;c<CDIM;c++){ float v=x[c*LSEQ+s]; ss += v*v; }
  float sc = rsqrtf(ss*(1.f/CDIM)+1e-6f);
  #pragma unroll 8
  for (int c=0;c<CDIM;c++){ XN[c*LSEQ+s] = x[c*LSEQ+s]*sc*nw[c]; }
}

// ---------------- K1b: gates softmax, layout (j,s) --------------------------
__global__ void k_gates(const float* __restrict__ XN, const float* __restrict__ gw, const float* __restrict__ gb, float* __restrict__ G){
  int s = blockIdx.x*256 + threadIdx.x;
  float a[6];
  #pragma unroll
  for (int j=0;j<6;j++) a[j]=gb[j];
  for (int c=0;c<CDIM;c++){
    float v = XN[c*LSEQ+s];
    #pragma unroll
    for (int j=0;j<6;j++) a[j] += v*gw[c*6+j];
  }
  float m=a[0];
  #pragma unroll
  for (int j=1;j<6;j++) m = fmaxf(m,a[j]);
  float e[6], ssum=0.f;
  #pragma unroll
  for (int j=0;j<6;j++){ e[j]=__expf(a[j]-m); ssum+=e[j]; }
  float inv = 1.f/ssum;
  #pragma unroll
  for (int j=0;j<6;j++) G[j*LSEQ+s] = e[j]*inv;
}

// ---------------- K_perm: XNT[t][c] bf16, sequence-ordered for direction ----
// blocks: (a,b) in 32x32; inner i in [0,32) contiguous in sp.
__global__ __launch_bounds__(256) void k_permute(const float* __restrict__ XN, u16* __restrict__ XNT, int dir){
  __shared__ u16 TS[128*34];
  int a = blockIdx.x>>5, b = blockIdx.x&31;
  int tid = threadIdx.x;
  int spa = (dir==1)? b : a;
  int spb = (dir==1)? a : b;
  int spbase = spa*1024 + spb*32;
  for (int idx=tid; idx<4096; idx+=256){
    int c = idx>>5, i = idx&31;
    TS[c*34+i] = f2b(XN[c*LSEQ + spbase + i]);
  }
  __syncthreads();
  for (int idx=tid; idx<4096; idx+=256){
    int i = idx>>7, c = idx&127;
    int t = (dir==2) ? (i*1024 + a*32 + b) : (a*1024 + b*32 + i);
    XNT[t*128 + c] = TS[c*34+i];
  }
  // second half of i (16..31): loop covers idx<4096 => i in [0,32) since 4096 = 32*128
}

// ---------------- K_prepw: WinT[j][k] bf16, j padded to 768 -----------------
__global__ void k_prepw(const float* __restrict__ Win, u16* __restrict__ WinT){
  int idx = blockIdx.x*256 + threadIdx.x;   // 768*128 = 98304
  int j = idx>>7, k = idx&127;
  float v = (j<NPROJ)? Win[k*NPROJ + j] : 0.f;
  WinT[idx] = f2b(v);
}

// ---------------- K2: ZX[t,j] = sum_k XNT[t,k] * WinT[j,k]  (bf16 MFMA) -----
__global__ __launch_bounds__(256) void k_gin_mfma(const u16* __restrict__ XNT, const u16* __restrict__ WinT,
                                                  float* __restrict__ ZX, int flip){
  __shared__ u16 Asb[128*136];
  __shared__ u16 Bsb[128*136];
  int j0 = blockIdx.x*128, t0 = blockIdx.y*128;
  int tid = threadIdx.x;
  for (int ch = tid; ch < 2048; ch += 256){
    int row = ch>>4, c8 = ch&15;
    int tg = flip ? (LSEQ-1-(t0+row)) : (t0+row);
    uint4 av = *(const uint4*)(XNT + tg*128 + c8*8);
    *(uint4*)(&Asb[row*136 + c8*8]) = av;
    uint4 bv = *(const uint4*)(WinT + (j0+row)*128 + c8*8);
    *(uint4*)(&Bsb[row*136 + c8*8]) = bv;
  }
  __syncthreads();
  int lane = tid&63, wid = tid>>6;
  int wm = (wid>>1)*64, wn = (wid&1)*64;
  int lm = lane&15, lq = lane>>4;
  f32x4 acc[4][4] = {};
  for (int kt=0; kt<4; kt++){
    short8 af[4], bf[4];
    #pragma unroll
    for (int mt=0;mt<4;mt++) af[mt] = *(const short8*)(&Asb[(wm+mt*16+lm)*136 + kt*32 + lq*8]);
    #pragma unroll
    for (int nt=0;nt<4;nt++) bf[nt] = *(const short8*)(&Bsb[(wn+nt*16+lm)*136 + kt*32 + lq*8]);
    #pragma unroll
    for (int mt=0;mt<4;mt++)
      #pragma unroll
      for (int nt=0;nt<4;nt++)
        acc[mt][nt] = __builtin_amdgcn_mfma_f32_16x16x32_bf16(af[mt], bf[nt], acc[mt][nt], 0,0,0);
  }
  #pragma unroll
  for (int mt=0;mt<4;mt++){
    #pragma unroll
    for (int nt=0;nt<4;nt++){
      int j = j0 + wn + nt*16 + lm;
      if (j < NPROJ){
        #pragma unroll
        for (int r=0;r<4;r++){
          int t = t0 + wm + mt*16 + lq*4 + r;
          ZX[t*NPROJ + j] = acc[mt][nt][r];
        }
      }
    }
  }
}

// ---------------- K3a: causal depthwise conv1d K=4 + silu -------------------
__global__ void k_conv(const float* __restrict__ ZX, const float* __restrict__ cw, const float* __restrict__ cb,
                       float* __restrict__ XB){
  int t = blockIdx.x; int ch = threadIdx.x;
  const float* col = ZX + 256 + ch;
  float acc = 0.f;
  #pragma unroll
  for (int k=0;k<4;k++){
    int tt = t-3+k;
    if (tt>=0) acc += cw[ch*4+k] * col[tt*NPROJ];
  }
  acc += cb[ch];
  XB[t*CCH+ch] = siluf_(acc);
}

// ---------------- K3b: dt softplus + per-chunk cumsum of dt*A ---------------
__global__ void k_dtcum(const float* __restrict__ ZX, const float* __restrict__ dtb, const float* __restrict__ Alog,
                        float* __restrict__ DT, float* __restrict__ CUM, float* __restrict__ CDEC){
  int g = blockIdx.x*256 + threadIdx.x;   // 1024 = NCHK*NHD
  int c = g>>2, h = g&3;
  float A = -__expf(Alog[h]);
  float bias = dtb[h];
  float acc = 0.f;
  for (int i=0;i<CKL;i++){
    int t = c*CKL+i;
    float dt = softplusf_(ZX[t*NPROJ + 640 + h] + bias);
    DT[t*4+h] = dt;
    acc += dt*A;
    CUM[t*4+h] = acc;
  }
  CDEC[c*4+h] = __expf(acc);
}

// ---------------- K_cb: per-chunk CB[t,s] = Cm[t]·Bm[s] (head-indep) --------
__global__ __launch_bounds__(256) void k_cb(const float* __restrict__ XB, float* __restrict__ CBg){
  __shared__ u16 Cs[128*66];
  __shared__ u16 Bsm[128*66];
  int c = blockIdx.x; int tid = threadIdx.x;
  for (int idx=tid; idx<8192; idx+=256){
    int t = idx>>6, n = idx&63;
    int row = (c*CKL+t)*CCH;
    Cs[t*66+n]  = f2b(XB[row+320+n]);
    Bsm[t*66+n] = f2b(XB[row+256+n]);
  }
  __syncthreads();
  int tx = tid&15, ty = tid>>4;
  float acc[8][8]={};
  for (int k=0;k<64;k++){
    float a[8], b[8];
    #pragma unroll
    for (int j=0;j<8;j++) a[j] = b2f(Cs[(ty*8+j)*66 + k]);
    #pragma unroll
    for (int j=0;j<8;j++) b[j] = b2f(Bsm[(tx*8+j)*66 + k]);
    #pragma unroll
    for (int jj=0;jj<8;jj++)
      #pragma unroll
      for (int mm=0;mm<8;mm++) acc[jj][mm] += a[jj]*b[mm];
  }
  #pragma unroll
  for (int jj=0;jj<8;jj++){
    int t = ty*8+jj;
    float* dst = &CBg[(c*CKL+t)*CKL + tx*8];
    #pragma unroll
    for (int mm=0;mm<8;mm++) dst[mm] = acc[jj][mm];
  }
}

// ---------------- K4: per (chunk,head): Y_intra (+D*xh) and chunk state S ---
__global__ __launch_bounds__(256) void k_chunk(const float* __restrict__ XB, const float* __restrict__ DT,
                                               const float* __restrict__ CUM, const float* __restrict__ CBg,
                                               const float* __restrict__ Dp,
                                               float* __restrict__ Y, float* __restrict__ ST){
  __shared__ u16 Mh[128*128];     // fp16 bits; region reused for Bs[s][66] in S phase
  __shared__ u16 Xsh[64*136];     // bf16 xdt, layout [p][t], stride 136
  __shared__ float cum_s[128];
  __shared__ float de_s[128];
  int bid = blockIdx.x; int c = bid>>2, h = bid&3;
  int tid = threadIdx.x, lane = tid&63, wid = tid>>6;

  for (int idx=tid; idx<8192; idx+=256){
    int t = idx>>6, q = idx&63;
    int row = (c*CKL+t)*CCH;
    float xv = XB[row + h*64 + q] * DT[(c*CKL+t)*4 + h];
    Xsh[q*136 + t] = f2b(xv);
  }
  if (tid<128) cum_s[tid] = CUM[(c*CKL+tid)*4 + h];
  __syncthreads();
  if (tid<128) de_s[tid] = __expf(cum_s[127]-cum_s[tid]);
  // build M = CB * L (fp16), zero above diagonal
  for (int idx=tid; idx<16384; idx+=256){
    int t = idx>>7, s = idx&127;
    float m = 0.f;
    if (s<=t) m = CBg[(c*CKL+t)*CKL + s] * __expf(cum_s[t]-cum_s[s]);
    _Float16 hm = (_Float16)m; u16 bits; __builtin_memcpy(&bits,&hm,2);
    Mh[t*128+s] = bits;
  }
  __syncthreads();

  float dval = Dp[h];
  const u16* Xrow = &Xsh[lane*136];
  for (int i=0;i<8;i++){
    int tb = (wid<<2) + (i<<4);   // covers all multiples of 4 in [0,128)
    float y0=0.f,y1=0.f,y2=0.f,y3=0.f;
    const u16* M0=&Mh[(tb+0)<<7]; const u16* M1=&Mh[(tb+1)<<7];
    const u16* M2=&Mh[(tb+2)<<7]; const u16* M3=&Mh[(tb+3)<<7];
    int nq = (tb+3)>>2;
    for (int s4=0; s4<=nq; s4++){
      uint2 xp = *(const uint2*)(Xrow + (s4<<2));
      float x0=lo16f(xp.x), x1=hi16f(xp.x), x2=lo16f(xp.y), x3=hi16f(xp.y);
      uint2 ma=*(const uint2*)(M0+(s4<<2)); uint2 mb=*(const uint2*)(M1+(s4<<2));
      uint2 mc=*(const uint2*)(M2+(s4<<2)); uint2 md=*(const uint2*)(M3+(s4<<2));
      float p0,p1,p2,p3;
      unpack_h2(ma.x,p0,p1); unpack_h2(ma.y,p2,p3); y0 += p0*x0+p1*x1+p2*x2+p3*x3;
      unpack_h2(mb.x,p0,p1); unpack_h2(mb.y,p2,p3); y1 += p0*x0+p1*x1+p2*x2+p3*x3;
      unpack_h2(mc.x,p0,p1); unpack_h2(mc.y,p2,p3); y2 += p0*x0+p1*x1+p2*x2+p3*x3;
      unpack_h2(md.x,p0,p1); unpack_h2(md.y,p2,p3); y3 += p0*x0+p1*x1+p2*x2+p3*x3;
    }
    #pragma unroll
    for (int k=0;k<4;k++){
      int t = tb+k;
      float yv = (k==0)?y0:((k==1)?y1:((k==2)?y2:y3));
      float xhv = XB[(c*CKL+t)*CCH + (h<<6) + lane];
      Y[((c*CKL+t)<<8) + (h<<6) + lane] = yv + dval*xhv;
    }
  }
  __syncthreads();
  // restage Bm bf16 into Mh region: Bs[s][n], stride 66
  u16* Bs = Mh;
  for (int idx=tid; idx<8192; idx+=256){
    int t = idx>>6, n = idx&63;
    Bs[t*66+n] = f2b(XB[(c*CKL+t)*CCH + 256 + n]);
  }
  __syncthreads();
  // S[p][n] = sum_s xdt[s,p]*Bm[s,n]*decay_end[s]
  {
    int n = lane, pg = wid;
    float acc[16]={};
    for (int s=0;s<128;s++){
      float bn = b2f(Bs[s*66+n]) * de_s[s];
      #pragma unroll
      for (int j=0;j<16;j++) acc[j] += b2f(Xsh[(pg*16+j)*136 + s]) * bn;
    }
    #pragma unroll
    for (int j=0;j<16;j++) ST[((c*4+h)*64 + pg*16 + j)*64 + n] = acc[j];
  }
}

// ---------------- K5: sequential chunk-state scan (in place -> hprev) -------
__global__ void k_scan(float* __restrict__ ST, const float* __restrict__ CDEC){
  int g = blockIdx.x*256 + threadIdx.x;   // 16384 = NHD*64*64
  int h = g>>12;
  float hp = 0.f;
  #pragma unroll 4
  for (int c=0;c<NCHK;c++){
    float dec = CDEC[(c<<2)+h];
    float sv = ST[g + (c<<14)];
    ST[g + (c<<14)] = hp;
    hp = dec*hp + sv;
  }
}

// ---------------- K6: Y += exp(cum[t]) * Cm[t]·hprev[p,:] -------------------
__global__ __launch_bounds__(256) void k_inter(const float* __restrict__ XB, const float* __restrict__ CUM,
                                               const float* __restrict__ ST, float* __restrict__ Y){
  __shared__ float Hs[64*68];
  int bid = blockIdx.x; int c = bid>>2, h = bid&3;
  int tid = threadIdx.x, lane = tid&63, wid = tid>>6;
  for (int idx=tid; idx<4096; idx+=256){
    int p = idx>>6, n = idx&63;
    Hs[p*68+n] = ST[((c*4+h)*64+p)*64+n];
  }
  __syncthreads();
  const float4* H4 = (const float4*)&Hs[lane*68];
  for (int i=0;i<32;i++){
    int t = wid + i*4;
    const float4* C4 = (const float4*)(XB + (c*CKL+t)*CCH + 320);
    float acc = 0.f;
    #pragma unroll
    for (int n4=0;n4<16;n4++){
      float4 cc = C4[n4]; float4 hh = H4[n4];
      acc += cc.x*hh.x + cc.y*hh.y + cc.z*hh.z + cc.w*hh.w;
    }
    float et = __expf(CUM[(c*CKL+t)*4+h]);
    Y[((c*CKL+t)<<8) + (h<<6) + lane] += et*acc;
  }
}

// ---------------- K7a: y = rmsnorm(y*silu(z)) * normw (in place) ------------
__global__ void k_ynorm(float* __restrict__ Y, const float* __restrict__ ZX, const float* __restrict__ nw){
  __shared__ float red[4];
  int t = blockIdx.x, i = threadIdx.x;
  float u = Y[t*DIN+i];
  float z = ZX[t*NPROJ+i];
  u *= siluf_(z);
  float ss = u*u;
  #pragma unroll
  for (int off=32; off; off>>=1) ss += __shfl_down(ss, off, 64);
  int lane = i&63, w = i>>6;
  if (lane==0) red[w] = ss;
  __syncthreads();
  float tot = red[0]+red[1]+red[2]+red[3];
  float sc = rsqrtf(tot*(1.f/DIN)+1e-6f);
  Y[t*DIN+i] = u*sc*nw[i];
}

// ---------------- K7b: out GEMM + gate-weighted scatter into GACC(s,c) ------
__global__ __launch_bounds__(256) void k_gemm_out(const float* __restrict__ Y, const float* __restrict__ Wout,
                                                  const float* __restrict__ G, float* __restrict__ GACC, int run){
  __shared__ float As[64*65];    // [k][t]
  __shared__ float Bsf[64*128];  // [k][c]
  int t0 = blockIdx.x*64;
  int tid = threadIdx.x, tx = tid&15, ty = tid>>4;
  float acc[4][8]={};
  for (int k0=0;k0<256;k0+=64){
    __syncthreads();
    for (int idx=tid; idx<4096; idx+=256){
      int kl = idx&63, tl = idx>>6;
      As[kl*65+tl] = Y[(t0+tl)*DIN + k0+kl];
    }
    for (int idx=tid; idx<8192; idx+=256){
      int cl = idx&127, kl = idx>>7;
      Bsf[kl*128+cl] = Wout[(k0+kl)*CDIM + cl];
    }
    __syncthreads();
    for (int k=0;k<64;k++){
      float a[4];
      #pragma unroll
      for (int j=0;j<4;j++) a[j] = As[k*65 + ty*4 + j];
      float4 bb0 = *(const float4*)&Bsf[k*128 + tx*8];
      float4 bb1 = *(const float4*)&Bsf[k*128 + tx*8 + 4];
      #pragma unroll
      for (int j=0;j<4;j++){
        acc[j][0]+=a[j]*bb0.x; acc[j][1]+=a[j]*bb0.y; acc[j][2]+=a[j]*bb0.z; acc[j][3]+=a[j]*bb0.w;
        acc[j][4]+=a[j]*bb1.x; acc[j][5]+=a[j]*bb1.y; acc[j][6]+=a[j]*bb1.z; acc[j][7]+=a[j]*bb1.w;
      }
    }
  }
  #pragma unroll
  for (int j=0;j<4;j++){
    int t = t0 + ty*4 + j;
    int sp = seq2sp(t, run);
    float g = G[run*LSEQ + sp];
    float4* dst = (float4*)&GACC[sp*CDIM + tx*8];
    float4 c0 = dst[0], c1 = dst[1];
    c0.x += g*acc[j][0]; c0.y += g*acc[j][1]; c0.z += g*acc[j][2]; c0.w += g*acc[j][3];
    c1.x += g*acc[j][4]; c1.y += g*acc[j][5]; c1.z += g*acc[j][6]; c1.w += g*acc[j][7];
    dst[0]=c0; dst[1]=c1;
  }
}

// ---------------- K8: depthwise 3x3x3 conv (zero pad), layout (c,s) ---------
__global__ void k_dwconv(const float* __restrict__ XN, const float* __restrict__ w, const float* __restrict__ b,
                         float* __restrict__ LC1){
  int idx = blockIdx.x*256 + threadIdx.x;
  int cc = idx>>15, s = idx&32767;
  int d = s>>10, hh=(s>>5)&31, ww=s&31;
  float acc = 0.f;
  for (int dz=-1;dz<=1;dz++){
    int nd = d+dz; if ((unsigned)nd>31u) continue;
    for (int dy=-1;dy<=1;dy++){
      int nh = hh+dy; if ((unsigned)nh>31u) continue;
      for (int dx=-1;dx<=1;dx++){
        int nw = ww+dx; if ((unsigned)nw>31u) continue;
        acc += w[cc*27 + (dz+1)*9 + (dy+1)*3 + (dx+1)] * XN[cc*LSEQ + (nd<<10)+(nh<<5)+nw];
      }
    }
  }
  LC1[idx] = acc + b[cc];
}

// ---------------- K9: pointwise 128x128 + silu, (c,s) in -> (c,s) out -------
__global__ __launch_bounds__(256) void k_pw(const float* __restrict__ LC1, const float* __restrict__ pw,
                                            const float* __restrict__ pwb, float* __restrict__ LC2){
  __shared__ float sm[8320];   // stage 128x64, then out 64x130
  int s0 = blockIdx.x*64;
  int tid = threadIdx.x, sl = tid&63, og = tid>>6;
  for (int idx=tid; idx<8192; idx+=256){
    int cl = idx>>6, ssl = idx&63;
    sm[cl*64+ssl] = LC1[cl*LSEQ + s0 + ssl];
  }
  __syncthreads();
  float acc[32]={};
  for (int c=0;c<128;c++){
    float xv = sm[c*64+sl];
    #pragma unroll
    for (int j=0;j<32;j++) acc[j] += pw[(og*32+j)*128 + c] * xv;
  }
  __syncthreads();
  #pragma unroll
  for (int j=0;j<32;j++){
    int o = og*32+j;
    float v = acc[j] + pwb[o];
    sm[sl*130 + o] = siluf_(v);
  }
  __syncthreads();
  for (int idx=tid; idx<8192; idx+=256){
    int o = idx>>6, ssl = idx&63;
    LC2[o*LSEQ + s0 + ssl] = sm[ssl*130 + o];
  }
}

// ---------------- K10: fused = a*g + (1-a)*lc, transpose (s,c)->(c,s) -------
__global__ void k_fuse(const float* __restrict__ GACC, const float* __restrict__ LC2,
                       const float* __restrict__ alpha, float* __restrict__ FUSED){
  __shared__ float tile[64*65];
  int bs = blockIdx.x>>1, bc = blockIdx.x&1;
  int s0 = bs*64, c0 = bc*64;
  int tid = threadIdx.x;
  float a = alpha[0];
  for (int idx=tid; idx<4096; idx+=256){
    int i = idx>>6, j = idx&63;
    tile[i*65+j] = GACC[(s0+i)*CDIM + c0+j];
  }
  __syncthreads();
  for (int idx=tid; idx<4096; idx+=256){
    int j = idx>>6, i = idx&63;
    float g = tile[i*65+j];
    float l = LC2[(c0+j)*LSEQ + s0+i];
    FUSED[(c0+j)*LSEQ + s0+i] = a*g + (1.f-a)*l;
  }
}

// ---------------- K_mean: per-channel spatial mean of FUSED -----------------
__global__ void k_mean(const float* __restrict__ F, float* __restrict__ MEAN){
  __shared__ float red[4];
  int cc = blockIdx.x, tid = threadIdx.x;
  float acc = 0.f;
  for (int s=tid; s<LSEQ; s+=256) acc += F[cc*LSEQ + s];
  #pragma unroll
  for (int off=32; off; off>>=1) acc += __shfl_down(acc, off, 64);
  if ((tid&63)==0) red[tid>>6] = acc;
  __syncthreads();
  if (tid==0) MEAN[cc] = (red[0]+red[1]+red[2]+red[3])*(1.f/LSEQ);
}

// ---------------- K11: channel attention -> per-channel sigmoid -------------
__global__ void k_ca(const float* __restrict__ MEAN, const float* __restrict__ w1, const float* __restrict__ b1,
                     const float* __restrict__ w2, const float* __restrict__ b2, float* __restrict__ SIG){
  __shared__ float y1[8];
  int tid = threadIdx.x;
  if (tid<8){
    float acc = b1[tid];
    for (int c=0;c<128;c++) acc += w1[tid*128+c]*MEAN[c];
    y1[tid] = (acc>=0.f)? acc : 0.1f*acc;
  }
  __syncthreads();
  float acc = b2[tid];
  #pragma unroll
  for (int o=0;o<8;o++) acc += w2[tid*8+o]*y1[o];
  SIG[tid] = sigmoidf_(acc);
}

// ---------------- K12: out = x + fused * sigmoid(yc) ------------------------
__global__ void k_final(const float* __restrict__ x, const float* __restrict__ F, const float* __restrict__ SIG,
                        float* __restrict__ out){
  int idx = blockIdx.x*256 + threadIdx.x;
  int cc = idx>>15;
  out[idx] = x[idx] + F[idx]*SIG[cc];
}

extern "C" void kernel_launch(void* const* d_in, const int* in_sizes, int n_in,
                              void* d_out, int out_size, void* d_ws, size_t ws_size,
                              hipStream_t stream){
  (void)in_sizes; (void)n_in; (void)out_size; (void)ws_size;
  const float* x       = (const float*)d_in[0];
  const float* norm_w  = (const float*)d_in[1];
  const float* gate_w  = (const float*)d_in[2];
  const float* gate_b  = (const float*)d_in[3];
  const float* loc_dw_w= (const float*)d_in[28];
  const float* loc_dw_b= (const float*)d_in[29];
  const float* loc_pw_w= (const float*)d_in[30];
  const float* loc_pw_b= (const float*)d_in[31];
  const float* ca_w1   = (const float*)d_in[32];
  const float* ca_b1   = (const float*)d_in[33];
  const float* ca_w2   = (const float*)d_in[34];
  const float* ca_b2   = (const float*)d_in[35];
  const float* alpha   = (const float*)d_in[36];

  // workspace arena (floats); total ~263 MB
  float* W     = (float*)d_ws;
  float* XN    = W;                    // 4,194,304  (c,s)
  float* GATES = XN    + 4194304;      //   196,608  (j,s)
  float* GACC  = GATES + 196608;       // 4,194,304  (s,c)
  float* ZX    = GACC  + 4194304;      //21,102,592  (t,644)
  float* XB    = ZX    + 21102592;     //12,582,912  (t,384)
  float* DT    = XB    + 12582912;     //   131,072
  float* CUM   = DT    + 131072;       //   131,072
  float* CDEC  = CUM   + 131072;       //     1,024
  float* ST    = CDEC  + 1024;         // 4,194,304
  float* Y     = ST    + 4194304;      // 8,388,608  (t,256)
  float* LC1   = Y     + 8388608;      // 4,194,304  (c,s)   (aliased as CB during runs)
  float* LC2   = LC1   + 4194304;      // 4,194,304  (c,s)
  float* MEAN  = LC2   + 4194304;      //       128
  float* SIG   = MEAN  + 128;          //       128
  u16*   XNT   = (u16*)(SIG + 128);    // 4,194,304 u16 (2,097,152 floats)
  u16*   WinT  = (u16*)(SIG + 128 + 2097152);  // 98,304 u16
  float* CB    = LC1;                  // alias: per-chunk CB scratch (dead before LC1 used)

  hipMemsetAsync(GACC, 0, 4194304*sizeof(float), stream);
  k_xn   <<<128,256,0,stream>>>(x, norm_w, XN);
  k_gates<<<128,256,0,stream>>>(XN, gate_w, gate_b, GATES);

  for (int r=0;r<6;r++){
    int m = r>>1;
    const float* Win   = (const float*)d_in[4 + m*8 + 0];
    const float* convw = (const float*)d_in[4 + m*8 + 1];
    const float* convb = (const float*)d_in[4 + m*8 + 2];
    const float* dtb   = (const float*)d_in[4 + m*8 + 3];
    const float* Alog  = (const float*)d_in[4 + m*8 + 4];
    const float* Dp    = (const float*)d_in[4 + m*8 + 5];
    const float* nw2   = (const float*)d_in[4 + m*8 + 6];
    const float* Wout  = (const float*)d_in[4 + m*8 + 7];
    if ((r&1)==0){
      k_permute<<<1024,256,0,stream>>>(XN, XNT, m);
      k_prepw  <<<384,256,0,stream>>>(Win, WinT);
    }
    k_gin_mfma<<<dim3(6,256),256,0,stream>>>(XNT, WinT, ZX, r&1);
    k_conv    <<<32768,384,0,stream>>>(ZX, convw, convb, XB);
    k_dtcum   <<<4,256,0,stream>>>(ZX, dtb, Alog, DT, CUM, CDEC);
    k_cb      <<<256,256,0,stream>>>(XB, CB);
    k_chunk   <<<1024,256,0,stream>>>(XB, DT, CUM, CB, Dp, Y, ST);
    k_scan    <<<64,256,0,stream>>>(ST, CDEC);
    k_inter   <<<1024,256,0,stream>>>(XB, CUM, ST, Y);
    k_ynorm   <<<32768,256,0,stream>>>(Y, ZX, nw2);
    k_gemm_out<<<512,256,0,stream>>>(Y, Wout, GATES, GACC, r);
  }

  k_dwconv<<<16384,256,0,stream>>>(XN, loc_dw_w, loc_dw_b, LC1);
  k_pw    <<<512,256,0,stream>>>(LC1, loc_pw_w, loc_pw_b, LC2);
  k_fuse  <<<1024,256,0,stream>>>(GACC, LC2, alpha, LC1);   // FUSED -> LC1
  k_mean  <<<128,256,0,stream>>>(LC1, MEAN);
  k_ca    <<<1,128,0,stream>>>(MEAN, ca_w1, ca_b1, ca_w2, ca_b2, SIG);
  k_final <<<16384,256,0,stream>>>(x, LC1, SIG, (float*)d_out);
}

// Round 4
// 2384.978 us; speedup vs baseline: 1.9671x; 1.3706x over previous
//
#include <hip/hip_runtime.h>

// OmniMambaBlock — round 4: MFMA everywhere GEMM-shaped.
// fp32 I/O per reference; fp16/bf16 LDS staging + MFMA internally.

typedef unsigned short u16;
typedef unsigned int   u32;
typedef __attribute__((ext_vector_type(8))) short short8;      // bf16x8
typedef __attribute__((ext_vector_type(8))) _Float16 half8;    // fp16x8
typedef __attribute__((ext_vector_type(4))) float f32x4;

#define LSEQ 32768
#define CDIM 128
#define NPROJ 644
#define CCH 384
#define DIN 256
#define NHD 4
#define CKL 128
#define NCHK 256

__device__ __forceinline__ float b2f(u16 u){ u32 x=((u32)u)<<16; float f; __builtin_memcpy(&f,&x,4); return f; }
__device__ __forceinline__ u16 f2b(float f){ u32 x; __builtin_memcpy(&x,&f,4); x += 0x7fffu + ((x>>16)&1u); return (u16)(x>>16); }
__device__ __forceinline__ u16 f2h(float v){ _Float16 h=(_Float16)v; u16 b; __builtin_memcpy(&b,&h,2); return b; }
__device__ __forceinline__ float h2f(u16 b){ _Float16 h; __builtin_memcpy(&h,&b,2); return (float)h; }
__device__ __forceinline__ float sigmoidf_(float v){ return 1.f/(1.f+__expf(-v)); }
__device__ __forceinline__ float siluf_(float v){ return v*sigmoidf_(v); }
__device__ __forceinline__ float softplusf_(float v){ return (v>20.f)? v : log1pf(__expf(v)); }

__device__ __forceinline__ int seq2sp(int t, int run){
  int te = (run&1) ? (LSEQ-1-t) : t;
  int a = te>>10, b=(te>>5)&31, c=te&31;
  int d,h,w;
  switch(run>>1){
    case 0: d=a; h=b; w=c; break;
    case 1: h=a; d=b; w=c; break;
    default: w=a; d=b; h=c; break;
  }
  return (d<<10)|(h<<5)|w;
}

// ---------------- K1: xn = rmsnorm(x, norm_w), layout (c,s) -----------------
__global__ void k_xn(const float* __restrict__ x, const float* __restrict__ nw, float* __restrict__ XN){
  int s = blockIdx.x*256 + threadIdx.x;
  float ss = 0.f;
  #pragma unroll 8
  for (int c=0;c<CDIM;c++){ float v=x[c*LSEQ+s]; ss += v*v; }
  float sc = rsqrtf(ss*(1.f/CDIM)+1e-6f);
  #pragma unroll 8
  for (int c=0;c<CDIM;c++){ XN[c*LSEQ+s] = x[c*LSEQ+s]*sc*nw[c]; }
}

// ---------------- K1b: gates softmax, layout (j,s) --------------------------
__global__ void k_gates(const float* __restrict__ XN, const float* __restrict__ gw, const float* __restrict__ gb, float* __restrict__ G){
  int s = blockIdx.x*256 + threadIdx.x;
  float a[6];
  #pragma unroll
  for (int j=0;j<6;j++) a[j]=gb[j];
  for (int c=0;c<CDIM;c++){
    float v = XN[c*LSEQ+s];
    #pragma unroll
    for (int j=0;j<6;j++) a[j] += v*gw[c*6+j];
  }
  float m=a[0];
  #pragma unroll
  for (int j=1;j<6;j++) m = fmaxf(m,a[j]);
  float e[6], ssum=0.f;
  #pragma unroll
  for (int j=0;j<6;j++){ e[j]=__expf(a[j]-m); ssum+=e[j]; }
  float inv = 1.f/ssum;
  #pragma unroll
  for (int j=0;j<6;j++) G[j*LSEQ+s] = e[j]*inv;
}

// ---------------- K_perm: XNT[t][c] bf16, sequence-ordered ------------------
__global__ __launch_bounds__(256) void k_permute(const float* __restrict__ XN, u16* __restrict__ XNT, int dir){
  __shared__ u16 TS[128*34];
  int a = blockIdx.x>>5, b = blockIdx.x&31;
  int tid = threadIdx.x;
  int spa = (dir==1)? b : a;
  int spb = (dir==1)? a : b;
  int spbase = spa*1024 + spb*32;
  for (int idx=tid; idx<4096; idx+=256){
    int c = idx>>5, i = idx&31;
    TS[c*34+i] = f2b(XN[c*LSEQ + spbase + i]);
  }
  __syncthreads();
  for (int idx=tid; idx<4096; idx+=256){
    int i = idx>>7, c = idx&127;
    int t = (dir==2) ? (i*1024 + a*32 + b) : (a*1024 + b*32 + i);
    XNT[t*128 + c] = TS[c*34+i];
  }
}

// ---------------- K_prepw: WinT[j][k] bf16, j padded to 768 -----------------
__global__ void k_prepw(const float* __restrict__ Win, u16* __restrict__ WinT){
  int idx = blockIdx.x*256 + threadIdx.x;   // 768*128
  int j = idx>>7, k = idx&127;
  float v = (j<NPROJ)? Win[k*NPROJ + j] : 0.f;
  WinT[idx] = f2b(v);
}

// ---------------- K_prewo: WoT[c][k] fp16 (Wout transposed) -----------------
__global__ void k_prewo(const float* __restrict__ Wout, u16* __restrict__ WoT){
  int idx = blockIdx.x*256 + threadIdx.x;   // 128*256
  int c = idx>>8, k = idx&255;
  WoT[idx] = f2h(Wout[k*CDIM + c]);
}

// ---------------- K2: ZX[t,j] = XNT[t,:]·WinT[j,:]  (bf16 MFMA) -------------
__global__ __launch_bounds__(256) void k_gin_mfma(const u16* __restrict__ XNT, const u16* __restrict__ WinT,
                                                  float* __restrict__ ZX, int flip){
  __shared__ u16 Asb[128*136];
  __shared__ u16 Bsb[128*136];
  int j0 = blockIdx.x*128, t0 = blockIdx.y*128;
  int tid = threadIdx.x;
  for (int ch = tid; ch < 2048; ch += 256){
    int row = ch>>4, c8 = ch&15;
    int tg = flip ? (LSEQ-1-(t0+row)) : (t0+row);
    uint4 av = *(const uint4*)(XNT + tg*128 + c8*8);
    *(uint4*)(&Asb[row*136 + c8*8]) = av;
    uint4 bv = *(const uint4*)(WinT + (j0+row)*128 + c8*8);
    *(uint4*)(&Bsb[row*136 + c8*8]) = bv;
  }
  __syncthreads();
  int lane = tid&63, wid = tid>>6;
  int wm = (wid>>1)*64, wn = (wid&1)*64;
  int lm = lane&15, lq = lane>>4;
  f32x4 acc[4][4] = {};
  for (int kt=0; kt<4; kt++){
    short8 af[4], bf[4];
    #pragma unroll
    for (int mt=0;mt<4;mt++) af[mt] = *(const short8*)(&Asb[(wm+mt*16+lm)*136 + kt*32 + lq*8]);
    #pragma unroll
    for (int nt=0;nt<4;nt++) bf[nt] = *(const short8*)(&Bsb[(wn+nt*16+lm)*136 + kt*32 + lq*8]);
    #pragma unroll
    for (int mt=0;mt<4;mt++)
      #pragma unroll
      for (int nt=0;nt<4;nt++)
        acc[mt][nt] = __builtin_amdgcn_mfma_f32_16x16x32_bf16(af[mt], bf[nt], acc[mt][nt], 0,0,0);
  }
  #pragma unroll
  for (int mt=0;mt<4;mt++){
    #pragma unroll
    for (int nt=0;nt<4;nt++){
      int j = j0 + wn + nt*16 + lm;
      if (j < NPROJ){
        #pragma unroll
        for (int r=0;r<4;r++){
          int t = t0 + wm + mt*16 + lq*4 + r;
          ZX[t*NPROJ + j] = acc[mt][nt][r];
        }
      }
    }
  }
}

// ---------------- K3a: causal depthwise conv1d K=4 + silu (tiled) -----------
__global__ __launch_bounds__(384) void k_conv(const float* __restrict__ ZX, const float* __restrict__ cw,
                                              const float* __restrict__ cb, float* __restrict__ XB){
  __shared__ float smc[35*384];
  int t0 = blockIdx.x*32;
  int tid = threadIdx.x;
  for (int idx=tid; idx<13440; idx+=384){
    int j = idx/384, chh = idx - j*384;
    int t = t0-3+j;
    smc[idx] = (t>=0)? ZX[t*NPROJ + 256 + chh] : 0.f;
  }
  __syncthreads();
  int ch = tid;
  float w0=cw[ch*4], w1=cw[ch*4+1], w2=cw[ch*4+2], w3=cw[ch*4+3], bb=cb[ch];
  for (int i=0;i<32;i++){
    float acc = w0*smc[i*384+ch] + w1*smc[(i+1)*384+ch] + w2*smc[(i+2)*384+ch] + w3*smc[(i+3)*384+ch] + bb;
    XB[(t0+i)*CCH + ch] = siluf_(acc);
  }
}

// ---------------- K3b: dt softplus + per-chunk cumsum of dt*A ---------------
__global__ void k_dtcum(const float* __restrict__ ZX, const float* __restrict__ dtb, const float* __restrict__ Alog,
                        float* __restrict__ DT, float* __restrict__ CUM, float* __restrict__ CDEC){
  int g = blockIdx.x*256 + threadIdx.x;
  int c = g>>2, h = g&3;
  float A = -__expf(Alog[h]);
  float bias = dtb[h];
  float acc = 0.f;
  for (int i=0;i<CKL;i++){
    int t = c*CKL+i;
    float dt = softplusf_(ZX[t*NPROJ + 640 + h] + bias);
    DT[t*4+h] = dt;
    acc += dt*A;
    CUM[t*4+h] = acc;
  }
  CDEC[c*4+h] = __expf(acc);
}

// ---------------- K4: per (chunk,head): CB + Y_intra + S, all MFMA ----------
// LDS union: [0,18432) Cs[128][72] @0 / Bsm[128][72] @9216, later Mh[128][136]
//            [18432,27136) Xsh[64][136] fp16   [27136,35840) BdeT[64][136]
__global__ __launch_bounds__(256) void k_chunk(const float* __restrict__ XB, const float* __restrict__ DT,
                                               const float* __restrict__ CUM, const float* __restrict__ Dp,
                                               float* __restrict__ Y, float* __restrict__ ST){
  __shared__ u16 sh[35840];
  __shared__ float cum_s[128];
  u16* Cs   = sh;
  u16* Bsm  = sh + 9216;
  u16* Mh   = sh;            // overwrites Cs/Bsm after CB phase
  u16* Xsh  = sh + 18432;
  u16* BdeT = sh + 27136;

  int bid = blockIdx.x; int c = bid>>2, h = bid&3;
  int tid = threadIdx.x, lane = tid&63, wid = tid>>6;
  int lm = lane&15, lq = lane>>4;

  // stage C, B (fp16, [t][72]) and xdt (fp16, [p][136])
  for (int idx=tid; idx<8192; idx+=256){
    int t = idx>>6, n = idx&63;
    int row = (c*CKL+t)*CCH;
    Cs[t*72+n]  = f2h(XB[row+320+n]);
    Bsm[t*72+n] = f2h(XB[row+256+n]);
    float xv = XB[row + h*64 + n] * DT[(c*CKL+t)*4 + h];
    Xsh[n*136 + t] = f2h(xv);
  }
  if (tid<128) cum_s[tid] = CUM[(c*CKL+tid)*4 + h];
  __syncthreads();

  // ---- CB = C·B^T (per-wave: t-range wid*32..+31, all 8 s-tiles) ----
  f32x4 cbac[2][8] = {};
  for (int kt=0; kt<2; kt++){
    half8 af[2], bfv[8];
    #pragma unroll
    for (int mt=0;mt<2;mt++) af[mt] = *(const half8*)&Cs[(wid*32+mt*16+lm)*72 + kt*32 + lq*8];
    #pragma unroll
    for (int nt=0;nt<8;nt++) bfv[nt] = *(const half8*)&Bsm[(nt*16+lm)*72 + kt*32 + lq*8];
    #pragma unroll
    for (int mt=0;mt<2;mt++)
      #pragma unroll
      for (int nt=0;nt<8;nt++)
        cbac[mt][nt] = __builtin_amdgcn_mfma_f32_16x16x32_f16(af[mt], bfv[nt], cbac[mt][nt], 0,0,0);
  }
  // BdeT[n][s] = B[s][n]*exp(cum[127]-cum[s])  (reads Bsm before overwrite)
  {
    float cl = cum_s[127];
    for (int idx=tid; idx<8192; idx+=256){
      int s = idx&127, n = idx>>7;
      float de = __expf(cl - cum_s[s]);
      BdeT[n*136+s] = f2h(h2f(Bsm[s*72+n]) * de);
    }
  }
  __syncthreads();
  // ---- M[t][s] = mask(s<=t) * CB * exp(cum_t - cum_s), into Mh fp16 ----
  #pragma unroll
  for (int mt=0;mt<2;mt++){
    int tb = wid*32 + mt*16;
    #pragma unroll
    for (int nt=0;nt<8;nt++){
      int s = nt*16 + lm;
      #pragma unroll
      for (int r=0;r<4;r++){
        int t = tb + lq*4 + r;
        float m = (s<=t)? cbac[mt][nt][r]*__expf(cum_s[t]-cum_s[s]) : 0.f;
        Mh[t*136+s] = f2h(m);
      }
    }
  }
  __syncthreads();

  // ---- Y_intra = M @ xdt  (D[t][p]) ----
  f32x4 ya[2][4] = {};
  for (int kt=0; kt<4; kt++){
    half8 af[2], bfv[4];
    #pragma unroll
    for (int mt=0;mt<2;mt++) af[mt] = *(const half8*)&Mh[(wid*32+mt*16+lm)*136 + kt*32 + lq*8];
    #pragma unroll
    for (int nt=0;nt<4;nt++) bfv[nt] = *(const half8*)&Xsh[(nt*16+lm)*136 + kt*32 + lq*8];
    #pragma unroll
    for (int mt=0;mt<2;mt++)
      #pragma unroll
      for (int nt=0;nt<4;nt++)
        ya[mt][nt] = __builtin_amdgcn_mfma_f32_16x16x32_f16(af[mt], bfv[nt], ya[mt][nt], 0,0,0);
  }
  float dval = Dp[h];
  #pragma unroll
  for (int mt=0;mt<2;mt++){
    #pragma unroll
    for (int nt=0;nt<4;nt++){
      int p = nt*16 + lm;
      #pragma unroll
      for (int r=0;r<4;r++){
        int t = wid*32 + mt*16 + lq*4 + r;
        float xhv = XB[(c*CKL+t)*CCH + (h<<6) + p];
        Y[((c*CKL+t)<<8) + (h<<6) + p] = ya[mt][nt][r] + dval*xhv;
      }
    }
  }

  // ---- S[p][n] = xdt^T @ BdeT^T  (D[p][n], per-wave p-range wid*16..+15) ----
  f32x4 sa[4] = {};
  for (int kt=0; kt<4; kt++){
    half8 aa = *(const half8*)&Xsh[(wid*16+lm)*136 + kt*32 + lq*8];
    #pragma unroll
    for (int nt=0;nt<4;nt++){
      half8 bfv = *(const half8*)&BdeT[(nt*16+lm)*136 + kt*32 + lq*8];
      sa[nt] = __builtin_amdgcn_mfma_f32_16x16x32_f16(aa, bfv, sa[nt], 0,0,0);
    }
  }
  #pragma unroll
  for (int nt=0;nt<4;nt++){
    int n = nt*16 + lm;
    #pragma unroll
    for (int r=0;r<4;r++){
      int p = wid*16 + lq*4 + r;
      ST[((c*4+h)*64 + p)*64 + n] = sa[nt][r];
    }
  }
}

// ---------------- K5: sequential chunk-state scan ---------------------------
__global__ void k_scan(float* __restrict__ ST, const float* __restrict__ CDEC){
  int g = blockIdx.x*256 + threadIdx.x;
  int h = g>>12;
  float hp = 0.f;
  #pragma unroll 4
  for (int c=0;c<NCHK;c++){
    float dec = CDEC[(c<<2)+h];
    float sv = ST[g + (c<<14)];
    ST[g + (c<<14)] = hp;
    hp = dec*hp + sv;
  }
}

// ---------------- K6: Y += exp(cum[t]) * Cm[t]·hprev[p,:] -------------------
__global__ __launch_bounds__(256) void k_inter(const float* __restrict__ XB, const float* __restrict__ CUM,
                                               const float* __restrict__ ST, float* __restrict__ Y){
  __shared__ float Hs[64*68];
  int bid = blockIdx.x; int c = bid>>2, h = bid&3;
  int tid = threadIdx.x, lane = tid&63, wid = tid>>6;
  for (int idx=tid; idx<4096; idx+=256){
    int p = idx>>6, n = idx&63;
    Hs[p*68+n] = ST[((c*4+h)*64+p)*64+n];
  }
  __syncthreads();
  const float4* H4 = (const float4*)&Hs[lane*68];
  for (int i=0;i<32;i++){
    int t = wid + i*4;
    const float4* C4 = (const float4*)(XB + (c*CKL+t)*CCH + 320);
    float acc = 0.f;
    #pragma unroll
    for (int n4=0;n4<16;n4++){
      float4 cc = C4[n4]; float4 hh = H4[n4];
      acc += cc.x*hh.x + cc.y*hh.y + cc.z*hh.z + cc.w*hh.w;
    }
    float et = __expf(CUM[(c*CKL+t)*4+h]);
    Y[((c*CKL+t)<<8) + (h<<6) + lane] += et*acc;
  }
}

// ---------------- K7a: YH = fp16( rmsnorm(y*silu(z)) * normw ) --------------
__global__ void k_ynorm(const float* __restrict__ Y, const float* __restrict__ ZX, const float* __restrict__ nw,
                        u16* __restrict__ YH){
  __shared__ float red[4];
  int t = blockIdx.x, i = threadIdx.x;
  float u = Y[t*DIN+i];
  float z = ZX[t*NPROJ+i];
  u *= siluf_(z);
  float ss = u*u;
  #pragma unroll
  for (int off=32; off; off>>=1) ss += __shfl_down(ss, off, 64);
  int lane = i&63, w = i>>6;
  if (lane==0) red[w] = ss;
  __syncthreads();
  float tot = red[0]+red[1]+red[2]+red[3];
  float sc = rsqrtf(tot*(1.f/DIN)+1e-6f);
  YH[t*DIN+i] = f2h(u*sc*nw[i]);
}

// ---------------- K7b: out GEMM (fp16 MFMA) + gate scatter into GACC --------
__global__ __launch_bounds__(256) void k_gout_mfma(const u16* __restrict__ YH, const u16* __restrict__ WoT,
                                                   const float* __restrict__ G, float* __restrict__ GACC, int run){
  __shared__ u16 Ys[128*136];
  __shared__ u16 Ws[128*136];
  int t0 = blockIdx.x*128;
  int tid = threadIdx.x, lane = tid&63, wid = tid>>6;
  int lm = lane&15, lq = lane>>4;
  f32x4 acc[2][8] = {};
  for (int kb=0; kb<2; kb++){
    __syncthreads();
    for (int ch=tid; ch<2048; ch+=256){
      int row = ch>>4, c8 = ch&15;
      *(uint4*)&Ys[row*136 + c8*8] = *(const uint4*)(YH + (t0+row)*DIN + kb*128 + c8*8);
      *(uint4*)&Ws[row*136 + c8*8] = *(const uint4*)(WoT + row*DIN + kb*128 + c8*8);
    }
    __syncthreads();
    for (int kt=0; kt<4; kt++){
      half8 af[2], bfv[8];
      #pragma unroll
      for (int mt=0;mt<2;mt++) af[mt] = *(const half8*)&Ys[(wid*32+mt*16+lm)*136 + kt*32 + lq*8];
      #pragma unroll
      for (int nt=0;nt<8;nt++) bfv[nt] = *(const half8*)&Ws[(nt*16+lm)*136 + kt*32 + lq*8];
      #pragma unroll
      for (int mt=0;mt<2;mt++)
        #pragma unroll
        for (int nt=0;nt<8;nt++)
          acc[mt][nt] = __builtin_amdgcn_mfma_f32_16x16x32_f16(af[mt], bfv[nt], acc[mt][nt], 0,0,0);
    }
  }
  #pragma unroll
  for (int mt=0;mt<2;mt++){
    #pragma unroll
    for (int r=0;r<4;r++){
      int t = t0 + wid*32 + mt*16 + lq*4 + r;
      int sp = seq2sp(t, run);
      float g = G[run*LSEQ + sp];
      float* dst = &GACC[sp*CDIM];
      #pragma unroll
      for (int nt=0;nt<8;nt++){
        int cd = nt*16 + lm;
        dst[cd] += g*acc[mt][nt][r];
      }
    }
  }
}

// ---------------- K8: depthwise 3x3x3 conv (zero pad), layout (c,s) ---------
__global__ void k_dwconv(const float* __restrict__ XN, const float* __restrict__ w, const float* __restrict__ b,
                         float* __restrict__ LC1){
  int idx = blockIdx.x*256 + threadIdx.x;
  int cc = idx>>15, s = idx&32767;
  int d = s>>10, hh=(s>>5)&31, ww=s&31;
  float acc = 0.f;
  for (int dz=-1;dz<=1;dz++){
    int nd = d+dz; if ((unsigned)nd>31u) continue;
    for (int dy=-1;dy<=1;dy++){
      int nh = hh+dy; if ((unsigned)nh>31u) continue;
      for (int dx=-1;dx<=1;dx++){
        int nw = ww+dx; if ((unsigned)nw>31u) continue;
        acc += w[cc*27 + (dz+1)*9 + (dy+1)*3 + (dx+1)] * XN[cc*LSEQ + (nd<<10)+(nh<<5)+nw];
      }
    }
  }
  LC1[idx] = acc + b[cc];
}

// ---------------- K9: pointwise 128x128 + silu ------------------------------
__global__ __launch_bounds__(256) void k_pw(const float* __restrict__ LC1, const float* __restrict__ pw,
                                            const float* __restrict__ pwb, float* __restrict__ LC2){
  __shared__ float sm[8320];
  int s0 = blockIdx.x*64;
  int tid = threadIdx.x, sl = tid&63, og = tid>>6;
  for (int idx=tid; idx<8192; idx+=256){
    int cl = idx>>6, ssl = idx&63;
    sm[cl*64+ssl] = LC1[cl*LSEQ + s0 + ssl];
  }
  __syncthreads();
  float acc[32]={};
  for (int c=0;c<128;c++){
    float xv = sm[c*64+sl];
    #pragma unroll
    for (int j=0;j<32;j++) acc[j] += pw[(og*32+j)*128 + c] * xv;
  }
  __syncthreads();
  #pragma unroll
  for (int j=0;j<32;j++){
    int o = og*32+j;
    float v = acc[j] + pwb[o];
    sm[sl*130 + o] = siluf_(v);
  }
  __syncthreads();
  for (int idx=tid; idx<8192; idx+=256){
    int o = idx>>6, ssl = idx&63;
    LC2[o*LSEQ + s0 + ssl] = sm[ssl*130 + o];
  }
}

// ---------------- K10: fused = a*g + (1-a)*lc, transpose --------------------
__global__ void k_fuse(const float* __restrict__ GACC, const float* __restrict__ LC2,
                       const float* __restrict__ alpha, float* __restrict__ FUSED){
  __shared__ float tile[64*65];
  int bs = blockIdx.x>>1, bc = blockIdx.x&1;
  int s0 = bs*64, c0 = bc*64;
  int tid = threadIdx.x;
  float a = alpha[0];
  for (int idx=tid; idx<4096; idx+=256){
    int i = idx>>6, j = idx&63;
    tile[i*65+j] = GACC[(s0+i)*CDIM + c0+j];
  }
  __syncthreads();
  for (int idx=tid; idx<4096; idx+=256){
    int j = idx>>6, i = idx&63;
    float g = tile[i*65+j];
    float l = LC2[(c0+j)*LSEQ + s0+i];
    FUSED[(c0+j)*LSEQ + s0+i] = a*g + (1.f-a)*l;
  }
}

// ---------------- K_mean --------------------------------------------------
__global__ void k_mean(const float* __restrict__ F, float* __restrict__ MEAN){
  __shared__ float red[4];
  int cc = blockIdx.x, tid = threadIdx.x;
  float acc = 0.f;
  for (int s=tid; s<LSEQ; s+=256) acc += F[cc*LSEQ + s];
  #pragma unroll
  for (int off=32; off; off>>=1) acc += __shfl_down(acc, off, 64);
  if ((tid&63)==0) red[tid>>6] = acc;
  __syncthreads();
  if (tid==0) MEAN[cc] = (red[0]+red[1]+red[2]+red[3])*(1.f/LSEQ);
}

// ---------------- K11: channel attention ------------------------------------
__global__ void k_ca(const float* __restrict__ MEAN, const float* __restrict__ w1, const float* __restrict__ b1,
                     const float* __restrict__ w2, const float* __restrict__ b2, float* __restrict__ SIG){
  __shared__ float y1[8];
  int tid = threadIdx.x;
  if (tid<8){
    float acc = b1[tid];
    for (int c=0;c<128;c++) acc += w1[tid*128+c]*MEAN[c];
    y1[tid] = (acc>=0.f)? acc : 0.1f*acc;
  }
  __syncthreads();
  float acc = b2[tid];
  #pragma unroll
  for (int o=0;o<8;o++) acc += w2[tid*8+o]*y1[o];
  SIG[tid] = sigmoidf_(acc);
}

// ---------------- K12: out = x + fused * sigmoid(yc) ------------------------
__global__ void k_final(const float* __restrict__ x, const float* __restrict__ F, const float* __restrict__ SIG,
                        float* __restrict__ out){
  int idx = blockIdx.x*256 + threadIdx.x;
  int cc = idx>>15;
  out[idx] = x[idx] + F[idx]*SIG[cc];
}

extern "C" void kernel_launch(void* const* d_in, const int* in_sizes, int n_in,
                              void* d_out, int out_size, void* d_ws, size_t ws_size,
                              hipStream_t stream){
  (void)in_sizes; (void)n_in; (void)out_size; (void)ws_size;
  const float* x       = (const float*)d_in[0];
  const float* norm_w  = (const float*)d_in[1];
  const float* gate_w  = (const float*)d_in[2];
  const float* gate_b  = (const float*)d_in[3];
  const float* loc_dw_w= (const float*)d_in[28];
  const float* loc_dw_b= (const float*)d_in[29];
  const float* loc_pw_w= (const float*)d_in[30];
  const float* loc_pw_b= (const float*)d_in[31];
  const float* ca_w1   = (const float*)d_in[32];
  const float* ca_b1   = (const float*)d_in[33];
  const float* ca_w2   = (const float*)d_in[34];
  const float* ca_b2   = (const float*)d_in[35];
  const float* alpha   = (const float*)d_in[36];

  float* W     = (float*)d_ws;
  float* XN    = W;                    // 4,194,304  (c,s)
  float* GATES = XN    + 4194304;      //   196,608  (j,s)
  float* GACC  = GATES + 196608;       // 4,194,304  (s,c)
  float* ZX    = GACC  + 4194304;      //21,102,592  (t,644)
  float* XB    = ZX    + 21102592;     //12,582,912  (t,384)
  float* DT    = XB    + 12582912;     //   131,072
  float* CUM   = DT    + 131072;       //   131,072
  float* CDEC  = CUM   + 131072;       //     1,024
  float* ST    = CDEC  + 1024;         // 4,194,304  (also aliased as YH fp16 after k_inter)
  float* Y     = ST    + 4194304;      // 8,388,608  (t,256)
  float* LC1   = Y     + 8388608;      // 4,194,304  (c,s)
  float* LC2   = LC1   + 4194304;      // 4,194,304  (c,s)
  float* MEAN  = LC2   + 4194304;      //       128
  float* SIG   = MEAN  + 128;          //       128
  u16*   XNT   = (u16*)(SIG + 128);    // 4,194,304 u16
  u16*   WinT  = XNT + 4194304;        //    98,304 u16
  u16*   WoT   = WinT + 98304;         //    32,768 u16
  u16*   YH    = (u16*)ST;             // alias: ST dead after k_inter each run

  hipMemsetAsync(GACC, 0, 4194304*sizeof(float), stream);
  k_xn   <<<128,256,0,stream>>>(x, norm_w, XN);
  k_gates<<<128,256,0,stream>>>(XN, gate_w, gate_b, GATES);

  for (int r=0;r<6;r++){
    int m = r>>1;
    const float* Win   = (const float*)d_in[4 + m*8 + 0];
    const float* convw = (const float*)d_in[4 + m*8 + 1];
    const float* convb = (const float*)d_in[4 + m*8 + 2];
    const float* dtb   = (const float*)d_in[4 + m*8 + 3];
    const float* Alog  = (const float*)d_in[4 + m*8 + 4];
    const float* Dp    = (const float*)d_in[4 + m*8 + 5];
    const float* nw2   = (const float*)d_in[4 + m*8 + 6];
    const float* Wout  = (const float*)d_in[4 + m*8 + 7];
    if ((r&1)==0){
      k_permute<<<1024,256,0,stream>>>(XN, XNT, m);
      k_prepw  <<<384,256,0,stream>>>(Win, WinT);
      k_prewo  <<<128,256,0,stream>>>(Wout, WoT);
    }
    k_gin_mfma<<<dim3(6,256),256,0,stream>>>(XNT, WinT, ZX, r&1);
    k_conv    <<<1024,384,0,stream>>>(ZX, convw, convb, XB);
    k_dtcum   <<<4,256,0,stream>>>(ZX, dtb, Alog, DT, CUM, CDEC);
    k_chunk   <<<1024,256,0,stream>>>(XB, DT, CUM, Dp, Y, ST);
    k_scan    <<<64,256,0,stream>>>(ST, CDEC);
    k_inter   <<<1024,256,0,stream>>>(XB, CUM, ST, Y);
    k_ynorm   <<<32768,256,0,stream>>>(Y, ZX, nw2, YH);
    k_gout_mfma<<<256,256,0,stream>>>(YH, WoT, GATES, GACC, r);
  }

  k_dwconv<<<16384,256,0,stream>>>(XN, loc_dw_w, loc_dw_b, LC1);
  k_pw    <<<512,256,0,stream>>>(LC1, loc_pw_w, loc_pw_b, LC2);
  k_fuse  <<<1024,256,0,stream>>>(GACC, LC2, alpha, LC1);
  k_mean  <<<128,256,0,stream>>>(LC1, MEAN);
  k_ca    <<<1,128,0,stream>>>(MEAN, ca_w1, ca_b1, ca_w2, ca_b2, SIG);
  k_final <<<16384,256,0,stream>>>(x, LC1, SIG, (float*)d_out);
}

// Round 5
// 1863.980 us; speedup vs baseline: 2.5169x; 1.2795x over previous
//
#include <hip/hip_runtime.h>

// OmniMambaBlock — round 5: MFMA k_inter, fp16 ZX, pipelined scan.

typedef unsigned short u16;
typedef unsigned int   u32;
typedef __attribute__((ext_vector_type(8))) short short8;      // bf16x8
typedef __attribute__((ext_vector_type(8))) _Float16 half8;    // fp16x8
typedef __attribute__((ext_vector_type(4))) float f32x4;

#define LSEQ 32768
#define CDIM 128
#define NPROJ 644
#define CCH 384
#define DIN 256
#define NHD 4
#define CKL 128
#define NCHK 256

__device__ __forceinline__ float b2f(u16 u){ u32 x=((u32)u)<<16; float f; __builtin_memcpy(&f,&x,4); return f; }
__device__ __forceinline__ u16 f2b(float f){ u32 x; __builtin_memcpy(&x,&f,4); x += 0x7fffu + ((x>>16)&1u); return (u16)(x>>16); }
__device__ __forceinline__ u16 f2h(float v){ _Float16 h=(_Float16)v; u16 b; __builtin_memcpy(&b,&h,2); return b; }
__device__ __forceinline__ float h2f(u16 b){ _Float16 h; __builtin_memcpy(&h,&b,2); return (float)h; }
__device__ __forceinline__ float sigmoidf_(float v){ return 1.f/(1.f+__expf(-v)); }
__device__ __forceinline__ float siluf_(float v){ return v*sigmoidf_(v); }
__device__ __forceinline__ float softplusf_(float v){ return (v>20.f)? v : log1pf(__expf(v)); }

__device__ __forceinline__ int seq2sp(int t, int run){
  int te = (run&1) ? (LSEQ-1-t) : t;
  int a = te>>10, b=(te>>5)&31, c=te&31;
  int d,h,w;
  switch(run>>1){
    case 0: d=a; h=b; w=c; break;
    case 1: h=a; d=b; w=c; break;
    default: w=a; d=b; h=c; break;
  }
  return (d<<10)|(h<<5)|w;
}

// ---------------- K1: xn = rmsnorm(x, norm_w), layout (c,s) -----------------
__global__ void k_xn(const float* __restrict__ x, const float* __restrict__ nw, float* __restrict__ XN){
  int s = blockIdx.x*256 + threadIdx.x;
  float ss = 0.f;
  #pragma unroll 8
  for (int c=0;c<CDIM;c++){ float v=x[c*LSEQ+s]; ss += v*v; }
  float sc = rsqrtf(ss*(1.f/CDIM)+1e-6f);
  #pragma unroll 8
  for (int c=0;c<CDIM;c++){ XN[c*LSEQ+s] = x[c*LSEQ+s]*sc*nw[c]; }
}

// ---------------- K1b: gates softmax, layout (j,s) --------------------------
__global__ void k_gates(const float* __restrict__ XN, const float* __restrict__ gw, const float* __restrict__ gb, float* __restrict__ G){
  int s = blockIdx.x*256 + threadIdx.x;
  float a[6];
  #pragma unroll
  for (int j=0;j<6;j++) a[j]=gb[j];
  for (int c=0;c<CDIM;c++){
    float v = XN[c*LSEQ+s];
    #pragma unroll
    for (int j=0;j<6;j++) a[j] += v*gw[c*6+j];
  }
  float m=a[0];
  #pragma unroll
  for (int j=1;j<6;j++) m = fmaxf(m,a[j]);
  float e[6], ssum=0.f;
  #pragma unroll
  for (int j=0;j<6;j++){ e[j]=__expf(a[j]-m); ssum+=e[j]; }
  float inv = 1.f/ssum;
  #pragma unroll
  for (int j=0;j<6;j++) G[j*LSEQ+s] = e[j]*inv;
}

// ---------------- K_perm: XNT[t][c] bf16, sequence-ordered ------------------
__global__ __launch_bounds__(256) void k_permute(const float* __restrict__ XN, u16* __restrict__ XNT, int dir){
  __shared__ u16 TS[128*34];
  int a = blockIdx.x>>5, b = blockIdx.x&31;
  int tid = threadIdx.x;
  int spa = (dir==1)? b : a;
  int spb = (dir==1)? a : b;
  int spbase = spa*1024 + spb*32;
  for (int idx=tid; idx<4096; idx+=256){
    int c = idx>>5, i = idx&31;
    TS[c*34+i] = f2b(XN[c*LSEQ + spbase + i]);
  }
  __syncthreads();
  for (int idx=tid; idx<4096; idx+=256){
    int i = idx>>7, c = idx&127;
    int t = (dir==2) ? (i*1024 + a*32 + b) : (a*1024 + b*32 + i);
    XNT[t*128 + c] = TS[c*34+i];
  }
}

// ---------------- K_prepw: WinT[j][k] bf16, j padded to 768 -----------------
__global__ void k_prepw(const float* __restrict__ Win, u16* __restrict__ WinT){
  int idx = blockIdx.x*256 + threadIdx.x;
  int j = idx>>7, k = idx&127;
  float v = (j<NPROJ)? Win[k*NPROJ + j] : 0.f;
  WinT[idx] = f2b(v);
}

// ---------------- K_prewo: WoT[c][k] fp16 (Wout transposed) -----------------
__global__ void k_prewo(const float* __restrict__ Wout, u16* __restrict__ WoT){
  int idx = blockIdx.x*256 + threadIdx.x;
  int c = idx>>8, k = idx&255;
  WoT[idx] = f2h(Wout[k*CDIM + c]);
}

// ---------------- K2: ZX[t,j] = XNT[t,:]·WinT[j,:]  (bf16 MFMA, fp16 out) ---
__global__ __launch_bounds__(256) void k_gin_mfma(const u16* __restrict__ XNT, const u16* __restrict__ WinT,
                                                  u16* __restrict__ ZX, int flip){
  __shared__ u16 Asb[128*136];
  __shared__ u16 Bsb[128*136];
  int j0 = blockIdx.x*128, t0 = blockIdx.y*128;
  int tid = threadIdx.x;
  for (int ch = tid; ch < 2048; ch += 256){
    int row = ch>>4, c8 = ch&15;
    int tg = flip ? (LSEQ-1-(t0+row)) : (t0+row);
    uint4 av = *(const uint4*)(XNT + tg*128 + c8*8);
    *(uint4*)(&Asb[row*136 + c8*8]) = av;
    uint4 bv = *(const uint4*)(WinT + (j0+row)*128 + c8*8);
    *(uint4*)(&Bsb[row*136 + c8*8]) = bv;
  }
  __syncthreads();
  int lane = tid&63, wid = tid>>6;
  int wm = (wid>>1)*64, wn = (wid&1)*64;
  int lm = lane&15, lq = lane>>4;
  f32x4 acc[4][4] = {};
  for (int kt=0; kt<4; kt++){
    short8 af[4], bf[4];
    #pragma unroll
    for (int mt=0;mt<4;mt++) af[mt] = *(const short8*)(&Asb[(wm+mt*16+lm)*136 + kt*32 + lq*8]);
    #pragma unroll
    for (int nt=0;nt<4;nt++) bf[nt] = *(const short8*)(&Bsb[(wn+nt*16+lm)*136 + kt*32 + lq*8]);
    #pragma unroll
    for (int mt=0;mt<4;mt++)
      #pragma unroll
      for (int nt=0;nt<4;nt++)
        acc[mt][nt] = __builtin_amdgcn_mfma_f32_16x16x32_bf16(af[mt], bf[nt], acc[mt][nt], 0,0,0);
  }
  #pragma unroll
  for (int mt=0;mt<4;mt++){
    #pragma unroll
    for (int nt=0;nt<4;nt++){
      int j = j0 + wn + nt*16 + lm;
      if (j < NPROJ){
        #pragma unroll
        for (int r=0;r<4;r++){
          int t = t0 + wm + mt*16 + lq*4 + r;
          ZX[t*NPROJ + j] = f2h(acc[mt][nt][r]);
        }
      }
    }
  }
}

// ---------------- K3a: causal depthwise conv1d K=4 + silu (tiled) -----------
__global__ __launch_bounds__(384) void k_conv(const u16* __restrict__ ZX, const float* __restrict__ cw,
                                              const float* __restrict__ cb, float* __restrict__ XB){
  __shared__ u16 smc[35*384];
  int t0 = blockIdx.x*32;
  int tid = threadIdx.x;
  for (int idx=tid; idx<13440; idx+=384){
    int j = idx/384, chh = idx - j*384;
    int t = t0-3+j;
    smc[idx] = (t>=0)? ZX[t*NPROJ + 256 + chh] : (u16)0;
  }
  __syncthreads();
  int ch = tid;
  float w0=cw[ch*4], w1=cw[ch*4+1], w2=cw[ch*4+2], w3=cw[ch*4+3], bb=cb[ch];
  for (int i=0;i<32;i++){
    float acc = w0*h2f(smc[i*384+ch]) + w1*h2f(smc[(i+1)*384+ch])
              + w2*h2f(smc[(i+2)*384+ch]) + w3*h2f(smc[(i+3)*384+ch]) + bb;
    XB[(t0+i)*CCH + ch] = siluf_(acc);
  }
}

// ---------------- K3b: dt softplus + per-chunk cumsum of dt*A ---------------
__global__ void k_dtcum(const u16* __restrict__ ZX, const float* __restrict__ dtb, const float* __restrict__ Alog,
                        float* __restrict__ DT, float* __restrict__ CUM, float* __restrict__ CDEC){
  int g = blockIdx.x*256 + threadIdx.x;
  int c = g>>2, h = g&3;
  float A = -__expf(Alog[h]);
  float bias = dtb[h];
  float acc = 0.f;
  for (int i=0;i<CKL;i++){
    int t = c*CKL+i;
    float dt = softplusf_(h2f(ZX[t*NPROJ + 640 + h]) + bias);
    DT[t*4+h] = dt;
    acc += dt*A;
    CUM[t*4+h] = acc;
  }
  CDEC[c*4+h] = __expf(acc);
}

// ---------------- K4: per (chunk,head): CB + Y_intra + S, all MFMA ----------
__global__ __launch_bounds__(256) void k_chunk(const float* __restrict__ XB, const float* __restrict__ DT,
                                               const float* __restrict__ CUM, const float* __restrict__ Dp,
                                               float* __restrict__ Y, float* __restrict__ ST){
  __shared__ u16 sh[35840];
  __shared__ float cum_s[128];
  u16* Cs   = sh;
  u16* Bsm  = sh + 9216;
  u16* Mh   = sh;
  u16* Xsh  = sh + 18432;
  u16* BdeT = sh + 27136;

  int bid = blockIdx.x; int c = bid>>2, h = bid&3;
  int tid = threadIdx.x, lane = tid&63, wid = tid>>6;
  int lm = lane&15, lq = lane>>4;

  for (int idx=tid; idx<8192; idx+=256){
    int t = idx>>6, n = idx&63;
    int row = (c*CKL+t)*CCH;
    Cs[t*72+n]  = f2h(XB[row+320+n]);
    Bsm[t*72+n] = f2h(XB[row+256+n]);
    float xv = XB[row + h*64 + n] * DT[(c*CKL+t)*4 + h];
    Xsh[n*136 + t] = f2h(xv);
  }
  if (tid<128) cum_s[tid] = CUM[(c*CKL+tid)*4 + h];
  __syncthreads();

  f32x4 cbac[2][8] = {};
  for (int kt=0; kt<2; kt++){
    half8 af[2], bfv[8];
    #pragma unroll
    for (int mt=0;mt<2;mt++) af[mt] = *(const half8*)&Cs[(wid*32+mt*16+lm)*72 + kt*32 + lq*8];
    #pragma unroll
    for (int nt=0;nt<8;nt++) bfv[nt] = *(const half8*)&Bsm[(nt*16+lm)*72 + kt*32 + lq*8];
    #pragma unroll
    for (int mt=0;mt<2;mt++)
      #pragma unroll
      for (int nt=0;nt<8;nt++)
        cbac[mt][nt] = __builtin_amdgcn_mfma_f32_16x16x32_f16(af[mt], bfv[nt], cbac[mt][nt], 0,0,0);
  }
  {
    float cl = cum_s[127];
    for (int idx=tid; idx<8192; idx+=256){
      int s = idx&127, n = idx>>7;
      float de = __expf(cl - cum_s[s]);
      BdeT[n*136+s] = f2h(h2f(Bsm[s*72+n]) * de);
    }
  }
  __syncthreads();
  #pragma unroll
  for (int mt=0;mt<2;mt++){
    int tb = wid*32 + mt*16;
    #pragma unroll
    for (int nt=0;nt<8;nt++){
      int s = nt*16 + lm;
      #pragma unroll
      for (int r=0;r<4;r++){
        int t = tb + lq*4 + r;
        float m = (s<=t)? cbac[mt][nt][r]*__expf(cum_s[t]-cum_s[s]) : 0.f;
        Mh[t*136+s] = f2h(m);
      }
    }
  }
  __syncthreads();

  f32x4 ya[2][4] = {};
  for (int kt=0; kt<4; kt++){
    half8 af[2], bfv[4];
    #pragma unroll
    for (int mt=0;mt<2;mt++) af[mt] = *(const half8*)&Mh[(wid*32+mt*16+lm)*136 + kt*32 + lq*8];
    #pragma unroll
    for (int nt=0;nt<4;nt++) bfv[nt] = *(const half8*)&Xsh[(nt*16+lm)*136 + kt*32 + lq*8];
    #pragma unroll
    for (int mt=0;mt<2;mt++)
      #pragma unroll
      for (int nt=0;nt<4;nt++)
        ya[mt][nt] = __builtin_amdgcn_mfma_f32_16x16x32_f16(af[mt], bfv[nt], ya[mt][nt], 0,0,0);
  }
  float dval = Dp[h];
  #pragma unroll
  for (int mt=0;mt<2;mt++){
    #pragma unroll
    for (int nt=0;nt<4;nt++){
      int p = nt*16 + lm;
      #pragma unroll
      for (int r=0;r<4;r++){
        int t = wid*32 + mt*16 + lq*4 + r;
        float xhv = XB[(c*CKL+t)*CCH + (h<<6) + p];
        Y[((c*CKL+t)<<8) + (h<<6) + p] = ya[mt][nt][r] + dval*xhv;
      }
    }
  }

  f32x4 sa[4] = {};
  for (int kt=0; kt<4; kt++){
    half8 aa = *(const half8*)&Xsh[(wid*16+lm)*136 + kt*32 + lq*8];
    #pragma unroll
    for (int nt=0;nt<4;nt++){
      half8 bfv = *(const half8*)&BdeT[(nt*16+lm)*136 + kt*32 + lq*8];
      sa[nt] = __builtin_amdgcn_mfma_f32_16x16x32_f16(aa, bfv, sa[nt], 0,0,0);
    }
  }
  #pragma unroll
  for (int nt=0;nt<4;nt++){
    int n = nt*16 + lm;
    #pragma unroll
    for (int r=0;r<4;r++){
      int p = wid*16 + lq*4 + r;
      ST[((c*4+h)*64 + p)*64 + n] = sa[nt][r];
    }
  }
}

// ---------------- K5: chunk-state scan, out-of-place (pipelined loads) ------
__global__ void k_scan(const float* __restrict__ ST, float* __restrict__ HP, const float* __restrict__ CDEC){
  int g = blockIdx.x*256 + threadIdx.x;
  int h = g>>12;
  float hp = 0.f;
  #pragma unroll 8
  for (int c=0;c<NCHK;c++){
    float dec = CDEC[(c<<2)+h];
    float sv = ST[g + (c<<14)];
    HP[g + (c<<14)] = hp;
    hp = dec*hp + sv;
  }
}

// ---------------- K6: Y += exp(cum[t,h]) * C·H^T  (fp16 MFMA, all heads) ----
__global__ __launch_bounds__(256) void k_inter(const float* __restrict__ XB, const float* __restrict__ CUM,
                                               const float* __restrict__ HP, float* __restrict__ Y){
  __shared__ u16 Cs[128*72];       // fp16 C[t][n]
  __shared__ u16 Hs[4*64*72];      // fp16 H[h][p][n]
  __shared__ float ex_s[4*128];
  int c = blockIdx.x;
  int tid = threadIdx.x, lane = tid&63, wid = tid>>6;
  int lm = lane&15, lq = lane>>4;
  for (int idx=tid; idx<8192; idx+=256){
    int t = idx>>6, n = idx&63;
    Cs[t*72+n] = f2h(XB[(c*CKL+t)*CCH + 320 + n]);
  }
  for (int idx=tid; idx<16384; idx+=256){
    int h = idx>>12, p = (idx>>6)&63, n = idx&63;
    Hs[(h*64+p)*72+n] = f2h(HP[((c*4+h)*64+p)*64+n]);
  }
  for (int idx=tid; idx<512; idx+=256){
    int h = idx>>7, t = idx&127;
    ex_s[h*128+t] = __expf(CUM[(c*CKL+t)*4+h]);
  }
  __syncthreads();
  int h = wid;
  const u16* Hh = &Hs[h*64*72];
  f32x4 acc[8][4] = {};
  for (int kt=0; kt<2; kt++){
    half8 af[8], bfv[4];
    #pragma unroll
    for (int mt=0;mt<8;mt++) af[mt] = *(const half8*)&Cs[(mt*16+lm)*72 + kt*32 + lq*8];
    #pragma unroll
    for (int nt=0;nt<4;nt++) bfv[nt] = *(const half8*)&Hh[(nt*16+lm)*72 + kt*32 + lq*8];
    #pragma unroll
    for (int mt=0;mt<8;mt++)
      #pragma unroll
      for (int nt=0;nt<4;nt++)
        acc[mt][nt] = __builtin_amdgcn_mfma_f32_16x16x32_f16(af[mt], bfv[nt], acc[mt][nt], 0,0,0);
  }
  #pragma unroll
  for (int mt=0;mt<8;mt++){
    #pragma unroll
    for (int r=0;r<4;r++){
      int t = mt*16 + lq*4 + r;
      float e = ex_s[h*128+t];
      float* dst = &Y[((c*CKL+t)<<8) + (h<<6)];
      #pragma unroll
      for (int nt=0;nt<4;nt++){
        int p = nt*16 + lm;
        dst[p] += e*acc[mt][nt][r];
      }
    }
  }
}

// ---------------- K7a: YH = fp16( rmsnorm(y*silu(z)) * normw ) --------------
__global__ void k_ynorm(const float* __restrict__ Y, const u16* __restrict__ ZX, const float* __restrict__ nw,
                        u16* __restrict__ YH){
  __shared__ float red[4];
  int t = blockIdx.x, i = threadIdx.x;
  float u = Y[t*DIN+i];
  float z = h2f(ZX[t*NPROJ+i]);
  u *= siluf_(z);
  float ss = u*u;
  #pragma unroll
  for (int off=32; off; off>>=1) ss += __shfl_down(ss, off, 64);
  int lane = i&63, w = i>>6;
  if (lane==0) red[w] = ss;
  __syncthreads();
  float tot = red[0]+red[1]+red[2]+red[3];
  float sc = rsqrtf(tot*(1.f/DIN)+1e-6f);
  YH[t*DIN+i] = f2h(u*sc*nw[i]);
}

// ---------------- K7b: out GEMM (fp16 MFMA) + gate scatter into GACC --------
__global__ __launch_bounds__(256) void k_gout_mfma(const u16* __restrict__ YH, const u16* __restrict__ WoT,
                                                   const float* __restrict__ G, float* __restrict__ GACC, int run){
  __shared__ u16 Ys[128*136];
  __shared__ u16 Ws[128*136];
  int t0 = blockIdx.x*128;
  int tid = threadIdx.x, lane = tid&63, wid = tid>>6;
  int lm = lane&15, lq = lane>>4;
  f32x4 acc[2][8] = {};
  for (int kb=0; kb<2; kb++){
    __syncthreads();
    for (int ch=tid; ch<2048; ch+=256){
      int row = ch>>4, c8 = ch&15;
      *(uint4*)&Ys[row*136 + c8*8] = *(const uint4*)(YH + (t0+row)*DIN + kb*128 + c8*8);
      *(uint4*)&Ws[row*136 + c8*8] = *(const uint4*)(WoT + row*DIN + kb*128 + c8*8);
    }
    __syncthreads();
    for (int kt=0; kt<4; kt++){
      half8 af[2], bfv[8];
      #pragma unroll
      for (int mt=0;mt<2;mt++) af[mt] = *(const half8*)&Ys[(wid*32+mt*16+lm)*136 + kt*32 + lq*8];
      #pragma unroll
      for (int nt=0;nt<8;nt++) bfv[nt] = *(const half8*)&Ws[(nt*16+lm)*136 + kt*32 + lq*8];
      #pragma unroll
      for (int mt=0;mt<2;mt++)
        #pragma unroll
        for (int nt=0;nt<8;nt++)
          acc[mt][nt] = __builtin_amdgcn_mfma_f32_16x16x32_f16(af[mt], bfv[nt], acc[mt][nt], 0,0,0);
    }
  }
  #pragma unroll
  for (int mt=0;mt<2;mt++){
    #pragma unroll
    for (int r=0;r<4;r++){
      int t = t0 + wid*32 + mt*16 + lq*4 + r;
      int sp = seq2sp(t, run);
      float g = G[run*LSEQ + sp];
      float* dst = &GACC[sp*CDIM];
      #pragma unroll
      for (int nt=0;nt<8;nt++){
        int cd = nt*16 + lm;
        dst[cd] += g*acc[mt][nt][r];
      }
    }
  }
}

// ---------------- K8: depthwise 3x3x3 conv ----------------------------------
__global__ void k_dwconv(const float* __restrict__ XN, const float* __restrict__ w, const float* __restrict__ b,
                         float* __restrict__ LC1){
  int idx = blockIdx.x*256 + threadIdx.x;
  int cc = idx>>15, s = idx&32767;
  int d = s>>10, hh=(s>>5)&31, ww=s&31;
  float acc = 0.f;
  for (int dz=-1;dz<=1;dz++){
    int nd = d+dz; if ((unsigned)nd>31u) continue;
    for (int dy=-1;dy<=1;dy++){
      int nh = hh+dy; if ((unsigned)nh>31u) continue;
      for (int dx=-1;dx<=1;dx++){
        int nw = ww+dx; if ((unsigned)nw>31u) continue;
        acc += w[cc*27 + (dz+1)*9 + (dy+1)*3 + (dx+1)] * XN[cc*LSEQ + (nd<<10)+(nh<<5)+nw];
      }
    }
  }
  LC1[idx] = acc + b[cc];
}

// ---------------- K9: pointwise 128x128 + silu ------------------------------
__global__ __launch_bounds__(256) void k_pw(const float* __restrict__ LC1, const float* __restrict__ pw,
                                            const float* __restrict__ pwb, float* __restrict__ LC2){
  __shared__ float sm[8320];
  int s0 = blockIdx.x*64;
  int tid = threadIdx.x, sl = tid&63, og = tid>>6;
  for (int idx=tid; idx<8192; idx+=256){
    int cl = idx>>6, ssl = idx&63;
    sm[cl*64+ssl] = LC1[cl*LSEQ + s0 + ssl];
  }
  __syncthreads();
  float acc[32]={};
  for (int c=0;c<128;c++){
    float xv = sm[c*64+sl];
    #pragma unroll
    for (int j=0;j<32;j++) acc[j] += pw[(og*32+j)*128 + c] * xv;
  }
  __syncthreads();
  #pragma unroll
  for (int j=0;j<32;j++){
    int o = og*32+j;
    float v = acc[j] + pwb[o];
    sm[sl*130 + o] = siluf_(v);
  }
  __syncthreads();
  for (int idx=tid; idx<8192; idx+=256){
    int o = idx>>6, ssl = idx&63;
    LC2[o*LSEQ + s0 + ssl] = sm[ssl*130 + o];
  }
}

// ---------------- K10: fused = a*g + (1-a)*lc, transpose --------------------
__global__ void k_fuse(const float* __restrict__ GACC, const float* __restrict__ LC2,
                       const float* __restrict__ alpha, float* __restrict__ FUSED){
  __shared__ float tile[64*65];
  int bs = blockIdx.x>>1, bc = blockIdx.x&1;
  int s0 = bs*64, c0 = bc*64;
  int tid = threadIdx.x;
  float a = alpha[0];
  for (int idx=tid; idx<4096; idx+=256){
    int i = idx>>6, j = idx&63;
    tile[i*65+j] = GACC[(s0+i)*CDIM + c0+j];
  }
  __syncthreads();
  for (int idx=tid; idx<4096; idx+=256){
    int j = idx>>6, i = idx&63;
    float g = tile[i*65+j];
    float l = LC2[(c0+j)*LSEQ + s0+i];
    FUSED[(c0+j)*LSEQ + s0+i] = a*g + (1.f-a)*l;
  }
}

// ---------------- K_mean ----------------------------------------------------
__global__ void k_mean(const float* __restrict__ F, float* __restrict__ MEAN){
  __shared__ float red[4];
  int cc = blockIdx.x, tid = threadIdx.x;
  float acc = 0.f;
  for (int s=tid; s<LSEQ; s+=256) acc += F[cc*LSEQ + s];
  #pragma unroll
  for (int off=32; off; off>>=1) acc += __shfl_down(acc, off, 64);
  if ((tid&63)==0) red[tid>>6] = acc;
  __syncthreads();
  if (tid==0) MEAN[cc] = (red[0]+red[1]+red[2]+red[3])*(1.f/LSEQ);
}

// ---------------- K11: channel attention ------------------------------------
__global__ void k_ca(const float* __restrict__ MEAN, const float* __restrict__ w1, const float* __restrict__ b1,
                     const float* __restrict__ w2, const float* __restrict__ b2, float* __restrict__ SIG){
  __shared__ float y1[8];
  int tid = threadIdx.x;
  if (tid<8){
    float acc = b1[tid];
    for (int c=0;c<128;c++) acc += w1[tid*128+c]*MEAN[c];
    y1[tid] = (acc>=0.f)? acc : 0.1f*acc;
  }
  __syncthreads();
  float acc = b2[tid];
  #pragma unroll
  for (int o=0;o<8;o++) acc += w2[tid*8+o]*y1[o];
  SIG[tid] = sigmoidf_(acc);
}

// ---------------- K12: out = x + fused * sigmoid(yc) ------------------------
__global__ void k_final(const float* __restrict__ x, const float* __restrict__ F, const float* __restrict__ SIG,
                        float* __restrict__ out){
  int idx = blockIdx.x*256 + threadIdx.x;
  int cc = idx>>15;
  out[idx] = x[idx] + F[idx]*SIG[cc];
}

extern "C" void kernel_launch(void* const* d_in, const int* in_sizes, int n_in,
                              void* d_out, int out_size, void* d_ws, size_t ws_size,
                              hipStream_t stream){
  (void)in_sizes; (void)n_in; (void)out_size; (void)ws_size;
  const float* x       = (const float*)d_in[0];
  const float* norm_w  = (const float*)d_in[1];
  const float* gate_w  = (const float*)d_in[2];
  const float* gate_b  = (const float*)d_in[3];
  const float* loc_dw_w= (const float*)d_in[28];
  const float* loc_dw_b= (const float*)d_in[29];
  const float* loc_pw_w= (const float*)d_in[30];
  const float* loc_pw_b= (const float*)d_in[31];
  const float* ca_w1   = (const float*)d_in[32];
  const float* ca_b1   = (const float*)d_in[33];
  const float* ca_w2   = (const float*)d_in[34];
  const float* ca_b2   = (const float*)d_in[35];
  const float* alpha   = (const float*)d_in[36];

  float* W     = (float*)d_ws;
  float* XN    = W;                    // 4,194,304  (c,s)
  float* GATES = XN    + 4194304;      //   196,608  (j,s)
  float* GACC  = GATES + 196608;       // 4,194,304  (s,c)
  u16*   ZX    = (u16*)(GACC + 4194304);  // 21,102,592 u16 = 10,551,296 fl
  float* XB    = GACC + 4194304 + 10551296;  // 12,582,912
  float* DT    = XB    + 12582912;     //   131,072
  float* CUM   = DT    + 131072;       //   131,072
  float* CDEC  = CUM   + 131072;       //     1,024
  float* ST    = CDEC  + 1024;         // 4,194,304  (aliased YH fp16 after k_inter)
  float* Y     = ST    + 4194304;      // 8,388,608  (t,256)
  float* LC1   = Y     + 8388608;      // 4,194,304  (c,s)  (aliased HPREV during runs)
  float* LC2   = LC1   + 4194304;      // 4,194,304  (c,s)
  float* MEAN  = LC2   + 4194304;      //       128
  float* SIG   = MEAN  + 128;          //       128
  u16*   XNT   = (u16*)(SIG + 128);    // 4,194,304 u16
  u16*   WinT  = XNT + 4194304;        //    98,304 u16
  u16*   WoT   = WinT + 98304;         //    32,768 u16
  u16*   YH    = (u16*)ST;
  float* HPREV = LC1;

  hipMemsetAsync(GACC, 0, 4194304*sizeof(float), stream);
  k_xn   <<<128,256,0,stream>>>(x, norm_w, XN);
  k_gates<<<128,256,0,stream>>>(XN, gate_w, gate_b, GATES);

  for (int r=0;r<6;r++){
    int m = r>>1;
    const float* Win   = (const float*)d_in[4 + m*8 + 0];
    const float* convw = (const float*)d_in[4 + m*8 + 1];
    const float* convb = (const float*)d_in[4 + m*8 + 2];
    const float* dtb   = (const float*)d_in[4 + m*8 + 3];
    const float* Alog  = (const float*)d_in[4 + m*8 + 4];
    const float* Dp    = (const float*)d_in[4 + m*8 + 5];
    const float* nw2   = (const float*)d_in[4 + m*8 + 6];
    const float* Wout  = (const float*)d_in[4 + m*8 + 7];
    if ((r&1)==0){
      k_permute<<<1024,256,0,stream>>>(XN, XNT, m);
      k_prepw  <<<384,256,0,stream>>>(Win, WinT);
      k_prewo  <<<128,256,0,stream>>>(Wout, WoT);
    }
    k_gin_mfma<<<dim3(6,256),256,0,stream>>>(XNT, WinT, ZX, r&1);
    k_conv    <<<1024,384,0,stream>>>(ZX, convw, convb, XB);
    k_dtcum   <<<4,256,0,stream>>>(ZX, dtb, Alog, DT, CUM, CDEC);
    k_chunk   <<<1024,256,0,stream>>>(XB, DT, CUM, Dp, Y, ST);
    k_scan    <<<64,256,0,stream>>>(ST, HPREV, CDEC);
    k_inter   <<<256,256,0,stream>>>(XB, CUM, HPREV, Y);
    k_ynorm   <<<32768,256,0,stream>>>(Y, ZX, nw2, YH);
    k_gout_mfma<<<256,256,0,stream>>>(YH, WoT, GATES, GACC, r);
  }

  k_dwconv<<<16384,256,0,stream>>>(XN, loc_dw_w, loc_dw_b, LC1);
  k_pw    <<<512,256,0,stream>>>(LC1, loc_pw_w, loc_pw_b, LC2);
  k_fuse  <<<1024,256,0,stream>>>(GACC, LC2, alpha, LC1);
  k_mean  <<<128,256,0,stream>>>(LC1, MEAN);
  k_ca    <<<1,128,0,stream>>>(MEAN, ca_w1, ca_b1, ca_w2, ca_b2, SIG);
  k_final <<<16384,256,0,stream>>>(x, LC1, SIG, (float*)d_out);
}

// Round 6
// 1298.813 us; speedup vs baseline: 3.6121x; 1.4351x over previous
//
#include <hip/hip_runtime.h>

// OmniMambaBlock — round 6: MFMA k_pw, parallel dtcum scan, fp16 XB.

typedef unsigned short u16;
typedef unsigned int   u32;
typedef __attribute__((ext_vector_type(8))) short short8;      // bf16x8
typedef __attribute__((ext_vector_type(8))) _Float16 half8;    // fp16x8
typedef __attribute__((ext_vector_type(4))) float f32x4;

#define LSEQ 32768
#define CDIM 128
#define NPROJ 644
#define CCH 384
#define DIN 256
#define NHD 4
#define CKL 128
#define NCHK 256

__device__ __forceinline__ float b2f(u16 u){ u32 x=((u32)u)<<16; float f; __builtin_memcpy(&f,&x,4); return f; }
__device__ __forceinline__ u16 f2b(float f){ u32 x; __builtin_memcpy(&x,&f,4); x += 0x7fffu + ((x>>16)&1u); return (u16)(x>>16); }
__device__ __forceinline__ u16 f2h(float v){ _Float16 h=(_Float16)v; u16 b; __builtin_memcpy(&b,&h,2); return b; }
__device__ __forceinline__ float h2f(u16 b){ _Float16 h; __builtin_memcpy(&h,&b,2); return (float)h; }
__device__ __forceinline__ float sigmoidf_(float v){ return 1.f/(1.f+__expf(-v)); }
__device__ __forceinline__ float siluf_(float v){ return v*sigmoidf_(v); }
__device__ __forceinline__ float softplusf_(float v){ return (v>20.f)? v : log1pf(__expf(v)); }

__device__ __forceinline__ int seq2sp(int t, int run){
  int te = (run&1) ? (LSEQ-1-t) : t;
  int a = te>>10, b=(te>>5)&31, c=te&31;
  int d,h,w;
  switch(run>>1){
    case 0: d=a; h=b; w=c; break;
    case 1: h=a; d=b; w=c; break;
    default: w=a; d=b; h=c; break;
  }
  return (d<<10)|(h<<5)|w;
}

// ---------------- K1: xn = rmsnorm(x, norm_w), layout (c,s) -----------------
__global__ void k_xn(const float* __restrict__ x, const float* __restrict__ nw, float* __restrict__ XN){
  int s = blockIdx.x*256 + threadIdx.x;
  float ss = 0.f;
  #pragma unroll 8
  for (int c=0;c<CDIM;c++){ float v=x[c*LSEQ+s]; ss += v*v; }
  float sc = rsqrtf(ss*(1.f/CDIM)+1e-6f);
  #pragma unroll 8
  for (int c=0;c<CDIM;c++){ XN[c*LSEQ+s] = x[c*LSEQ+s]*sc*nw[c]; }
}

// ---------------- K1b: gates softmax, layout (j,s) --------------------------
__global__ void k_gates(const float* __restrict__ XN, const float* __restrict__ gw, const float* __restrict__ gb, float* __restrict__ G){
  int s = blockIdx.x*256 + threadIdx.x;
  float a[6];
  #pragma unroll
  for (int j=0;j<6;j++) a[j]=gb[j];
  for (int c=0;c<CDIM;c++){
    float v = XN[c*LSEQ+s];
    #pragma unroll
    for (int j=0;j<6;j++) a[j] += v*gw[c*6+j];
  }
  float m=a[0];
  #pragma unroll
  for (int j=1;j<6;j++) m = fmaxf(m,a[j]);
  float e[6], ssum=0.f;
  #pragma unroll
  for (int j=0;j<6;j++){ e[j]=__expf(a[j]-m); ssum+=e[j]; }
  float inv = 1.f/ssum;
  #pragma unroll
  for (int j=0;j<6;j++) G[j*LSEQ+s] = e[j]*inv;
}

// ---------------- K_perm: XNT[t][c] bf16, sequence-ordered ------------------
__global__ __launch_bounds__(256) void k_permute(const float* __restrict__ XN, u16* __restrict__ XNT, int dir){
  __shared__ u16 TS[128*34];
  int a = blockIdx.x>>5, b = blockIdx.x&31;
  int tid = threadIdx.x;
  int spa = (dir==1)? b : a;
  int spb = (dir==1)? a : b;
  int spbase = spa*1024 + spb*32;
  for (int idx=tid; idx<4096; idx+=256){
    int c = idx>>5, i = idx&31;
    TS[c*34+i] = f2b(XN[c*LSEQ + spbase + i]);
  }
  __syncthreads();
  for (int idx=tid; idx<4096; idx+=256){
    int i = idx>>7, c = idx&127;
    int t = (dir==2) ? (i*1024 + a*32 + b) : (a*1024 + b*32 + i);
    XNT[t*128 + c] = TS[c*34+i];
  }
}

// ---------------- K_prepw: WinT[j][k] bf16, j padded to 768 -----------------
__global__ void k_prepw(const float* __restrict__ Win, u16* __restrict__ WinT){
  int idx = blockIdx.x*256 + threadIdx.x;
  int j = idx>>7, k = idx&127;
  float v = (j<NPROJ)? Win[k*NPROJ + j] : 0.f;
  WinT[idx] = f2b(v);
}

// ---------------- K_prewo: WoT[c][k] fp16 (Wout transposed) -----------------
__global__ void k_prewo(const float* __restrict__ Wout, u16* __restrict__ WoT){
  int idx = blockIdx.x*256 + threadIdx.x;
  int c = idx>>8, k = idx&255;
  WoT[idx] = f2h(Wout[k*CDIM + c]);
}

// ---------------- K2: ZX[t,j] = XNT[t,:]·WinT[j,:]  (bf16 MFMA, fp16 out) ---
__global__ __launch_bounds__(256) void k_gin_mfma(const u16* __restrict__ XNT, const u16* __restrict__ WinT,
                                                  u16* __restrict__ ZX, int flip){
  __shared__ u16 Asb[128*136];
  __shared__ u16 Bsb[128*136];
  int j0 = blockIdx.x*128, t0 = blockIdx.y*128;
  int tid = threadIdx.x;
  for (int ch = tid; ch < 2048; ch += 256){
    int row = ch>>4, c8 = ch&15;
    int tg = flip ? (LSEQ-1-(t0+row)) : (t0+row);
    uint4 av = *(const uint4*)(XNT + tg*128 + c8*8);
    *(uint4*)(&Asb[row*136 + c8*8]) = av;
    uint4 bv = *(const uint4*)(WinT + (j0+row)*128 + c8*8);
    *(uint4*)(&Bsb[row*136 + c8*8]) = bv;
  }
  __syncthreads();
  int lane = tid&63, wid = tid>>6;
  int wm = (wid>>1)*64, wn = (wid&1)*64;
  int lm = lane&15, lq = lane>>4;
  f32x4 acc[4][4] = {};
  for (int kt=0; kt<4; kt++){
    short8 af[4], bf[4];
    #pragma unroll
    for (int mt=0;mt<4;mt++) af[mt] = *(const short8*)(&Asb[(wm+mt*16+lm)*136 + kt*32 + lq*8]);
    #pragma unroll
    for (int nt=0;nt<4;nt++) bf[nt] = *(const short8*)(&Bsb[(wn+nt*16+lm)*136 + kt*32 + lq*8]);
    #pragma unroll
    for (int mt=0;mt<4;mt++)
      #pragma unroll
      for (int nt=0;nt<4;nt++)
        acc[mt][nt] = __builtin_amdgcn_mfma_f32_16x16x32_bf16(af[mt], bf[nt], acc[mt][nt], 0,0,0);
  }
  #pragma unroll
  for (int mt=0;mt<4;mt++){
    #pragma unroll
    for (int nt=0;nt<4;nt++){
      int j = j0 + wn + nt*16 + lm;
      if (j < NPROJ){
        #pragma unroll
        for (int r=0;r<4;r++){
          int t = t0 + wm + mt*16 + lq*4 + r;
          ZX[t*NPROJ + j] = f2h(acc[mt][nt][r]);
        }
      }
    }
  }
}

// ---------------- K3a: causal depthwise conv1d K=4 + silu -> XB fp16 --------
__global__ __launch_bounds__(384) void k_conv(const u16* __restrict__ ZX, const float* __restrict__ cw,
                                              const float* __restrict__ cb, u16* __restrict__ XB){
  __shared__ u16 smc[35*384];
  int t0 = blockIdx.x*32;
  int tid = threadIdx.x;
  for (int idx=tid; idx<13440; idx+=384){
    int j = idx/384, chh = idx - j*384;
    int t = t0-3+j;
    smc[idx] = (t>=0)? ZX[t*NPROJ + 256 + chh] : (u16)0;
  }
  __syncthreads();
  int ch = tid;
  float w0=cw[ch*4], w1=cw[ch*4+1], w2=cw[ch*4+2], w3=cw[ch*4+3], bb=cb[ch];
  for (int i=0;i<32;i++){
    float acc = w0*h2f(smc[i*384+ch]) + w1*h2f(smc[(i+1)*384+ch])
              + w2*h2f(smc[(i+2)*384+ch]) + w3*h2f(smc[(i+3)*384+ch]) + bb;
    XB[(t0+i)*CCH + ch] = f2h(siluf_(acc));
  }
}

// ---------------- K3b: dt softplus + per-chunk cumsum (wave-parallel) -------
__global__ __launch_bounds__(256) void k_dtcum(const u16* __restrict__ ZX, const float* __restrict__ dtb,
                                               const float* __restrict__ Alog, float* __restrict__ DT,
                                               float* __restrict__ CUM, float* __restrict__ CDEC){
  int g = blockIdx.x*4 + (threadIdx.x>>6);  // 1024 (chunk,head) pairs
  int lane = threadIdx.x&63;
  int c = g>>2, h = g&3;
  float A = -__expf(Alog[h]);
  float bias = dtb[h];
  int t0 = c*CKL + lane*2;
  float x0 = h2f(ZX[t0*NPROJ + 640 + h]);
  float x1 = h2f(ZX[(t0+1)*NPROJ + 640 + h]);
  float d0 = softplusf_(x0+bias), d1 = softplusf_(x1+bias);
  DT[t0*4+h] = d0; DT[(t0+1)*4+h] = d1;
  float e0 = d0*A, e1 = d1*A;
  float s = e0+e1;
  #pragma unroll
  for (int off=1; off<64; off<<=1){
    float v = __shfl_up(s, off, 64);
    if (lane>=off) s += v;
  }
  CUM[t0*4+h] = s - e1;
  CUM[(t0+1)*4+h] = s;
  float tot = __shfl(s, 63, 64);
  if (lane==0) CDEC[c*4+h] = __expf(tot);
}

// ---------------- K4: per (chunk,head): CB + Y_intra + S, all MFMA ----------
__global__ __launch_bounds__(256) void k_chunk(const u16* __restrict__ XB, const float* __restrict__ DT,
                                               const float* __restrict__ CUM, const float* __restrict__ Dp,
                                               float* __restrict__ Y, float* __restrict__ ST){
  __shared__ u16 sh[35840];
  __shared__ float cum_s[128];
  u16* Cs   = sh;
  u16* Bsm  = sh + 9216;
  u16* Mh   = sh;
  u16* Xsh  = sh + 18432;
  u16* BdeT = sh + 27136;

  int bid = blockIdx.x; int c = bid>>2, h = bid&3;
  int tid = threadIdx.x, lane = tid&63, wid = tid>>6;
  int lm = lane&15, lq = lane>>4;

  // C/B staging: vector copies (XB fp16)
  for (int idx=tid; idx<1024; idx+=256){
    int t = idx>>3, b8 = idx&7;
    const u16* row = XB + (c*CKL+t)*CCH;
    *(uint4*)&Cs[t*72 + b8*8]  = *(const uint4*)(row + 320 + b8*8);
    *(uint4*)&Bsm[t*72 + b8*8] = *(const uint4*)(row + 256 + b8*8);
  }
  // xdt transpose staging
  for (int idx=tid; idx<8192; idx+=256){
    int t = idx>>6, n = idx&63;
    float xv = h2f(XB[(c*CKL+t)*CCH + h*64 + n]) * DT[(c*CKL+t)*4 + h];
    Xsh[n*136 + t] = f2h(xv);
  }
  if (tid<128) cum_s[tid] = CUM[(c*CKL+tid)*4 + h];
  __syncthreads();

  f32x4 cbac[2][8] = {};
  for (int kt=0; kt<2; kt++){
    half8 af[2], bfv[8];
    #pragma unroll
    for (int mt=0;mt<2;mt++) af[mt] = *(const half8*)&Cs[(wid*32+mt*16+lm)*72 + kt*32 + lq*8];
    #pragma unroll
    for (int nt=0;nt<8;nt++) bfv[nt] = *(const half8*)&Bsm[(nt*16+lm)*72 + kt*32 + lq*8];
    #pragma unroll
    for (int mt=0;mt<2;mt++)
      #pragma unroll
      for (int nt=0;nt<8;nt++)
        cbac[mt][nt] = __builtin_amdgcn_mfma_f32_16x16x32_f16(af[mt], bfv[nt], cbac[mt][nt], 0,0,0);
  }
  {
    float cl = cum_s[127];
    for (int idx=tid; idx<8192; idx+=256){
      int s = idx&127, n = idx>>7;
      float de = __expf(cl - cum_s[s]);
      BdeT[n*136+s] = f2h(h2f(Bsm[s*72+n]) * de);
    }
  }
  __syncthreads();
  #pragma unroll
  for (int mt=0;mt<2;mt++){
    int tb = wid*32 + mt*16;
    #pragma unroll
    for (int nt=0;nt<8;nt++){
      int s = nt*16 + lm;
      #pragma unroll
      for (int r=0;r<4;r++){
        int t = tb + lq*4 + r;
        float m = (s<=t)? cbac[mt][nt][r]*__expf(cum_s[t]-cum_s[s]) : 0.f;
        Mh[t*136+s] = f2h(m);
      }
    }
  }
  __syncthreads();

  f32x4 ya[2][4] = {};
  for (int kt=0; kt<4; kt++){
    half8 af[2], bfv[4];
    #pragma unroll
    for (int mt=0;mt<2;mt++) af[mt] = *(const half8*)&Mh[(wid*32+mt*16+lm)*136 + kt*32 + lq*8];
    #pragma unroll
    for (int nt=0;nt<4;nt++) bfv[nt] = *(const half8*)&Xsh[(nt*16+lm)*136 + kt*32 + lq*8];
    #pragma unroll
    for (int mt=0;mt<2;mt++)
      #pragma unroll
      for (int nt=0;nt<4;nt++)
        ya[mt][nt] = __builtin_amdgcn_mfma_f32_16x16x32_f16(af[mt], bfv[nt], ya[mt][nt], 0,0,0);
  }
  float dval = Dp[h];
  #pragma unroll
  for (int mt=0;mt<2;mt++){
    #pragma unroll
    for (int nt=0;nt<4;nt++){
      int p = nt*16 + lm;
      #pragma unroll
      for (int r=0;r<4;r++){
        int t = wid*32 + mt*16 + lq*4 + r;
        float xhv = h2f(XB[(c*CKL+t)*CCH + (h<<6) + p]);
        Y[((c*CKL+t)<<8) + (h<<6) + p] = ya[mt][nt][r] + dval*xhv;
      }
    }
  }

  f32x4 sa[4] = {};
  for (int kt=0; kt<4; kt++){
    half8 aa = *(const half8*)&Xsh[(wid*16+lm)*136 + kt*32 + lq*8];
    #pragma unroll
    for (int nt=0;nt<4;nt++){
      half8 bfv = *(const half8*)&BdeT[(nt*16+lm)*136 + kt*32 + lq*8];
      sa[nt] = __builtin_amdgcn_mfma_f32_16x16x32_f16(aa, bfv, sa[nt], 0,0,0);
    }
  }
  #pragma unroll
  for (int nt=0;nt<4;nt++){
    int n = nt*16 + lm;
    #pragma unroll
    for (int r=0;r<4;r++){
      int p = wid*16 + lq*4 + r;
      ST[((c*4+h)*64 + p)*64 + n] = sa[nt][r];
    }
  }
}

// ---------------- K5: chunk-state scan, out-of-place ------------------------
__global__ void k_scan(const float* __restrict__ ST, float* __restrict__ HP, const float* __restrict__ CDEC){
  int g = blockIdx.x*256 + threadIdx.x;
  int h = g>>12;
  float hp = 0.f;
  #pragma unroll 8
  for (int c=0;c<NCHK;c++){
    float dec = CDEC[(c<<2)+h];
    float sv = ST[g + (c<<14)];
    HP[g + (c<<14)] = hp;
    hp = dec*hp + sv;
  }
}

// ---------------- K6: Y += exp(cum[t,h]) * C·H^T  (fp16 MFMA, all heads) ----
__global__ __launch_bounds__(256) void k_inter(const u16* __restrict__ XB, const float* __restrict__ CUM,
                                               const float* __restrict__ HP, float* __restrict__ Y){
  __shared__ u16 Cs[128*72];
  __shared__ u16 Hs[4*64*72];
  __shared__ float ex_s[4*128];
  int c = blockIdx.x;
  int tid = threadIdx.x, lane = tid&63, wid = tid>>6;
  int lm = lane&15, lq = lane>>4;
  for (int idx=tid; idx<1024; idx+=256){
    int t = idx>>3, b8 = idx&7;
    *(uint4*)&Cs[t*72 + b8*8] = *(const uint4*)(XB + (c*CKL+t)*CCH + 320 + b8*8);
  }
  for (int idx=tid; idx<16384; idx+=256){
    int h = idx>>12, p = (idx>>6)&63, n = idx&63;
    Hs[(h*64+p)*72+n] = f2h(HP[((c*4+h)*64+p)*64+n]);
  }
  for (int idx=tid; idx<512; idx+=256){
    int h = idx>>7, t = idx&127;
    ex_s[h*128+t] = __expf(CUM[(c*CKL+t)*4+h]);
  }
  __syncthreads();
  int h = wid;
  const u16* Hh = &Hs[h*64*72];
  f32x4 acc[8][4] = {};
  for (int kt=0; kt<2; kt++){
    half8 af[8], bfv[4];
    #pragma unroll
    for (int mt=0;mt<8;mt++) af[mt] = *(const half8*)&Cs[(mt*16+lm)*72 + kt*32 + lq*8];
    #pragma unroll
    for (int nt=0;nt<4;nt++) bfv[nt] = *(const half8*)&Hh[(nt*16+lm)*72 + kt*32 + lq*8];
    #pragma unroll
    for (int mt=0;mt<8;mt++)
      #pragma unroll
      for (int nt=0;nt<4;nt++)
        acc[mt][nt] = __builtin_amdgcn_mfma_f32_16x16x32_f16(af[mt], bfv[nt], acc[mt][nt], 0,0,0);
  }
  #pragma unroll
  for (int mt=0;mt<8;mt++){
    #pragma unroll
    for (int r=0;r<4;r++){
      int t = mt*16 + lq*4 + r;
      float e = ex_s[h*128+t];
      float* dst = &Y[((c*CKL+t)<<8) + (h<<6)];
      #pragma unroll
      for (int nt=0;nt<4;nt++){
        int p = nt*16 + lm;
        dst[p] += e*acc[mt][nt][r];
      }
    }
  }
}

// ---------------- K7a: YH = fp16( rmsnorm(y*silu(z)) * normw ) --------------
__global__ void k_ynorm(const float* __restrict__ Y, const u16* __restrict__ ZX, const float* __restrict__ nw,
                        u16* __restrict__ YH){
  __shared__ float red[4];
  int t = blockIdx.x, i = threadIdx.x;
  float u = Y[t*DIN+i];
  float z = h2f(ZX[t*NPROJ+i]);
  u *= siluf_(z);
  float ss = u*u;
  #pragma unroll
  for (int off=32; off; off>>=1) ss += __shfl_down(ss, off, 64);
  int lane = i&63, w = i>>6;
  if (lane==0) red[w] = ss;
  __syncthreads();
  float tot = red[0]+red[1]+red[2]+red[3];
  float sc = rsqrtf(tot*(1.f/DIN)+1e-6f);
  YH[t*DIN+i] = f2h(u*sc*nw[i]);
}

// ---------------- K7b: out GEMM (fp16 MFMA) + gate scatter into GACC --------
__global__ __launch_bounds__(256) void k_gout_mfma(const u16* __restrict__ YH, const u16* __restrict__ WoT,
                                                   const float* __restrict__ G, float* __restrict__ GACC, int run){
  __shared__ u16 Ys[128*136];
  __shared__ u16 Ws[128*136];
  int t0 = blockIdx.x*128;
  int tid = threadIdx.x, lane = tid&63, wid = tid>>6;
  int lm = lane&15, lq = lane>>4;
  f32x4 acc[2][8] = {};
  for (int kb=0; kb<2; kb++){
    __syncthreads();
    for (int ch=tid; ch<2048; ch+=256){
      int row = ch>>4, c8 = ch&15;
      *(uint4*)&Ys[row*136 + c8*8] = *(const uint4*)(YH + (t0+row)*DIN + kb*128 + c8*8);
      *(uint4*)&Ws[row*136 + c8*8] = *(const uint4*)(WoT + row*DIN + kb*128 + c8*8);
    }
    __syncthreads();
    for (int kt=0; kt<4; kt++){
      half8 af[2], bfv[8];
      #pragma unroll
      for (int mt=0;mt<2;mt++) af[mt] = *(const half8*)&Ys[(wid*32+mt*16+lm)*136 + kt*32 + lq*8];
      #pragma unroll
      for (int nt=0;nt<8;nt++) bfv[nt] = *(const half8*)&Ws[(nt*16+lm)*136 + kt*32 + lq*8];
      #pragma unroll
      for (int mt=0;mt<2;mt++)
        #pragma unroll
        for (int nt=0;nt<8;nt++)
          acc[mt][nt] = __builtin_amdgcn_mfma_f32_16x16x32_f16(af[mt], bfv[nt], acc[mt][nt], 0,0,0);
    }
  }
  #pragma unroll
  for (int mt=0;mt<2;mt++){
    #pragma unroll
    for (int r=0;r<4;r++){
      int t = t0 + wid*32 + mt*16 + lq*4 + r;
      int sp = seq2sp(t, run);
      float g = G[run*LSEQ + sp];
      float* dst = &GACC[sp*CDIM];
      #pragma unroll
      for (int nt=0;nt<8;nt++){
        int cd = nt*16 + lm;
        dst[cd] += g*acc[mt][nt][r];
      }
    }
  }
}

// ---------------- K8: depthwise 3x3x3 conv ----------------------------------
__global__ void k_dwconv(const float* __restrict__ XN, const float* __restrict__ w, const float* __restrict__ b,
                         float* __restrict__ LC1){
  int idx = blockIdx.x*256 + threadIdx.x;
  int cc = idx>>15, s = idx&32767;
  int d = s>>10, hh=(s>>5)&31, ww=s&31;
  float acc = 0.f;
  for (int dz=-1;dz<=1;dz++){
    int nd = d+dz; if ((unsigned)nd>31u) continue;
    for (int dy=-1;dy<=1;dy++){
      int nh = hh+dy; if ((unsigned)nh>31u) continue;
      for (int dx=-1;dx<=1;dx++){
        int nw = ww+dx; if ((unsigned)nw>31u) continue;
        acc += w[cc*27 + (dz+1)*9 + (dy+1)*3 + (dx+1)] * XN[cc*LSEQ + (nd<<10)+(nh<<5)+nw];
      }
    }
  }
  LC1[idx] = acc + b[cc];
}

// ---------------- K9: pointwise 128x128 + silu (fp16 MFMA) ------------------
__global__ __launch_bounds__(256) void k_pw(const float* __restrict__ LC1, const float* __restrict__ pw,
                                            const float* __restrict__ pwb, float* __restrict__ LC2){
  __shared__ u16 Ws[128*136];   // W[o][c] fp16
  __shared__ u16 Bs[128*136];   // LC1^T [s][c] fp16
  int s0 = blockIdx.x*128;
  int tid = threadIdx.x, lane = tid&63, wid = tid>>6;
  int lm = lane&15, lq = lane>>4;
  for (int idx=tid; idx<16384; idx+=256){
    int o = idx>>7, cc = idx&127;
    Ws[o*136+cc] = f2h(pw[idx]);
  }
  for (int idx=tid; idx<16384; idx+=256){
    int cc = idx>>7, n = idx&127;
    Bs[n*136+cc] = f2h(LC1[cc*LSEQ + s0 + n]);
  }
  __syncthreads();
  f32x4 acc[2][8] = {};
  for (int kt=0; kt<4; kt++){
    half8 af[2], bfv[8];
    #pragma unroll
    for (int mt=0;mt<2;mt++) af[mt] = *(const half8*)&Ws[(wid*32+mt*16+lm)*136 + kt*32 + lq*8];
    #pragma unroll
    for (int nt=0;nt<8;nt++) bfv[nt] = *(const half8*)&Bs[(nt*16+lm)*136 + kt*32 + lq*8];
    #pragma unroll
    for (int mt=0;mt<2;mt++)
      #pragma unroll
      for (int nt=0;nt<8;nt++)
        acc[mt][nt] = __builtin_amdgcn_mfma_f32_16x16x32_f16(af[mt], bfv[nt], acc[mt][nt], 0,0,0);
  }
  #pragma unroll
  for (int mt=0;mt<2;mt++){
    #pragma unroll
    for (int r=0;r<4;r++){
      int o = wid*32 + mt*16 + lq*4 + r;
      float bb = pwb[o];
      float* dst = &LC2[o*LSEQ + s0];
      #pragma unroll
      for (int nt=0;nt<8;nt++){
        int n = nt*16 + lm;
        dst[n] = siluf_(acc[mt][nt][r] + bb);
      }
    }
  }
}

// ---------------- K10: fused = a*g + (1-a)*lc, transpose --------------------
__global__ void k_fuse(const float* __restrict__ GACC, const float* __restrict__ LC2,
                       const float* __restrict__ alpha, float* __restrict__ FUSED){
  __shared__ float tile[64*65];
  int bs = blockIdx.x>>1, bc = blockIdx.x&1;
  int s0 = bs*64, c0 = bc*64;
  int tid = threadIdx.x;
  float a = alpha[0];
  for (int idx=tid; idx<4096; idx+=256){
    int i = idx>>6, j = idx&63;
    tile[i*65+j] = GACC[(s0+i)*CDIM + c0+j];
  }
  __syncthreads();
  for (int idx=tid; idx<4096; idx+=256){
    int j = idx>>6, i = idx&63;
    float g = tile[i*65+j];
    float l = LC2[(c0+j)*LSEQ + s0+i];
    FUSED[(c0+j)*LSEQ + s0+i] = a*g + (1.f-a)*l;
  }
}

// ---------------- K_mean ----------------------------------------------------
__global__ void k_mean(const float* __restrict__ F, float* __restrict__ MEAN){
  __shared__ float red[4];
  int cc = blockIdx.x, tid = threadIdx.x;
  float acc = 0.f;
  for (int s=tid; s<LSEQ; s+=256) acc += F[cc*LSEQ + s];
  #pragma unroll
  for (int off=32; off; off>>=1) acc += __shfl_down(acc, off, 64);
  if ((tid&63)==0) red[tid>>6] = acc;
  __syncthreads();
  if (tid==0) MEAN[cc] = (red[0]+red[1]+red[2]+red[3])*(1.f/LSEQ);
}

// ---------------- K11: channel attention ------------------------------------
__global__ void k_ca(const float* __restrict__ MEAN, const float* __restrict__ w1, const float* __restrict__ b1,
                     const float* __restrict__ w2, const float* __restrict__ b2, float* __restrict__ SIG){
  __shared__ float y1[8];
  int tid = threadIdx.x;
  if (tid<8){
    float acc = b1[tid];
    for (int c=0;c<128;c++) acc += w1[tid*128+c]*MEAN[c];
    y1[tid] = (acc>=0.f)? acc : 0.1f*acc;
  }
  __syncthreads();
  float acc = b2[tid];
  #pragma unroll
  for (int o=0;o<8;o++) acc += w2[tid*8+o]*y1[o];
  SIG[tid] = sigmoidf_(acc);
}

// ---------------- K12: out = x + fused * sigmoid(yc) ------------------------
__global__ void k_final(const float* __restrict__ x, const float* __restrict__ F, const float* __restrict__ SIG,
                        float* __restrict__ out){
  int idx = blockIdx.x*256 + threadIdx.x;
  int cc = idx>>15;
  out[idx] = x[idx] + F[idx]*SIG[cc];
}

extern "C" void kernel_launch(void* const* d_in, const int* in_sizes, int n_in,
                              void* d_out, int out_size, void* d_ws, size_t ws_size,
                              hipStream_t stream){
  (void)in_sizes; (void)n_in; (void)out_size; (void)ws_size;
  const float* x       = (const float*)d_in[0];
  const float* norm_w  = (const float*)d_in[1];
  const float* gate_w  = (const float*)d_in[2];
  const float* gate_b  = (const float*)d_in[3];
  const float* loc_dw_w= (const float*)d_in[28];
  const float* loc_dw_b= (const float*)d_in[29];
  const float* loc_pw_w= (const float*)d_in[30];
  const float* loc_pw_b= (const float*)d_in[31];
  const float* ca_w1   = (const float*)d_in[32];
  const float* ca_b1   = (const float*)d_in[33];
  const float* ca_w2   = (const float*)d_in[34];
  const float* ca_b2   = (const float*)d_in[35];
  const float* alpha   = (const float*)d_in[36];

  float* W     = (float*)d_ws;
  float* XN    = W;                         // 4,194,304
  float* GATES = XN    + 4194304;           //   196,608
  float* GACC  = GATES + 196608;            // 4,194,304
  u16*   ZX    = (u16*)(GACC + 4194304);    // 21,102,592 u16 (10,551,296 fl)
  u16*   XB    = (u16*)(GACC + 4194304 + 10551296);  // 12,582,912 u16 (6,291,456 fl)
  float* DT    = GACC + 4194304 + 10551296 + 6291456; // 131,072
  float* CUM   = DT    + 131072;            //   131,072
  float* CDEC  = CUM   + 131072;            //     1,024
  float* ST    = CDEC  + 1024;              // 4,194,304 (aliased YH fp16)
  float* Y     = ST    + 4194304;           // 8,388,608
  float* LC1   = Y     + 8388608;           // 4,194,304 (aliased HPREV)
  float* LC2   = LC1   + 4194304;           // 4,194,304
  float* MEAN  = LC2   + 4194304;           //       128
  float* SIG   = MEAN  + 128;               //       128
  u16*   XNT   = (u16*)(SIG + 128);         // 4,194,304 u16
  u16*   WinT  = XNT + 4194304;             //    98,304 u16
  u16*   WoT   = WinT + 98304;              //    32,768 u16
  u16*   YH    = (u16*)ST;
  float* HPREV = LC1;

  hipMemsetAsync(GACC, 0, 4194304*sizeof(float), stream);
  k_xn   <<<128,256,0,stream>>>(x, norm_w, XN);
  k_gates<<<128,256,0,stream>>>(XN, gate_w, gate_b, GATES);

  for (int r=0;r<6;r++){
    int m = r>>1;
    const float* Win   = (const float*)d_in[4 + m*8 + 0];
    const float* convw = (const float*)d_in[4 + m*8 + 1];
    const float* convb = (const float*)d_in[4 + m*8 + 2];
    const float* dtb   = (const float*)d_in[4 + m*8 + 3];
    const float* Alog  = (const float*)d_in[4 + m*8 + 4];
    const float* Dp    = (const float*)d_in[4 + m*8 + 5];
    const float* nw2   = (const float*)d_in[4 + m*8 + 6];
    const float* Wout  = (const float*)d_in[4 + m*8 + 7];
    if ((r&1)==0){
      k_permute<<<1024,256,0,stream>>>(XN, XNT, m);
      k_prepw  <<<384,256,0,stream>>>(Win, WinT);
      k_prewo  <<<128,256,0,stream>>>(Wout, WoT);
    }
    k_gin_mfma<<<dim3(6,256),256,0,stream>>>(XNT, WinT, ZX, r&1);
    k_conv    <<<1024,384,0,stream>>>(ZX, convw, convb, XB);
    k_dtcum   <<<256,256,0,stream>>>(ZX, dtb, Alog, DT, CUM, CDEC);
    k_chunk   <<<1024,256,0,stream>>>(XB, DT, CUM, Dp, Y, ST);
    k_scan    <<<64,256,0,stream>>>(ST, HPREV, CDEC);
    k_inter   <<<256,256,0,stream>>>(XB, CUM, HPREV, Y);
    k_ynorm   <<<32768,256,0,stream>>>(Y, ZX, nw2, YH);
    k_gout_mfma<<<256,256,0,stream>>>(YH, WoT, GATES, GACC, r);
  }

  k_dwconv<<<16384,256,0,stream>>>(XN, loc_dw_w, loc_dw_b, LC1);
  k_pw    <<<256,256,0,stream>>>(LC1, loc_pw_w, loc_pw_b, LC2);
  k_fuse  <<<1024,256,0,stream>>>(GACC, LC2, alpha, LC1);
  k_mean  <<<128,256,0,stream>>>(LC1, MEAN);
  k_ca    <<<1,128,0,stream>>>(MEAN, ca_w1, ca_b1, ca_w2, ca_b2, SIG);
  k_final <<<16384,256,0,stream>>>(x, LC1, SIG, (float*)d_out);
}

// Round 7
// 1152.381 us; speedup vs baseline: 4.0711x; 1.1271x over previous
//
#include <hip/hip_runtime.h>

// OmniMambaBlock — round 7: LDS-tiled dwconv, fp16 Y streams, wave ynorm.

typedef unsigned short u16;
typedef unsigned int   u32;
typedef __attribute__((ext_vector_type(8))) short short8;      // bf16x8
typedef __attribute__((ext_vector_type(8))) _Float16 half8;    // fp16x8
typedef __attribute__((ext_vector_type(4))) float f32x4;

#define LSEQ 32768
#define CDIM 128
#define NPROJ 644
#define CCH 384
#define DIN 256
#define NHD 4
#define CKL 128
#define NCHK 256

__device__ __forceinline__ float b2f(u16 u){ u32 x=((u32)u)<<16; float f; __builtin_memcpy(&f,&x,4); return f; }
__device__ __forceinline__ u16 f2b(float f){ u32 x; __builtin_memcpy(&x,&f,4); x += 0x7fffu + ((x>>16)&1u); return (u16)(x>>16); }
__device__ __forceinline__ u16 f2h(float v){ _Float16 h=(_Float16)v; u16 b; __builtin_memcpy(&b,&h,2); return b; }
__device__ __forceinline__ float h2f(u16 b){ _Float16 h; __builtin_memcpy(&h,&b,2); return (float)h; }
__device__ __forceinline__ void up4(uint2 v, float* o){
  union { uint2 u; _Float16 h[4]; } c; c.u = v;
  o[0]=(float)c.h[0]; o[1]=(float)c.h[1]; o[2]=(float)c.h[2]; o[3]=(float)c.h[3];
}
__device__ __forceinline__ uint2 pk4(const float* o){
  union { uint2 u; _Float16 h[4]; } c;
  c.h[0]=(_Float16)o[0]; c.h[1]=(_Float16)o[1]; c.h[2]=(_Float16)o[2]; c.h[3]=(_Float16)o[3];
  return c.u;
}
__device__ __forceinline__ float sigmoidf_(float v){ return 1.f/(1.f+__expf(-v)); }
__device__ __forceinline__ float siluf_(float v){ return v*sigmoidf_(v); }
__device__ __forceinline__ float softplusf_(float v){ return (v>20.f)? v : log1pf(__expf(v)); }

__device__ __forceinline__ int seq2sp(int t, int run){
  int te = (run&1) ? (LSEQ-1-t) : t;
  int a = te>>10, b=(te>>5)&31, c=te&31;
  int d,h,w;
  switch(run>>1){
    case 0: d=a; h=b; w=c; break;
    case 1: h=a; d=b; w=c; break;
    default: w=a; d=b; h=c; break;
  }
  return (d<<10)|(h<<5)|w;
}

// ---------------- K1: xn = rmsnorm(x, norm_w), layout (c,s) -----------------
__global__ void k_xn(const float* __restrict__ x, const float* __restrict__ nw, float* __restrict__ XN){
  int s = blockIdx.x*256 + threadIdx.x;
  float ss = 0.f;
  #pragma unroll 8
  for (int c=0;c<CDIM;c++){ float v=x[c*LSEQ+s]; ss += v*v; }
  float sc = rsqrtf(ss*(1.f/CDIM)+1e-6f);
  #pragma unroll 8
  for (int c=0;c<CDIM;c++){ XN[c*LSEQ+s] = x[c*LSEQ+s]*sc*nw[c]; }
}

// ---------------- K1b: gates softmax, layout (j,s) --------------------------
__global__ void k_gates(const float* __restrict__ XN, const float* __restrict__ gw, const float* __restrict__ gb, float* __restrict__ G){
  int s = blockIdx.x*256 + threadIdx.x;
  float a[6];
  #pragma unroll
  for (int j=0;j<6;j++) a[j]=gb[j];
  for (int c=0;c<CDIM;c++){
    float v = XN[c*LSEQ+s];
    #pragma unroll
    for (int j=0;j<6;j++) a[j] += v*gw[c*6+j];
  }
  float m=a[0];
  #pragma unroll
  for (int j=1;j<6;j++) m = fmaxf(m,a[j]);
  float e[6], ssum=0.f;
  #pragma unroll
  for (int j=0;j<6;j++){ e[j]=__expf(a[j]-m); ssum+=e[j]; }
  float inv = 1.f/ssum;
  #pragma unroll
  for (int j=0;j<6;j++) G[j*LSEQ+s] = e[j]*inv;
}

// ---------------- K_perm: XNT[t][c] bf16, sequence-ordered ------------------
__global__ __launch_bounds__(256) void k_permute(const float* __restrict__ XN, u16* __restrict__ XNT, int dir){
  __shared__ u16 TS[128*34];
  int a = blockIdx.x>>5, b = blockIdx.x&31;
  int tid = threadIdx.x;
  int spa = (dir==1)? b : a;
  int spb = (dir==1)? a : b;
  int spbase = spa*1024 + spb*32;
  for (int idx=tid; idx<4096; idx+=256){
    int c = idx>>5, i = idx&31;
    TS[c*34+i] = f2b(XN[c*LSEQ + spbase + i]);
  }
  __syncthreads();
  for (int idx=tid; idx<4096; idx+=256){
    int i = idx>>7, c = idx&127;
    int t = (dir==2) ? (i*1024 + a*32 + b) : (a*1024 + b*32 + i);
    XNT[t*128 + c] = TS[c*34+i];
  }
}

// ---------------- K_prepw: WinT[j][k] bf16, j padded to 768 -----------------
__global__ void k_prepw(const float* __restrict__ Win, u16* __restrict__ WinT){
  int idx = blockIdx.x*256 + threadIdx.x;
  int j = idx>>7, k = idx&127;
  float v = (j<NPROJ)? Win[k*NPROJ + j] : 0.f;
  WinT[idx] = f2b(v);
}

// ---------------- K_prewo: WoT[c][k] fp16 (Wout transposed) -----------------
__global__ void k_prewo(const float* __restrict__ Wout, u16* __restrict__ WoT){
  int idx = blockIdx.x*256 + threadIdx.x;
  int c = idx>>8, k = idx&255;
  WoT[idx] = f2h(Wout[k*CDIM + c]);
}

// ---------------- K2: ZX[t,j] = XNT[t,:]·WinT[j,:]  (bf16 MFMA, fp16 out) ---
__global__ __launch_bounds__(256) void k_gin_mfma(const u16* __restrict__ XNT, const u16* __restrict__ WinT,
                                                  u16* __restrict__ ZX, int flip){
  __shared__ u16 Asb[128*136];
  __shared__ u16 Bsb[128*136];
  int j0 = blockIdx.x*128, t0 = blockIdx.y*128;
  int tid = threadIdx.x;
  for (int ch = tid; ch < 2048; ch += 256){
    int row = ch>>4, c8 = ch&15;
    int tg = flip ? (LSEQ-1-(t0+row)) : (t0+row);
    uint4 av = *(const uint4*)(XNT + tg*128 + c8*8);
    *(uint4*)(&Asb[row*136 + c8*8]) = av;
    uint4 bv = *(const uint4*)(WinT + (j0+row)*128 + c8*8);
    *(uint4*)(&Bsb[row*136 + c8*8]) = bv;
  }
  __syncthreads();
  int lane = tid&63, wid = tid>>6;
  int wm = (wid>>1)*64, wn = (wid&1)*64;
  int lm = lane&15, lq = lane>>4;
  f32x4 acc[4][4] = {};
  for (int kt=0; kt<4; kt++){
    short8 af[4], bf[4];
    #pragma unroll
    for (int mt=0;mt<4;mt++) af[mt] = *(const short8*)(&Asb[(wm+mt*16+lm)*136 + kt*32 + lq*8]);
    #pragma unroll
    for (int nt=0;nt<4;nt++) bf[nt] = *(const short8*)(&Bsb[(wn+nt*16+lm)*136 + kt*32 + lq*8]);
    #pragma unroll
    for (int mt=0;mt<4;mt++)
      #pragma unroll
      for (int nt=0;nt<4;nt++)
        acc[mt][nt] = __builtin_amdgcn_mfma_f32_16x16x32_bf16(af[mt], bf[nt], acc[mt][nt], 0,0,0);
  }
  #pragma unroll
  for (int mt=0;mt<4;mt++){
    #pragma unroll
    for (int nt=0;nt<4;nt++){
      int j = j0 + wn + nt*16 + lm;
      if (j < NPROJ){
        #pragma unroll
        for (int r=0;r<4;r++){
          int t = t0 + wm + mt*16 + lq*4 + r;
          ZX[t*NPROJ + j] = f2h(acc[mt][nt][r]);
        }
      }
    }
  }
}

// ---------------- K3a: causal depthwise conv1d K=4 + silu -> XB fp16 --------
__global__ __launch_bounds__(384) void k_conv(const u16* __restrict__ ZX, const float* __restrict__ cw,
                                              const float* __restrict__ cb, u16* __restrict__ XB){
  __shared__ u16 smc[35*384];
  int t0 = blockIdx.x*32;
  int tid = threadIdx.x;
  for (int idx=tid; idx<13440; idx+=384){
    int j = idx/384, chh = idx - j*384;
    int t = t0-3+j;
    smc[idx] = (t>=0)? ZX[t*NPROJ + 256 + chh] : (u16)0;
  }
  __syncthreads();
  int ch = tid;
  float w0=cw[ch*4], w1=cw[ch*4+1], w2=cw[ch*4+2], w3=cw[ch*4+3], bb=cb[ch];
  for (int i=0;i<32;i++){
    float acc = w0*h2f(smc[i*384+ch]) + w1*h2f(smc[(i+1)*384+ch])
              + w2*h2f(smc[(i+2)*384+ch]) + w3*h2f(smc[(i+3)*384+ch]) + bb;
    XB[(t0+i)*CCH + ch] = f2h(siluf_(acc));
  }
}

// ---------------- K3b: dt softplus + per-chunk cumsum (wave-parallel) -------
__global__ __launch_bounds__(256) void k_dtcum(const u16* __restrict__ ZX, const float* __restrict__ dtb,
                                               const float* __restrict__ Alog, float* __restrict__ DT,
                                               float* __restrict__ CUM, float* __restrict__ CDEC){
  int g = blockIdx.x*4 + (threadIdx.x>>6);
  int lane = threadIdx.x&63;
  int c = g>>2, h = g&3;
  float A = -__expf(Alog[h]);
  float bias = dtb[h];
  int t0 = c*CKL + lane*2;
  float x0 = h2f(ZX[t0*NPROJ + 640 + h]);
  float x1 = h2f(ZX[(t0+1)*NPROJ + 640 + h]);
  float d0 = softplusf_(x0+bias), d1 = softplusf_(x1+bias);
  DT[t0*4+h] = d0; DT[(t0+1)*4+h] = d1;
  float e0 = d0*A, e1 = d1*A;
  float s = e0+e1;
  #pragma unroll
  for (int off=1; off<64; off<<=1){
    float v = __shfl_up(s, off, 64);
    if (lane>=off) s += v;
  }
  CUM[t0*4+h] = s - e1;
  CUM[(t0+1)*4+h] = s;
  float tot = __shfl(s, 63, 64);
  if (lane==0) CDEC[c*4+h] = __expf(tot);
}

// ---------------- K4: per (chunk,head): CB + Y_intra + S, all MFMA ----------
__global__ __launch_bounds__(256) void k_chunk(const u16* __restrict__ XB, const float* __restrict__ DT,
                                               const float* __restrict__ CUM, const float* __restrict__ Dp,
                                               u16* __restrict__ YA, float* __restrict__ ST){
  __shared__ u16 sh[35840];
  __shared__ float cum_s[128];
  u16* Cs   = sh;
  u16* Bsm  = sh + 9216;
  u16* Mh   = sh;
  u16* Xsh  = sh + 18432;
  u16* BdeT = sh + 27136;

  int bid = blockIdx.x; int c = bid>>2, h = bid&3;
  int tid = threadIdx.x, lane = tid&63, wid = tid>>6;
  int lm = lane&15, lq = lane>>4;

  for (int idx=tid; idx<1024; idx+=256){
    int t = idx>>3, b8 = idx&7;
    const u16* row = XB + (c*CKL+t)*CCH;
    *(uint4*)&Cs[t*72 + b8*8]  = *(const uint4*)(row + 320 + b8*8);
    *(uint4*)&Bsm[t*72 + b8*8] = *(const uint4*)(row + 256 + b8*8);
  }
  for (int idx=tid; idx<8192; idx+=256){
    int t = idx>>6, n = idx&63;
    float xv = h2f(XB[(c*CKL+t)*CCH + h*64 + n]) * DT[(c*CKL+t)*4 + h];
    Xsh[n*136 + t] = f2h(xv);
  }
  if (tid<128) cum_s[tid] = CUM[(c*CKL+tid)*4 + h];
  __syncthreads();

  f32x4 cbac[2][8] = {};
  for (int kt=0; kt<2; kt++){
    half8 af[2], bfv[8];
    #pragma unroll
    for (int mt=0;mt<2;mt++) af[mt] = *(const half8*)&Cs[(wid*32+mt*16+lm)*72 + kt*32 + lq*8];
    #pragma unroll
    for (int nt=0;nt<8;nt++) bfv[nt] = *(const half8*)&Bsm[(nt*16+lm)*72 + kt*32 + lq*8];
    #pragma unroll
    for (int mt=0;mt<2;mt++)
      #pragma unroll
      for (int nt=0;nt<8;nt++)
        cbac[mt][nt] = __builtin_amdgcn_mfma_f32_16x16x32_f16(af[mt], bfv[nt], cbac[mt][nt], 0,0,0);
  }
  {
    float cl = cum_s[127];
    for (int idx=tid; idx<8192; idx+=256){
      int s = idx&127, n = idx>>7;
      float de = __expf(cl - cum_s[s]);
      BdeT[n*136+s] = f2h(h2f(Bsm[s*72+n]) * de);
    }
  }
  __syncthreads();
  #pragma unroll
  for (int mt=0;mt<2;mt++){
    int tb = wid*32 + mt*16;
    #pragma unroll
    for (int nt=0;nt<8;nt++){
      int s = nt*16 + lm;
      #pragma unroll
      for (int r=0;r<4;r++){
        int t = tb + lq*4 + r;
        float m = (s<=t)? cbac[mt][nt][r]*__expf(cum_s[t]-cum_s[s]) : 0.f;
        Mh[t*136+s] = f2h(m);
      }
    }
  }
  __syncthreads();

  f32x4 ya[2][4] = {};
  for (int kt=0; kt<4; kt++){
    half8 af[2], bfv[4];
    #pragma unroll
    for (int mt=0;mt<2;mt++) af[mt] = *(const half8*)&Mh[(wid*32+mt*16+lm)*136 + kt*32 + lq*8];
    #pragma unroll
    for (int nt=0;nt<4;nt++) bfv[nt] = *(const half8*)&Xsh[(nt*16+lm)*136 + kt*32 + lq*8];
    #pragma unroll
    for (int mt=0;mt<2;mt++)
      #pragma unroll
      for (int nt=0;nt<4;nt++)
        ya[mt][nt] = __builtin_amdgcn_mfma_f32_16x16x32_f16(af[mt], bfv[nt], ya[mt][nt], 0,0,0);
  }
  float dval = Dp[h];
  #pragma unroll
  for (int mt=0;mt<2;mt++){
    #pragma unroll
    for (int nt=0;nt<4;nt++){
      int p = nt*16 + lm;
      #pragma unroll
      for (int r=0;r<4;r++){
        int t = wid*32 + mt*16 + lq*4 + r;
        float xhv = h2f(XB[(c*CKL+t)*CCH + (h<<6) + p]);
        YA[((c*CKL+t)<<8) + (h<<6) + p] = f2h(ya[mt][nt][r] + dval*xhv);
      }
    }
  }

  f32x4 sa[4] = {};
  for (int kt=0; kt<4; kt++){
    half8 aa = *(const half8*)&Xsh[(wid*16+lm)*136 + kt*32 + lq*8];
    #pragma unroll
    for (int nt=0;nt<4;nt++){
      half8 bfv = *(const half8*)&BdeT[(nt*16+lm)*136 + kt*32 + lq*8];
      sa[nt] = __builtin_amdgcn_mfma_f32_16x16x32_f16(aa, bfv, sa[nt], 0,0,0);
    }
  }
  #pragma unroll
  for (int nt=0;nt<4;nt++){
    int n = nt*16 + lm;
    #pragma unroll
    for (int r=0;r<4;r++){
      int p = wid*16 + lq*4 + r;
      ST[((c*4+h)*64 + p)*64 + n] = sa[nt][r];
    }
  }
}

// ---------------- K5: chunk-state scan, out-of-place ------------------------
__global__ void k_scan(const float* __restrict__ ST, float* __restrict__ HP, const float* __restrict__ CDEC){
  int g = blockIdx.x*256 + threadIdx.x;
  int h = g>>12;
  float hp = 0.f;
  #pragma unroll 8
  for (int c=0;c<NCHK;c++){
    float dec = CDEC[(c<<2)+h];
    float sv = ST[g + (c<<14)];
    HP[g + (c<<14)] = hp;
    hp = dec*hp + sv;
  }
}

// ---------------- K6: YB = exp(cum[t,h]) * C·H^T  (fp16 MFMA, all heads) ----
__global__ __launch_bounds__(256) void k_inter(const u16* __restrict__ XB, const float* __restrict__ CUM,
                                               const float* __restrict__ HP, u16* __restrict__ YB){
  __shared__ u16 Cs[128*72];
  __shared__ u16 Hs[4*64*72];
  __shared__ float ex_s[4*128];
  int c = blockIdx.x;
  int tid = threadIdx.x, lane = tid&63, wid = tid>>6;
  int lm = lane&15, lq = lane>>4;
  for (int idx=tid; idx<1024; idx+=256){
    int t = idx>>3, b8 = idx&7;
    *(uint4*)&Cs[t*72 + b8*8] = *(const uint4*)(XB + (c*CKL+t)*CCH + 320 + b8*8);
  }
  for (int idx=tid; idx<16384; idx+=256){
    int h = idx>>12, p = (idx>>6)&63, n = idx&63;
    Hs[(h*64+p)*72+n] = f2h(HP[((c*4+h)*64+p)*64+n]);
  }
  for (int idx=tid; idx<512; idx+=256){
    int h = idx>>7, t = idx&127;
    ex_s[h*128+t] = __expf(CUM[(c*CKL+t)*4+h]);
  }
  __syncthreads();
  int h = wid;
  const u16* Hh = &Hs[h*64*72];
  f32x4 acc[8][4] = {};
  for (int kt=0; kt<2; kt++){
    half8 af[8], bfv[4];
    #pragma unroll
    for (int mt=0;mt<8;mt++) af[mt] = *(const half8*)&Cs[(mt*16+lm)*72 + kt*32 + lq*8];
    #pragma unroll
    for (int nt=0;nt<4;nt++) bfv[nt] = *(const half8*)&Hh[(nt*16+lm)*72 + kt*32 + lq*8];
    #pragma unroll
    for (int mt=0;mt<8;mt++)
      #pragma unroll
      for (int nt=0;nt<4;nt++)
        acc[mt][nt] = __builtin_amdgcn_mfma_f32_16x16x32_f16(af[mt], bfv[nt], acc[mt][nt], 0,0,0);
  }
  #pragma unroll
  for (int mt=0;mt<8;mt++){
    #pragma unroll
    for (int r=0;r<4;r++){
      int t = mt*16 + lq*4 + r;
      float e = ex_s[h*128+t];
      u16* dst = &YB[((c*CKL+t)<<8) + (h<<6)];
      #pragma unroll
      for (int nt=0;nt<4;nt++){
        int p = nt*16 + lm;
        dst[p] = f2h(e*acc[mt][nt][r]);
      }
    }
  }
}

// ---------------- K7a: YH = fp16( rmsnorm((ya+yb)*silu(z)) * normw ) --------
__global__ __launch_bounds__(256) void k_ynorm(const u16* __restrict__ YA, const u16* __restrict__ YB,
                                               const u16* __restrict__ ZX, const float* __restrict__ nw,
                                               u16* __restrict__ YH){
  int t = blockIdx.x*4 + (threadIdx.x>>6);
  int lane = threadIdx.x&63;
  float a[4], b[4], z[4], u[4];
  up4(*(const uint2*)(YA + t*DIN + lane*4), a);
  up4(*(const uint2*)(YB + t*DIN + lane*4), b);
  up4(*(const uint2*)(ZX + t*NPROJ + lane*4), z);
  float4 w = *(const float4*)(nw + lane*4);
  float ss = 0.f;
  #pragma unroll
  for (int j=0;j<4;j++){ u[j] = (a[j]+b[j])*siluf_(z[j]); ss += u[j]*u[j]; }
  #pragma unroll
  for (int off=32; off; off>>=1) ss += __shfl_xor(ss, off, 64);
  float sc = rsqrtf(ss*(1.f/DIN)+1e-6f);
  float o[4] = { u[0]*sc*w.x, u[1]*sc*w.y, u[2]*sc*w.z, u[3]*sc*w.w };
  *(uint2*)(YH + t*DIN + lane*4) = pk4(o);
}

// ---------------- K7b: out GEMM (fp16 MFMA) + gate scatter into GACC --------
__global__ __launch_bounds__(256) void k_gout_mfma(const u16* __restrict__ YH, const u16* __restrict__ WoT,
                                                   const float* __restrict__ G, float* __restrict__ GACC, int run){
  __shared__ u16 Ys[128*136];
  __shared__ u16 Ws[128*136];
  int t0 = blockIdx.x*128;
  int tid = threadIdx.x, lane = tid&63, wid = tid>>6;
  int lm = lane&15, lq = lane>>4;
  f32x4 acc[2][8] = {};
  for (int kb=0; kb<2; kb++){
    __syncthreads();
    for (int ch=tid; ch<2048; ch+=256){
      int row = ch>>4, c8 = ch&15;
      *(uint4*)&Ys[row*136 + c8*8] = *(const uint4*)(YH + (t0+row)*DIN + kb*128 + c8*8);
      *(uint4*)&Ws[row*136 + c8*8] = *(const uint4*)(WoT + row*DIN + kb*128 + c8*8);
    }
    __syncthreads();
    for (int kt=0; kt<4; kt++){
      half8 af[2], bfv[8];
      #pragma unroll
      for (int mt=0;mt<2;mt++) af[mt] = *(const half8*)&Ys[(wid*32+mt*16+lm)*136 + kt*32 + lq*8];
      #pragma unroll
      for (int nt=0;nt<8;nt++) bfv[nt] = *(const half8*)&Ws[(nt*16+lm)*136 + kt*32 + lq*8];
      #pragma unroll
      for (int mt=0;mt<2;mt++)
        #pragma unroll
        for (int nt=0;nt<8;nt++)
          acc[mt][nt] = __builtin_amdgcn_mfma_f32_16x16x32_f16(af[mt], bfv[nt], acc[mt][nt], 0,0,0);
    }
  }
  #pragma unroll
  for (int mt=0;mt<2;mt++){
    #pragma unroll
    for (int r=0;r<4;r++){
      int t = t0 + wid*32 + mt*16 + lq*4 + r;
      int sp = seq2sp(t, run);
      float g = G[run*LSEQ + sp];
      float* dst = &GACC[sp*CDIM];
      #pragma unroll
      for (int nt=0;nt<8;nt++){
        int cd = nt*16 + lm;
        dst[cd] += g*acc[mt][nt][r];
      }
    }
  }
}

// ---------------- K8: depthwise 3x3x3 conv, LDS-tiled -----------------------
// block = (cc, d). 3 planes in LDS, zero-padded: row stride 40, col offset 4.
__global__ __launch_bounds__(256) void k_dwconv(const float* __restrict__ XN, const float* __restrict__ w,
                                                const float* __restrict__ b, float* __restrict__ LC1){
  __shared__ float sm[3*34*40];   // 4080 floats
  int cc = blockIdx.x>>5, d = blockIdx.x&31;
  int tid = threadIdx.x;
  for (int i=tid; i<4080; i+=256) sm[i] = 0.f;
  __syncthreads();
  #pragma unroll
  for (int p=0;p<3;p++){
    int dz = d-1+p;
    if ((unsigned)dz<=31u){
      for (int idx=tid; idx<1024; idx+=256){
        int hh = idx>>5, ww = idx&31;
        sm[p*1360 + (hh+1)*40 + (ww+4)] = XN[cc*LSEQ + (dz<<10) + idx];
      }
    }
  }
  __syncthreads();
  float wreg[27];
  #pragma unroll
  for (int i=0;i<27;i++) wreg[i] = w[cc*27+i];
  float bias = b[cc];
  int h = tid>>3, w0 = (tid&7)*4;
  float4 acc = {bias,bias,bias,bias};
  #pragma unroll
  for (int p=0;p<3;p++){
    #pragma unroll
    for (int dy=0;dy<3;dy++){
      const float* row = &sm[p*1360 + (h+dy)*40 + 4];
      float left  = row[w0-1];
      float4 mid  = *(const float4*)&row[w0];
      float right = row[w0+4];
      float wa=wreg[p*9+dy*3+0], wb=wreg[p*9+dy*3+1], wc=wreg[p*9+dy*3+2];
      acc.x += wa*left  + wb*mid.x + wc*mid.y;
      acc.y += wa*mid.x + wb*mid.y + wc*mid.z;
      acc.z += wa*mid.y + wb*mid.z + wc*mid.w;
      acc.w += wa*mid.z + wb*mid.w + wc*right;
    }
  }
  *(float4*)&LC1[cc*LSEQ + (d<<10) + h*32 + w0] = acc;
}

// ---------------- K9: pointwise 128x128 + silu (fp16 MFMA) ------------------
__global__ __launch_bounds__(256) void k_pw(const float* __restrict__ LC1, const float* __restrict__ pw,
                                            const float* __restrict__ pwb, float* __restrict__ LC2){
  __shared__ u16 Ws[128*136];
  __shared__ u16 Bs[128*136];
  int s0 = blockIdx.x*128;
  int tid = threadIdx.x, lane = tid&63, wid = tid>>6;
  int lm = lane&15, lq = lane>>4;
  for (int idx=tid; idx<16384; idx+=256){
    int o = idx>>7, cc = idx&127;
    Ws[o*136+cc] = f2h(pw[idx]);
  }
  for (int idx=tid; idx<16384; idx+=256){
    int cc = idx>>7, n = idx&127;
    Bs[n*136+cc] = f2h(LC1[cc*LSEQ + s0 + n]);
  }
  __syncthreads();
  f32x4 acc[2][8] = {};
  for (int kt=0; kt<4; kt++){
    half8 af[2], bfv[8];
    #pragma unroll
    for (int mt=0;mt<2;mt++) af[mt] = *(const half8*)&Ws[(wid*32+mt*16+lm)*136 + kt*32 + lq*8];
    #pragma unroll
    for (int nt=0;nt<8;nt++) bfv[nt] = *(const half8*)&Bs[(nt*16+lm)*136 + kt*32 + lq*8];
    #pragma unroll
    for (int mt=0;mt<2;mt++)
      #pragma unroll
      for (int nt=0;nt<8;nt++)
        acc[mt][nt] = __builtin_amdgcn_mfma_f32_16x16x32_f16(af[mt], bfv[nt], acc[mt][nt], 0,0,0);
  }
  #pragma unroll
  for (int mt=0;mt<2;mt++){
    #pragma unroll
    for (int r=0;r<4;r++){
      int o = wid*32 + mt*16 + lq*4 + r;
      float bb = pwb[o];
      float* dst = &LC2[o*LSEQ + s0];
      #pragma unroll
      for (int nt=0;nt<8;nt++){
        int n = nt*16 + lm;
        dst[n] = siluf_(acc[mt][nt][r] + bb);
      }
    }
  }
}

// ---------------- K10: fused = a*g + (1-a)*lc, transpose --------------------
__global__ void k_fuse(const float* __restrict__ GACC, const float* __restrict__ LC2,
                       const float* __restrict__ alpha, float* __restrict__ FUSED){
  __shared__ float tile[64*65];
  int bs = blockIdx.x>>1, bc = blockIdx.x&1;
  int s0 = bs*64, c0 = bc*64;
  int tid = threadIdx.x;
  float a = alpha[0];
  for (int idx=tid; idx<4096; idx+=256){
    int i = idx>>6, j = idx&63;
    tile[i*65+j] = GACC[(s0+i)*CDIM + c0+j];
  }
  __syncthreads();
  for (int idx=tid; idx<4096; idx+=256){
    int j = idx>>6, i = idx&63;
    float g = tile[i*65+j];
    float l = LC2[(c0+j)*LSEQ + s0+i];
    FUSED[(c0+j)*LSEQ + s0+i] = a*g + (1.f-a)*l;
  }
}

// ---------------- K_mean ----------------------------------------------------
__global__ void k_mean(const float* __restrict__ F, float* __restrict__ MEAN){
  __shared__ float red[4];
  int cc = blockIdx.x, tid = threadIdx.x;
  float acc = 0.f;
  for (int s=tid; s<LSEQ; s+=256) acc += F[cc*LSEQ + s];
  #pragma unroll
  for (int off=32; off; off>>=1) acc += __shfl_down(acc, off, 64);
  if ((tid&63)==0) red[tid>>6] = acc;
  __syncthreads();
  if (tid==0) MEAN[cc] = (red[0]+red[1]+red[2]+red[3])*(1.f/LSEQ);
}

// ---------------- K11: channel attention ------------------------------------
__global__ void k_ca(const float* __restrict__ MEAN, const float* __restrict__ w1, const float* __restrict__ b1,
                     const float* __restrict__ w2, const float* __restrict__ b2, float* __restrict__ SIG){
  __shared__ float y1[8];
  int tid = threadIdx.x;
  if (tid<8){
    float acc = b1[tid];
    for (int c=0;c<128;c++) acc += w1[tid*128+c]*MEAN[c];
    y1[tid] = (acc>=0.f)? acc : 0.1f*acc;
  }
  __syncthreads();
  float acc = b2[tid];
  #pragma unroll
  for (int o=0;o<8;o++) acc += w2[tid*8+o]*y1[o];
  SIG[tid] = sigmoidf_(acc);
}

// ---------------- K12: out = x + fused * sigmoid(yc) ------------------------
__global__ void k_final(const float* __restrict__ x, const float* __restrict__ F, const float* __restrict__ SIG,
                        float* __restrict__ out){
  int idx = blockIdx.x*256 + threadIdx.x;
  int cc = idx>>15;
  out[idx] = x[idx] + F[idx]*SIG[cc];
}

extern "C" void kernel_launch(void* const* d_in, const int* in_sizes, int n_in,
                              void* d_out, int out_size, void* d_ws, size_t ws_size,
                              hipStream_t stream){
  (void)in_sizes; (void)n_in; (void)out_size; (void)ws_size;
  const float* x       = (const float*)d_in[0];
  const float* norm_w  = (const float*)d_in[1];
  const float* gate_w  = (const float*)d_in[2];
  const float* gate_b  = (const float*)d_in[3];
  const float* loc_dw_w= (const float*)d_in[28];
  const float* loc_dw_b= (const float*)d_in[29];
  const float* loc_pw_w= (const float*)d_in[30];
  const float* loc_pw_b= (const float*)d_in[31];
  const float* ca_w1   = (const float*)d_in[32];
  const float* ca_b1   = (const float*)d_in[33];
  const float* ca_w2   = (const float*)d_in[34];
  const float* ca_b2   = (const float*)d_in[35];
  const float* alpha   = (const float*)d_in[36];

  float* W     = (float*)d_ws;
  float* XN    = W;                         // 4,194,304
  float* GATES = XN    + 4194304;           //   196,608
  float* GACC  = GATES + 196608;            // 4,194,304
  u16*   ZX    = (u16*)(GACC + 4194304);    // 21,102,592 u16 (10,551,296 fl)
  u16*   XB    = (u16*)(GACC + 4194304 + 10551296);  // 12,582,912 u16 (6,291,456 fl)
  float* DT    = GACC + 4194304 + 10551296 + 6291456; // 131,072
  float* CUM   = DT    + 131072;            //   131,072
  float* CDEC  = CUM   + 131072;            //     1,024
  float* ST    = CDEC  + 1024;              // 4,194,304 (aliased YH fp16)
  float* Y     = ST    + 4194304;           // 8,388,608 fl = YA/YB fp16
  float* LC1   = Y     + 8388608;           // 4,194,304 (aliased HPREV)
  float* LC2   = LC1   + 4194304;           // 4,194,304
  float* MEAN  = LC2   + 4194304;           //       128
  float* SIG   = MEAN  + 128;               //       128
  u16*   XNT   = (u16*)(SIG + 128);         // 4,194,304 u16
  u16*   WinT  = XNT + 4194304;             //    98,304 u16
  u16*   WoT   = WinT + 98304;              //    32,768 u16
  u16*   YH    = (u16*)ST;
  u16*   YA    = (u16*)Y;                   // 8,388,608 u16
  u16*   YB    = YA + 8388608;              // 8,388,608 u16
  float* HPREV = LC1;

  hipMemsetAsync(GACC, 0, 4194304*sizeof(float), stream);
  k_xn   <<<128,256,0,stream>>>(x, norm_w, XN);
  k_gates<<<128,256,0,stream>>>(XN, gate_w, gate_b, GATES);

  for (int r=0;r<6;r++){
    int m = r>>1;
    const float* Win   = (const float*)d_in[4 + m*8 + 0];
    const float* convw = (const float*)d_in[4 + m*8 + 1];
    const float* convb = (const float*)d_in[4 + m*8 + 2];
    const float* dtb   = (const float*)d_in[4 + m*8 + 3];
    const float* Alog  = (const float*)d_in[4 + m*8 + 4];
    const float* Dp    = (const float*)d_in[4 + m*8 + 5];
    const float* nw2   = (const float*)d_in[4 + m*8 + 6];
    const float* Wout  = (const float*)d_in[4 + m*8 + 7];
    if ((r&1)==0){
      k_permute<<<1024,256,0,stream>>>(XN, XNT, m);
      k_prepw  <<<384,256,0,stream>>>(Win, WinT);
      k_prewo  <<<128,256,0,stream>>>(Wout, WoT);
    }
    k_gin_mfma<<<dim3(6,256),256,0,stream>>>(XNT, WinT, ZX, r&1);
    k_conv    <<<1024,384,0,stream>>>(ZX, convw, convb, XB);
    k_dtcum   <<<256,256,0,stream>>>(ZX, dtb, Alog, DT, CUM, CDEC);
    k_chunk   <<<1024,256,0,stream>>>(XB, DT, CUM, Dp, YA, ST);
    k_scan    <<<64,256,0,stream>>>(ST, HPREV, CDEC);
    k_inter   <<<256,256,0,stream>>>(XB, CUM, HPREV, YB);
    k_ynorm   <<<8192,256,0,stream>>>(YA, YB, ZX, nw2, YH);
    k_gout_mfma<<<256,256,0,stream>>>(YH, WoT, GATES, GACC, r);
  }

  k_dwconv<<<4096,256,0,stream>>>(XN, loc_dw_w, loc_dw_b, LC1);
  k_pw    <<<256,256,0,stream>>>(LC1, loc_pw_w, loc_pw_b, LC2);
  k_fuse  <<<1024,256,0,stream>>>(GACC, LC2, alpha, LC1);
  k_mean  <<<128,256,0,stream>>>(LC1, MEAN);
  k_ca    <<<1,128,0,stream>>>(MEAN, ca_w1, ca_b1, ca_w2, ca_b2, SIG);
  k_final <<<16384,256,0,stream>>>(x, LC1, SIG, (float*)d_out);
}

// Round 8
// 1128.406 us; speedup vs baseline: 4.1576x; 1.0212x over previous
//
#include <hip/hip_runtime.h>

// OmniMambaBlock — round 8: triangular-skip k_chunk, fp16 state, no GACC memset.

typedef unsigned short u16;
typedef unsigned int   u32;
typedef __attribute__((ext_vector_type(8))) short short8;      // bf16x8
typedef __attribute__((ext_vector_type(8))) _Float16 half8;    // fp16x8
typedef __attribute__((ext_vector_type(4))) float f32x4;

#define LSEQ 32768
#define CDIM 128
#define NPROJ 644
#define CCH 384
#define DIN 256
#define NHD 4
#define CKL 128
#define NCHK 256

__device__ __forceinline__ float b2f(u16 u){ u32 x=((u32)u)<<16; float f; __builtin_memcpy(&f,&x,4); return f; }
__device__ __forceinline__ u16 f2b(float f){ u32 x; __builtin_memcpy(&x,&f,4); x += 0x7fffu + ((x>>16)&1u); return (u16)(x>>16); }
__device__ __forceinline__ u16 f2h(float v){ _Float16 h=(_Float16)v; u16 b; __builtin_memcpy(&b,&h,2); return b; }
__device__ __forceinline__ float h2f(u16 b){ _Float16 h; __builtin_memcpy(&h,&b,2); return (float)h; }
__device__ __forceinline__ void up4(uint2 v, float* o){
  union { uint2 u; _Float16 h[4]; } c; c.u = v;
  o[0]=(float)c.h[0]; o[1]=(float)c.h[1]; o[2]=(float)c.h[2]; o[3]=(float)c.h[3];
}
__device__ __forceinline__ uint2 pk4(const float* o){
  union { uint2 u; _Float16 h[4]; } c;
  c.h[0]=(_Float16)o[0]; c.h[1]=(_Float16)o[1]; c.h[2]=(_Float16)o[2]; c.h[3]=(_Float16)o[3];
  return c.u;
}
__device__ __forceinline__ float sigmoidf_(float v){ return 1.f/(1.f+__expf(-v)); }
__device__ __forceinline__ float siluf_(float v){ return v*sigmoidf_(v); }
__device__ __forceinline__ float softplusf_(float v){ return (v>20.f)? v : log1pf(__expf(v)); }

__device__ __forceinline__ int seq2sp(int t, int run){
  int te = (run&1) ? (LSEQ-1-t) : t;
  int a = te>>10, b=(te>>5)&31, c=te&31;
  int d,h,w;
  switch(run>>1){
    case 0: d=a; h=b; w=c; break;
    case 1: h=a; d=b; w=c; break;
    default: w=a; d=b; h=c; break;
  }
  return (d<<10)|(h<<5)|w;
}

// ---------------- K1: xn = rmsnorm(x, norm_w), layout (c,s) -----------------
__global__ void k_xn(const float* __restrict__ x, const float* __restrict__ nw, float* __restrict__ XN){
  int s = blockIdx.x*256 + threadIdx.x;
  float ss = 0.f;
  #pragma unroll 8
  for (int c=0;c<CDIM;c++){ float v=x[c*LSEQ+s]; ss += v*v; }
  float sc = rsqrtf(ss*(1.f/CDIM)+1e-6f);
  #pragma unroll 8
  for (int c=0;c<CDIM;c++){ XN[c*LSEQ+s] = x[c*LSEQ+s]*sc*nw[c]; }
}

// ---------------- K1b: gates softmax, layout (j,s) --------------------------
__global__ void k_gates(const float* __restrict__ XN, const float* __restrict__ gw, const float* __restrict__ gb, float* __restrict__ G){
  int s = blockIdx.x*256 + threadIdx.x;
  float a[6];
  #pragma unroll
  for (int j=0;j<6;j++) a[j]=gb[j];
  for (int c=0;c<CDIM;c++){
    float v = XN[c*LSEQ+s];
    #pragma unroll
    for (int j=0;j<6;j++) a[j] += v*gw[c*6+j];
  }
  float m=a[0];
  #pragma unroll
  for (int j=1;j<6;j++) m = fmaxf(m,a[j]);
  float e[6], ssum=0.f;
  #pragma unroll
  for (int j=0;j<6;j++){ e[j]=__expf(a[j]-m); ssum+=e[j]; }
  float inv = 1.f/ssum;
  #pragma unroll
  for (int j=0;j<6;j++) G[j*LSEQ+s] = e[j]*inv;
}

// ---------------- K_perm: XNT[t][c] bf16, sequence-ordered ------------------
__global__ __launch_bounds__(256) void k_permute(const float* __restrict__ XN, u16* __restrict__ XNT, int dir){
  __shared__ u16 TS[128*34];
  int a = blockIdx.x>>5, b = blockIdx.x&31;
  int tid = threadIdx.x;
  int spa = (dir==1)? b : a;
  int spb = (dir==1)? a : b;
  int spbase = spa*1024 + spb*32;
  for (int idx=tid; idx<4096; idx+=256){
    int c = idx>>5, i = idx&31;
    TS[c*34+i] = f2b(XN[c*LSEQ + spbase + i]);
  }
  __syncthreads();
  for (int idx=tid; idx<4096; idx+=256){
    int i = idx>>7, c = idx&127;
    int t = (dir==2) ? (i*1024 + a*32 + b) : (a*1024 + b*32 + i);
    XNT[t*128 + c] = TS[c*34+i];
  }
}

// ---------------- K_prepw: WinT[j][k] bf16, j padded to 768 -----------------
__global__ void k_prepw(const float* __restrict__ Win, u16* __restrict__ WinT){
  int idx = blockIdx.x*256 + threadIdx.x;
  int j = idx>>7, k = idx&127;
  float v = (j<NPROJ)? Win[k*NPROJ + j] : 0.f;
  WinT[idx] = f2b(v);
}

// ---------------- K_prewo: WoT[c][k] fp16 (Wout transposed) -----------------
__global__ void k_prewo(const float* __restrict__ Wout, u16* __restrict__ WoT){
  int idx = blockIdx.x*256 + threadIdx.x;
  int c = idx>>8, k = idx&255;
  WoT[idx] = f2h(Wout[k*CDIM + c]);
}

// ---------------- K2: ZX[t,j] = XNT[t,:]·WinT[j,:]  (bf16 MFMA, fp16 out) ---
__global__ __launch_bounds__(256) void k_gin_mfma(const u16* __restrict__ XNT, const u16* __restrict__ WinT,
                                                  u16* __restrict__ ZX, int flip){
  __shared__ u16 Asb[128*136];
  __shared__ u16 Bsb[128*136];
  int j0 = blockIdx.x*128, t0 = blockIdx.y*128;
  int tid = threadIdx.x;
  for (int ch = tid; ch < 2048; ch += 256){
    int row = ch>>4, c8 = ch&15;
    int tg = flip ? (LSEQ-1-(t0+row)) : (t0+row);
    uint4 av = *(const uint4*)(XNT + tg*128 + c8*8);
    *(uint4*)(&Asb[row*136 + c8*8]) = av;
    uint4 bv = *(const uint4*)(WinT + (j0+row)*128 + c8*8);
    *(uint4*)(&Bsb[row*136 + c8*8]) = bv;
  }
  __syncthreads();
  int lane = tid&63, wid = tid>>6;
  int wm = (wid>>1)*64, wn = (wid&1)*64;
  int lm = lane&15, lq = lane>>4;
  f32x4 acc[4][4] = {};
  for (int kt=0; kt<4; kt++){
    short8 af[4], bf[4];
    #pragma unroll
    for (int mt=0;mt<4;mt++) af[mt] = *(const short8*)(&Asb[(wm+mt*16+lm)*136 + kt*32 + lq*8]);
    #pragma unroll
    for (int nt=0;nt<4;nt++) bf[nt] = *(const short8*)(&Bsb[(wn+nt*16+lm)*136 + kt*32 + lq*8]);
    #pragma unroll
    for (int mt=0;mt<4;mt++)
      #pragma unroll
      for (int nt=0;nt<4;nt++)
        acc[mt][nt] = __builtin_amdgcn_mfma_f32_16x16x32_bf16(af[mt], bf[nt], acc[mt][nt], 0,0,0);
  }
  #pragma unroll
  for (int mt=0;mt<4;mt++){
    #pragma unroll
    for (int nt=0;nt<4;nt++){
      int j = j0 + wn + nt*16 + lm;
      if (j < NPROJ){
        #pragma unroll
        for (int r=0;r<4;r++){
          int t = t0 + wm + mt*16 + lq*4 + r;
          ZX[t*NPROJ + j] = f2h(acc[mt][nt][r]);
        }
      }
    }
  }
}

// ---------------- K3a: causal depthwise conv1d K=4 + silu -> XB fp16 --------
__global__ __launch_bounds__(384) void k_conv(const u16* __restrict__ ZX, const float* __restrict__ cw,
                                              const float* __restrict__ cb, u16* __restrict__ XB){
  __shared__ u16 smc[35*384];
  int t0 = blockIdx.x*32;
  int tid = threadIdx.x;
  for (int idx=tid; idx<13440; idx+=384){
    int j = idx/384, chh = idx - j*384;
    int t = t0-3+j;
    smc[idx] = (t>=0)? ZX[t*NPROJ + 256 + chh] : (u16)0;
  }
  __syncthreads();
  int ch = tid;
  float w0=cw[ch*4], w1=cw[ch*4+1], w2=cw[ch*4+2], w3=cw[ch*4+3], bb=cb[ch];
  for (int i=0;i<32;i++){
    float acc = w0*h2f(smc[i*384+ch]) + w1*h2f(smc[(i+1)*384+ch])
              + w2*h2f(smc[(i+2)*384+ch]) + w3*h2f(smc[(i+3)*384+ch]) + bb;
    XB[(t0+i)*CCH + ch] = f2h(siluf_(acc));
  }
}

// ---------------- K3b: dt softplus + per-chunk cumsum (wave-parallel) -------
__global__ __launch_bounds__(256) void k_dtcum(const u16* __restrict__ ZX, const float* __restrict__ dtb,
                                               const float* __restrict__ Alog, float* __restrict__ DT,
                                               float* __restrict__ CUM, float* __restrict__ CDEC){
  int g = blockIdx.x*4 + (threadIdx.x>>6);
  int lane = threadIdx.x&63;
  int c = g>>2, h = g&3;
  float A = -__expf(Alog[h]);
  float bias = dtb[h];
  int t0 = c*CKL + lane*2;
  float x0 = h2f(ZX[t0*NPROJ + 640 + h]);
  float x1 = h2f(ZX[(t0+1)*NPROJ + 640 + h]);
  float d0 = softplusf_(x0+bias), d1 = softplusf_(x1+bias);
  DT[t0*4+h] = d0; DT[(t0+1)*4+h] = d1;
  float e0 = d0*A, e1 = d1*A;
  float s = e0+e1;
  #pragma unroll
  for (int off=1; off<64; off<<=1){
    float v = __shfl_up(s, off, 64);
    if (lane>=off) s += v;
  }
  CUM[t0*4+h] = s - e1;
  CUM[(t0+1)*4+h] = s;
  float tot = __shfl(s, 63, 64);
  if (lane==0) CDEC[c*4+h] = __expf(tot);
}

// ---------------- K4: per (chunk,head): CB + Y_intra + S, triangular skip ---
__global__ __launch_bounds__(256) void k_chunk(const u16* __restrict__ XB, const float* __restrict__ DT,
                                               const float* __restrict__ CUM, const float* __restrict__ Dp,
                                               u16* __restrict__ YA, u16* __restrict__ ST){
  __shared__ u16 sh[35840];
  __shared__ float cum_s[128];
  u16* Cs   = sh;
  u16* Bsm  = sh + 9216;
  u16* Mh   = sh;
  u16* Xsh  = sh + 18432;
  u16* BdeT = sh + 27136;

  int bid = blockIdx.x; int c = bid>>2, h = bid&3;
  int tid = threadIdx.x, lane = tid&63, wid = tid>>6;
  int lm = lane&15, lq = lane>>4;

  for (int idx=tid; idx<1024; idx+=256){
    int t = idx>>3, b8 = idx&7;
    const u16* row = XB + (c*CKL+t)*CCH;
    *(uint4*)&Cs[t*72 + b8*8]  = *(const uint4*)(row + 320 + b8*8);
    *(uint4*)&Bsm[t*72 + b8*8] = *(const uint4*)(row + 256 + b8*8);
  }
  for (int idx=tid; idx<8192; idx+=256){
    int t = idx>>6, n = idx&63;
    float xv = h2f(XB[(c*CKL+t)*CCH + h*64 + n]) * DT[(c*CKL+t)*4 + h];
    Xsh[n*136 + t] = f2h(xv);
  }
  if (tid<128) cum_s[tid] = CUM[(c*CKL+tid)*4 + h];
  __syncthreads();

  // CB = C·B^T — only tiles touching the lower triangle (nt <= wid*2+mt)
  f32x4 cbac[2][8] = {};
  for (int kt=0; kt<2; kt++){
    half8 af0 = *(const half8*)&Cs[(wid*32+ 0+lm)*72 + kt*32 + lq*8];
    half8 af1 = *(const half8*)&Cs[(wid*32+16+lm)*72 + kt*32 + lq*8];
    #pragma unroll
    for (int nt=0;nt<8;nt++){
      if (nt <= wid*2+1){
        half8 bfv = *(const half8*)&Bsm[(nt*16+lm)*72 + kt*32 + lq*8];
        if (nt <= wid*2)
          cbac[0][nt] = __builtin_amdgcn_mfma_f32_16x16x32_f16(af0, bfv, cbac[0][nt], 0,0,0);
        cbac[1][nt] = __builtin_amdgcn_mfma_f32_16x16x32_f16(af1, bfv, cbac[1][nt], 0,0,0);
      }
    }
  }
  {
    float cl = cum_s[127];
    for (int idx=tid; idx<8192; idx+=256){
      int s = idx&127, n = idx>>7;
      float de = __expf(cl - cum_s[s]);
      BdeT[n*136+s] = f2h(h2f(Bsm[s*72+n]) * de);
    }
  }
  __syncthreads();
  // M build: upper tiles -> zeros (no exp); diagonal tile -> masked; lower -> full
  #pragma unroll
  for (int mt=0;mt<2;mt++){
    int tb = wid*32 + mt*16;
    int diag = wid*2 + mt;
    #pragma unroll
    for (int nt=0;nt<8;nt++){
      int s = nt*16 + lm;
      if (nt > diag){
        #pragma unroll
        for (int r=0;r<4;r++) Mh[(tb+lq*4+r)*136+s] = 0;
      } else if (nt == diag){
        #pragma unroll
        for (int r=0;r<4;r++){
          int t = tb + lq*4 + r;
          float m = (s<=t)? cbac[mt][nt][r]*__expf(cum_s[t]-cum_s[s]) : 0.f;
          Mh[t*136+s] = f2h(m);
        }
      } else {
        #pragma unroll
        for (int r=0;r<4;r++){
          int t = tb + lq*4 + r;
          Mh[t*136+s] = f2h(cbac[mt][nt][r]*__expf(cum_s[t]-cum_s[s]));
        }
      }
    }
  }
  __syncthreads();

  // Y_intra = M @ xdt — K-tiles only up to the diagonal (kt <= wid)
  f32x4 ya[2][4] = {};
  for (int kt=0; kt<=wid; kt++){
    half8 af[2], bfv[4];
    #pragma unroll
    for (int mt=0;mt<2;mt++) af[mt] = *(const half8*)&Mh[(wid*32+mt*16+lm)*136 + kt*32 + lq*8];
    #pragma unroll
    for (int nt=0;nt<4;nt++) bfv[nt] = *(const half8*)&Xsh[(nt*16+lm)*136 + kt*32 + lq*8];
    #pragma unroll
    for (int mt=0;mt<2;mt++)
      #pragma unroll
      for (int nt=0;nt<4;nt++)
        ya[mt][nt] = __builtin_amdgcn_mfma_f32_16x16x32_f16(af[mt], bfv[nt], ya[mt][nt], 0,0,0);
  }
  float dval = Dp[h];
  #pragma unroll
  for (int mt=0;mt<2;mt++){
    #pragma unroll
    for (int nt=0;nt<4;nt++){
      int p = nt*16 + lm;
      #pragma unroll
      for (int r=0;r<4;r++){
        int t = wid*32 + mt*16 + lq*4 + r;
        float xhv = h2f(XB[(c*CKL+t)*CCH + (h<<6) + p]);
        YA[((c*CKL+t)<<8) + (h<<6) + p] = f2h(ya[mt][nt][r] + dval*xhv);
      }
    }
  }

  f32x4 sa[4] = {};
  for (int kt=0; kt<4; kt++){
    half8 aa = *(const half8*)&Xsh[(wid*16+lm)*136 + kt*32 + lq*8];
    #pragma unroll
    for (int nt=0;nt<4;nt++){
      half8 bfv = *(const half8*)&BdeT[(nt*16+lm)*136 + kt*32 + lq*8];
      sa[nt] = __builtin_amdgcn_mfma_f32_16x16x32_f16(aa, bfv, sa[nt], 0,0,0);
    }
  }
  #pragma unroll
  for (int nt=0;nt<4;nt++){
    int n = nt*16 + lm;
    #pragma unroll
    for (int r=0;r<4;r++){
      int p = wid*16 + lq*4 + r;
      ST[((c*4+h)*64 + p)*64 + n] = f2h(sa[nt][r]);
    }
  }
}

// ---------------- K5: chunk-state scan (fp16 streams, fp32 accum) -----------
__global__ void k_scan(const u16* __restrict__ ST, u16* __restrict__ HP, const float* __restrict__ CDEC){
  int g = blockIdx.x*256 + threadIdx.x;
  int h = g>>12;
  float hp = 0.f;
  #pragma unroll 8
  for (int c=0;c<NCHK;c++){
    float dec = CDEC[(c<<2)+h];
    float sv = h2f(ST[g + (c<<14)]);
    HP[g + (c<<14)] = f2h(hp);
    hp = dec*hp + sv;
  }
}

// ---------------- K6: YB = exp(cum[t,h]) * C·H^T  (fp16 MFMA, all heads) ----
__global__ __launch_bounds__(256) void k_inter(const u16* __restrict__ XB, const float* __restrict__ CUM,
                                               const u16* __restrict__ HP, u16* __restrict__ YB){
  __shared__ u16 Cs[128*72];
  __shared__ u16 Hs[4*64*72];
  __shared__ float ex_s[4*128];
  int c = blockIdx.x;
  int tid = threadIdx.x, lane = tid&63, wid = tid>>6;
  int lm = lane&15, lq = lane>>4;
  for (int idx=tid; idx<1024; idx+=256){
    int t = idx>>3, b8 = idx&7;
    *(uint4*)&Cs[t*72 + b8*8] = *(const uint4*)(XB + (c*CKL+t)*CCH + 320 + b8*8);
  }
  for (int idx=tid; idx<2048; idx+=256){
    int h = idx>>9, p = (idx>>3)&63, b8 = idx&7;
    *(uint4*)&Hs[(h*64+p)*72 + b8*8] = *(const uint4*)(HP + ((c*4+h)*64+p)*64 + b8*8);
  }
  for (int idx=tid; idx<512; idx+=256){
    int h = idx>>7, t = idx&127;
    ex_s[h*128+t] = __expf(CUM[(c*CKL+t)*4+h]);
  }
  __syncthreads();
  int h = wid;
  const u16* Hh = &Hs[h*64*72];
  f32x4 acc[8][4] = {};
  for (int kt=0; kt<2; kt++){
    half8 af[8], bfv[4];
    #pragma unroll
    for (int mt=0;mt<8;mt++) af[mt] = *(const half8*)&Cs[(mt*16+lm)*72 + kt*32 + lq*8];
    #pragma unroll
    for (int nt=0;nt<4;nt++) bfv[nt] = *(const half8*)&Hh[(nt*16+lm)*72 + kt*32 + lq*8];
    #pragma unroll
    for (int mt=0;mt<8;mt++)
      #pragma unroll
      for (int nt=0;nt<4;nt++)
        acc[mt][nt] = __builtin_amdgcn_mfma_f32_16x16x32_f16(af[mt], bfv[nt], acc[mt][nt], 0,0,0);
  }
  #pragma unroll
  for (int mt=0;mt<8;mt++){
    #pragma unroll
    for (int r=0;r<4;r++){
      int t = mt*16 + lq*4 + r;
      float e = ex_s[h*128+t];
      u16* dst = &YB[((c*CKL+t)<<8) + (h<<6)];
      #pragma unroll
      for (int nt=0;nt<4;nt++){
        int p = nt*16 + lm;
        dst[p] = f2h(e*acc[mt][nt][r]);
      }
    }
  }
}

// ---------------- K7a: YH = fp16( rmsnorm((ya+yb)*silu(z)) * normw ) --------
__global__ __launch_bounds__(256) void k_ynorm(const u16* __restrict__ YA, const u16* __restrict__ YB,
                                               const u16* __restrict__ ZX, const float* __restrict__ nw,
                                               u16* __restrict__ YH){
  int t = blockIdx.x*4 + (threadIdx.x>>6);
  int lane = threadIdx.x&63;
  float a[4], b[4], z[4], u[4];
  up4(*(const uint2*)(YA + t*DIN + lane*4), a);
  up4(*(const uint2*)(YB + t*DIN + lane*4), b);
  up4(*(const uint2*)(ZX + t*NPROJ + lane*4), z);
  float4 w = *(const float4*)(nw + lane*4);
  float ss = 0.f;
  #pragma unroll
  for (int j=0;j<4;j++){ u[j] = (a[j]+b[j])*siluf_(z[j]); ss += u[j]*u[j]; }
  #pragma unroll
  for (int off=32; off; off>>=1) ss += __shfl_xor(ss, off, 64);
  float sc = rsqrtf(ss*(1.f/DIN)+1e-6f);
  float o[4] = { u[0]*sc*w.x, u[1]*sc*w.y, u[2]*sc*w.z, u[3]*sc*w.w };
  *(uint2*)(YH + t*DIN + lane*4) = pk4(o);
}

// ---------------- K7b: out GEMM + gate scatter (write run0, acc after) ------
__global__ __launch_bounds__(256) void k_gout_mfma(const u16* __restrict__ YH, const u16* __restrict__ WoT,
                                                   const float* __restrict__ G, float* __restrict__ GACC, int run){
  __shared__ u16 Ys[128*136];
  __shared__ u16 Ws[128*136];
  int t0 = blockIdx.x*128;
  int tid = threadIdx.x, lane = tid&63, wid = tid>>6;
  int lm = lane&15, lq = lane>>4;
  f32x4 acc[2][8] = {};
  for (int kb=0; kb<2; kb++){
    __syncthreads();
    for (int ch=tid; ch<2048; ch+=256){
      int row = ch>>4, c8 = ch&15;
      *(uint4*)&Ys[row*136 + c8*8] = *(const uint4*)(YH + (t0+row)*DIN + kb*128 + c8*8);
      *(uint4*)&Ws[row*136 + c8*8] = *(const uint4*)(WoT + row*DIN + kb*128 + c8*8);
    }
    __syncthreads();
    for (int kt=0; kt<4; kt++){
      half8 af[2], bfv[8];
      #pragma unroll
      for (int mt=0;mt<2;mt++) af[mt] = *(const half8*)&Ys[(wid*32+mt*16+lm)*136 + kt*32 + lq*8];
      #pragma unroll
      for (int nt=0;nt<8;nt++) bfv[nt] = *(const half8*)&Ws[(nt*16+lm)*136 + kt*32 + lq*8];
      #pragma unroll
      for (int mt=0;mt<2;mt++)
        #pragma unroll
        for (int nt=0;nt<8;nt++)
          acc[mt][nt] = __builtin_amdgcn_mfma_f32_16x16x32_f16(af[mt], bfv[nt], acc[mt][nt], 0,0,0);
    }
  }
  #pragma unroll
  for (int mt=0;mt<2;mt++){
    #pragma unroll
    for (int r=0;r<4;r++){
      int t = t0 + wid*32 + mt*16 + lq*4 + r;
      int sp = seq2sp(t, run);
      float g = G[run*LSEQ + sp];
      float* dst = &GACC[sp*CDIM];
      if (run==0){
        #pragma unroll
        for (int nt=0;nt<8;nt++) dst[nt*16+lm] = g*acc[mt][nt][r];
      } else {
        #pragma unroll
        for (int nt=0;nt<8;nt++) dst[nt*16+lm] += g*acc[mt][nt][r];
      }
    }
  }
}

// ---------------- K8: depthwise 3x3x3 conv, LDS-tiled -----------------------
__global__ __launch_bounds__(256) void k_dwconv(const float* __restrict__ XN, const float* __restrict__ w,
                                                const float* __restrict__ b, float* __restrict__ LC1){
  __shared__ float sm[3*34*40];
  int cc = blockIdx.x>>5, d = blockIdx.x&31;
  int tid = threadIdx.x;
  for (int i=tid; i<4080; i+=256) sm[i] = 0.f;
  __syncthreads();
  #pragma unroll
  for (int p=0;p<3;p++){
    int dz = d-1+p;
    if ((unsigned)dz<=31u){
      for (int idx=tid; idx<1024; idx+=256){
        int hh = idx>>5, ww = idx&31;
        sm[p*1360 + (hh+1)*40 + (ww+4)] = XN[cc*LSEQ + (dz<<10) + idx];
      }
    }
  }
  __syncthreads();
  float wreg[27];
  #pragma unroll
  for (int i=0;i<27;i++) wreg[i] = w[cc*27+i];
  float bias = b[cc];
  int h = tid>>3, w0 = (tid&7)*4;
  float4 acc = {bias,bias,bias,bias};
  #pragma unroll
  for (int p=0;p<3;p++){
    #pragma unroll
    for (int dy=0;dy<3;dy++){
      const float* row = &sm[p*1360 + (h+dy)*40 + 4];
      float left  = row[w0-1];
      float4 mid  = *(const float4*)&row[w0];
      float right = row[w0+4];
      float wa=wreg[p*9+dy*3+0], wb=wreg[p*9+dy*3+1], wc=wreg[p*9+dy*3+2];
      acc.x += wa*left  + wb*mid.x + wc*mid.y;
      acc.y += wa*mid.x + wb*mid.y + wc*mid.z;
      acc.z += wa*mid.y + wb*mid.z + wc*mid.w;
      acc.w += wa*mid.z + wb*mid.w + wc*right;
    }
  }
  *(float4*)&LC1[cc*LSEQ + (d<<10) + h*32 + w0] = acc;
}

// ---------------- K9: pointwise 128x128 + silu (fp16 MFMA) ------------------
__global__ __launch_bounds__(256) void k_pw(const float* __restrict__ LC1, const float* __restrict__ pw,
                                            const float* __restrict__ pwb, float* __restrict__ LC2){
  __shared__ u16 Ws[128*136];
  __shared__ u16 Bs[128*136];
  int s0 = blockIdx.x*128;
  int tid = threadIdx.x, lane = tid&63, wid = tid>>6;
  int lm = lane&15, lq = lane>>4;
  for (int idx=tid; idx<16384; idx+=256){
    int o = idx>>7, cc = idx&127;
    Ws[o*136+cc] = f2h(pw[idx]);
  }
  for (int idx=tid; idx<16384; idx+=256){
    int cc = idx>>7, n = idx&127;
    Bs[n*136+cc] = f2h(LC1[cc*LSEQ + s0 + n]);
  }
  __syncthreads();
  f32x4 acc[2][8] = {};
  for (int kt=0; kt<4; kt++){
    half8 af[2], bfv[8];
    #pragma unroll
    for (int mt=0;mt<2;mt++) af[mt] = *(const half8*)&Ws[(wid*32+mt*16+lm)*136 + kt*32 + lq*8];
    #pragma unroll
    for (int nt=0;nt<8;nt++) bfv[nt] = *(const half8*)&Bs[(nt*16+lm)*136 + kt*32 + lq*8];
    #pragma unroll
    for (int mt=0;mt<2;mt++)
      #pragma unroll
      for (int nt=0;nt<8;nt++)
        acc[mt][nt] = __builtin_amdgcn_mfma_f32_16x16x32_f16(af[mt], bfv[nt], acc[mt][nt], 0,0,0);
  }
  #pragma unroll
  for (int mt=0;mt<2;mt++){
    #pragma unroll
    for (int r=0;r<4;r++){
      int o = wid*32 + mt*16 + lq*4 + r;
      float bb = pwb[o];
      float* dst = &LC2[o*LSEQ + s0];
      #pragma unroll
      for (int nt=0;nt<8;nt++){
        int n = nt*16 + lm;
        dst[n] = siluf_(acc[mt][nt][r] + bb);
      }
    }
  }
}

// ---------------- K10: fused = a*g + (1-a)*lc, transpose --------------------
__global__ void k_fuse(const float* __restrict__ GACC, const float* __restrict__ LC2,
                       const float* __restrict__ alpha, float* __restrict__ FUSED){
  __shared__ float tile[64*65];
  int bs = blockIdx.x>>1, bc = blockIdx.x&1;
  int s0 = bs*64, c0 = bc*64;
  int tid = threadIdx.x;
  float a = alpha[0];
  for (int idx=tid; idx<4096; idx+=256){
    int i = idx>>6, j = idx&63;
    tile[i*65+j] = GACC[(s0+i)*CDIM + c0+j];
  }
  __syncthreads();
  for (int idx=tid; idx<4096; idx+=256){
    int j = idx>>6, i = idx&63;
    float g = tile[i*65+j];
    float l = LC2[(c0+j)*LSEQ + s0+i];
    FUSED[(c0+j)*LSEQ + s0+i] = a*g + (1.f-a)*l;
  }
}

// ---------------- K_mean ----------------------------------------------------
__global__ void k_mean(const float* __restrict__ F, float* __restrict__ MEAN){
  __shared__ float red[4];
  int cc = blockIdx.x, tid = threadIdx.x;
  float acc = 0.f;
  for (int s=tid; s<LSEQ; s+=256) acc += F[cc*LSEQ + s];
  #pragma unroll
  for (int off=32; off; off>>=1) acc += __shfl_down(acc, off, 64);
  if ((tid&63)==0) red[tid>>6] = acc;
  __syncthreads();
  if (tid==0) MEAN[cc] = (red[0]+red[1]+red[2]+red[3])*(1.f/LSEQ);
}

// ---------------- K11: channel attention ------------------------------------
__global__ void k_ca(const float* __restrict__ MEAN, const float* __restrict__ w1, const float* __restrict__ b1,
                     const float* __restrict__ w2, const float* __restrict__ b2, float* __restrict__ SIG){
  __shared__ float y1[8];
  int tid = threadIdx.x;
  if (tid<8){
    float acc = b1[tid];
    for (int c=0;c<128;c++) acc += w1[tid*128+c]*MEAN[c];
    y1[tid] = (acc>=0.f)? acc : 0.1f*acc;
  }
  __syncthreads();
  float acc = b2[tid];
  #pragma unroll
  for (int o=0;o<8;o++) acc += w2[tid*8+o]*y1[o];
  SIG[tid] = sigmoidf_(acc);
}

// ---------------- K12: out = x + fused * sigmoid(yc) ------------------------
__global__ void k_final(const float* __restrict__ x, const float* __restrict__ F, const float* __restrict__ SIG,
                        float* __restrict__ out){
  int idx = blockIdx.x*256 + threadIdx.x;
  int cc = idx>>15;
  out[idx] = x[idx] + F[idx]*SIG[cc];
}

extern "C" void kernel_launch(void* const* d_in, const int* in_sizes, int n_in,
                              void* d_out, int out_size, void* d_ws, size_t ws_size,
                              hipStream_t stream){
  (void)in_sizes; (void)n_in; (void)out_size; (void)ws_size;
  const float* x       = (const float*)d_in[0];
  const float* norm_w  = (const float*)d_in[1];
  const float* gate_w  = (const float*)d_in[2];
  const float* gate_b  = (const float*)d_in[3];
  const float* loc_dw_w= (const float*)d_in[28];
  const float* loc_dw_b= (const float*)d_in[29];
  const float* loc_pw_w= (const float*)d_in[30];
  const float* loc_pw_b= (const float*)d_in[31];
  const float* ca_w1   = (const float*)d_in[32];
  const float* ca_b1   = (const float*)d_in[33];
  const float* ca_w2   = (const float*)d_in[34];
  const float* ca_b2   = (const float*)d_in[35];
  const float* alpha   = (const float*)d_in[36];

  float* W     = (float*)d_ws;
  float* XN    = W;                         // 4,194,304
  float* GATES = XN    + 4194304;           //   196,608
  float* GACC  = GATES + 196608;            // 4,194,304
  u16*   ZX    = (u16*)(GACC + 4194304);    // 21,102,592 u16
  u16*   XB    = (u16*)(GACC + 4194304 + 10551296);   // 12,582,912 u16
  float* DT    = GACC + 4194304 + 10551296 + 6291456; // 131,072
  float* CUM   = DT    + 131072;            //   131,072
  float* CDEC  = CUM   + 131072;            //     1,024
  float* STreg = CDEC  + 1024;              // 4,194,304 fl region (ST16 / YH alias)
  float* Y     = STreg + 4194304;           // 8,388,608 fl = YA/YB fp16
  float* LC1   = Y     + 8388608;           // 4,194,304 (HPREV16 alias)
  float* LC2   = LC1   + 4194304;           // 4,194,304
  float* MEAN  = LC2   + 4194304;           //       128
  float* SIG   = MEAN  + 128;               //       128
  u16*   XNT   = (u16*)(SIG + 128);         // 4,194,304 u16
  u16*   WinT  = XNT + 4194304;             //    98,304 u16
  u16*   WoT   = WinT + 98304;              //    32,768 u16
  u16*   ST16  = (u16*)STreg;               // 4,194,304 u16 (8 MB of 16)
  u16*   YH    = (u16*)STreg;               // alias (ST dead after k_inter)
  u16*   YA    = (u16*)Y;                   // 8,388,608 u16
  u16*   YB    = YA + 8388608;              // 8,388,608 u16
  u16*   HP16  = (u16*)LC1;                 // 4,194,304 u16 (8 MB of 16)

  k_xn   <<<128,256,0,stream>>>(x, norm_w, XN);
  k_gates<<<128,256,0,stream>>>(XN, gate_w, gate_b, GATES);

  for (int r=0;r<6;r++){
    int m = r>>1;
    const float* Win   = (const float*)d_in[4 + m*8 + 0];
    const float* convw = (const float*)d_in[4 + m*8 + 1];
    const float* convb = (const float*)d_in[4 + m*8 + 2];
    const float* dtb   = (const float*)d_in[4 + m*8 + 3];
    const float* Alog  = (const float*)d_in[4 + m*8 + 4];
    const float* Dp    = (const float*)d_in[4 + m*8 + 5];
    const float* nw2   = (const float*)d_in[4 + m*8 + 6];
    const float* Wout  = (const float*)d_in[4 + m*8 + 7];
    if ((r&1)==0){
      k_permute<<<1024,256,0,stream>>>(XN, XNT, m);
      k_prepw  <<<384,256,0,stream>>>(Win, WinT);
      k_prewo  <<<128,256,0,stream>>>(Wout, WoT);
    }
    k_gin_mfma<<<dim3(6,256),256,0,stream>>>(XNT, WinT, ZX, r&1);
    k_conv    <<<1024,384,0,stream>>>(ZX, convw, convb, XB);
    k_dtcum   <<<256,256,0,stream>>>(ZX, dtb, Alog, DT, CUM, CDEC);
    k_chunk   <<<1024,256,0,stream>>>(XB, DT, CUM, Dp, YA, ST16);
    k_scan    <<<64,256,0,stream>>>(ST16, HP16, CDEC);
    k_inter   <<<256,256,0,stream>>>(XB, CUM, HP16, YB);
    k_ynorm   <<<8192,256,0,stream>>>(YA, YB, ZX, nw2, YH);
    k_gout_mfma<<<256,256,0,stream>>>(YH, WoT, GATES, GACC, r);
  }

  k_dwconv<<<4096,256,0,stream>>>(XN, loc_dw_w, loc_dw_b, LC1);
  k_pw    <<<256,256,0,stream>>>(LC1, loc_pw_w, loc_pw_b, LC2);
  k_fuse  <<<1024,256,0,stream>>>(GACC, LC2, alpha, LC1);
  k_mean  <<<128,256,0,stream>>>(LC1, MEAN);
  k_ca    <<<1,128,0,stream>>>(MEAN, ca_w1, ca_b1, ca_w2, ca_b2, SIG);
  k_final <<<16384,256,0,stream>>>(x, LC1, SIG, (float*)d_out);
}

// Round 9
// 1124.465 us; speedup vs baseline: 4.1721x; 1.0035x over previous
//
#include <hip/hip_runtime.h>

// OmniMambaBlock — round 9: k_chunk occupancy 2->3 blocks/CU (LDS 72->54 KB),
// phase reorder (S before M), wave-private M (fewer syncs/zero-fills).

typedef unsigned short u16;
typedef unsigned int   u32;
typedef __attribute__((ext_vector_type(8))) short short8;      // bf16x8
typedef __attribute__((ext_vector_type(8))) _Float16 half8;    // fp16x8
typedef __attribute__((ext_vector_type(4))) float f32x4;

#define LSEQ 32768
#define CDIM 128
#define NPROJ 644
#define CCH 384
#define DIN 256
#define NHD 4
#define CKL 128
#define NCHK 256

__device__ __forceinline__ float b2f(u16 u){ u32 x=((u32)u)<<16; float f; __builtin_memcpy(&f,&x,4); return f; }
__device__ __forceinline__ u16 f2b(float f){ u32 x; __builtin_memcpy(&x,&f,4); x += 0x7fffu + ((x>>16)&1u); return (u16)(x>>16); }
__device__ __forceinline__ u16 f2h(float v){ _Float16 h=(_Float16)v; u16 b; __builtin_memcpy(&b,&h,2); return b; }
__device__ __forceinline__ float h2f(u16 b){ _Float16 h; __builtin_memcpy(&h,&b,2); return (float)h; }
__device__ __forceinline__ void up4(uint2 v, float* o){
  union { uint2 u; _Float16 h[4]; } c; c.u = v;
  o[0]=(float)c.h[0]; o[1]=(float)c.h[1]; o[2]=(float)c.h[2]; o[3]=(float)c.h[3];
}
__device__ __forceinline__ uint2 pk4(const float* o){
  union { uint2 u; _Float16 h[4]; } c;
  c.h[0]=(_Float16)o[0]; c.h[1]=(_Float16)o[1]; c.h[2]=(_Float16)o[2]; c.h[3]=(_Float16)o[3];
  return c.u;
}
__device__ __forceinline__ float sigmoidf_(float v){ return 1.f/(1.f+__expf(-v)); }
__device__ __forceinline__ float siluf_(float v){ return v*sigmoidf_(v); }
__device__ __forceinline__ float softplusf_(float v){ return (v>20.f)? v : log1pf(__expf(v)); }

__device__ __forceinline__ int seq2sp(int t, int run){
  int te = (run&1) ? (LSEQ-1-t) : t;
  int a = te>>10, b=(te>>5)&31, c=te&31;
  int d,h,w;
  switch(run>>1){
    case 0: d=a; h=b; w=c; break;
    case 1: h=a; d=b; w=c; break;
    default: w=a; d=b; h=c; break;
  }
  return (d<<10)|(h<<5)|w;
}

// ---------------- K1: xn = rmsnorm(x, norm_w), layout (c,s) -----------------
__global__ void k_xn(const float* __restrict__ x, const float* __restrict__ nw, float* __restrict__ XN){
  int s = blockIdx.x*256 + threadIdx.x;
  float ss = 0.f;
  #pragma unroll 8
  for (int c=0;c<CDIM;c++){ float v=x[c*LSEQ+s]; ss += v*v; }
  float sc = rsqrtf(ss*(1.f/CDIM)+1e-6f);
  #pragma unroll 8
  for (int c=0;c<CDIM;c++){ XN[c*LSEQ+s] = x[c*LSEQ+s]*sc*nw[c]; }
}

// ---------------- K1b: gates softmax, layout (j,s) --------------------------
__global__ void k_gates(const float* __restrict__ XN, const float* __restrict__ gw, const float* __restrict__ gb, float* __restrict__ G){
  int s = blockIdx.x*256 + threadIdx.x;
  float a[6];
  #pragma unroll
  for (int j=0;j<6;j++) a[j]=gb[j];
  for (int c=0;c<CDIM;c++){
    float v = XN[c*LSEQ+s];
    #pragma unroll
    for (int j=0;j<6;j++) a[j] += v*gw[c*6+j];
  }
  float m=a[0];
  #pragma unroll
  for (int j=1;j<6;j++) m = fmaxf(m,a[j]);
  float e[6], ssum=0.f;
  #pragma unroll
  for (int j=0;j<6;j++){ e[j]=__expf(a[j]-m); ssum+=e[j]; }
  float inv = 1.f/ssum;
  #pragma unroll
  for (int j=0;j<6;j++) G[j*LSEQ+s] = e[j]*inv;
}

// ---------------- K_perm: XNT[t][c] bf16, sequence-ordered ------------------
__global__ __launch_bounds__(256) void k_permute(const float* __restrict__ XN, u16* __restrict__ XNT, int dir){
  __shared__ u16 TS[128*34];
  int a = blockIdx.x>>5, b = blockIdx.x&31;
  int tid = threadIdx.x;
  int spa = (dir==1)? b : a;
  int spb = (dir==1)? a : b;
  int spbase = spa*1024 + spb*32;
  for (int idx=tid; idx<4096; idx+=256){
    int c = idx>>5, i = idx&31;
    TS[c*34+i] = f2b(XN[c*LSEQ + spbase + i]);
  }
  __syncthreads();
  for (int idx=tid; idx<4096; idx+=256){
    int i = idx>>7, c = idx&127;
    int t = (dir==2) ? (i*1024 + a*32 + b) : (a*1024 + b*32 + i);
    XNT[t*128 + c] = TS[c*34+i];
  }
}

// ---------------- K_prepw: WinT[j][k] bf16, j padded to 768 -----------------
__global__ void k_prepw(const float* __restrict__ Win, u16* __restrict__ WinT){
  int idx = blockIdx.x*256 + threadIdx.x;
  int j = idx>>7, k = idx&127;
  float v = (j<NPROJ)? Win[k*NPROJ + j] : 0.f;
  WinT[idx] = f2b(v);
}

// ---------------- K_prewo: WoT[c][k] fp16 (Wout transposed) -----------------
__global__ void k_prewo(const float* __restrict__ Wout, u16* __restrict__ WoT){
  int idx = blockIdx.x*256 + threadIdx.x;
  int c = idx>>8, k = idx&255;
  WoT[idx] = f2h(Wout[k*CDIM + c]);
}

// ---------------- K2: ZX[t,j] = XNT[t,:]·WinT[j,:]  (bf16 MFMA, fp16 out) ---
__global__ __launch_bounds__(256) void k_gin_mfma(const u16* __restrict__ XNT, const u16* __restrict__ WinT,
                                                  u16* __restrict__ ZX, int flip){
  __shared__ u16 Asb[128*136];
  __shared__ u16 Bsb[128*136];
  int j0 = blockIdx.x*128, t0 = blockIdx.y*128;
  int tid = threadIdx.x;
  for (int ch = tid; ch < 2048; ch += 256){
    int row = ch>>4, c8 = ch&15;
    int tg = flip ? (LSEQ-1-(t0+row)) : (t0+row);
    uint4 av = *(const uint4*)(XNT + tg*128 + c8*8);
    *(uint4*)(&Asb[row*136 + c8*8]) = av;
    uint4 bv = *(const uint4*)(WinT + (j0+row)*128 + c8*8);
    *(uint4*)(&Bsb[row*136 + c8*8]) = bv;
  }
  __syncthreads();
  int lane = tid&63, wid = tid>>6;
  int wm = (wid>>1)*64, wn = (wid&1)*64;
  int lm = lane&15, lq = lane>>4;
  f32x4 acc[4][4] = {};
  for (int kt=0; kt<4; kt++){
    short8 af[4], bf[4];
    #pragma unroll
    for (int mt=0;mt<4;mt++) af[mt] = *(const short8*)(&Asb[(wm+mt*16+lm)*136 + kt*32 + lq*8]);
    #pragma unroll
    for (int nt=0;nt<4;nt++) bf[nt] = *(const short8*)(&Bsb[(wn+nt*16+lm)*136 + kt*32 + lq*8]);
    #pragma unroll
    for (int mt=0;mt<4;mt++)
      #pragma unroll
      for (int nt=0;nt<4;nt++)
        acc[mt][nt] = __builtin_amdgcn_mfma_f32_16x16x32_bf16(af[mt], bf[nt], acc[mt][nt], 0,0,0);
  }
  #pragma unroll
  for (int mt=0;mt<4;mt++){
    #pragma unroll
    for (int nt=0;nt<4;nt++){
      int j = j0 + wn + nt*16 + lm;
      if (j < NPROJ){
        #pragma unroll
        for (int r=0;r<4;r++){
          int t = t0 + wm + mt*16 + lq*4 + r;
          ZX[t*NPROJ + j] = f2h(acc[mt][nt][r]);
        }
      }
    }
  }
}

// ---------------- K3a: causal depthwise conv1d K=4 + silu -> XB fp16 --------
__global__ __launch_bounds__(384) void k_conv(const u16* __restrict__ ZX, const float* __restrict__ cw,
                                              const float* __restrict__ cb, u16* __restrict__ XB){
  __shared__ u16 smc[35*384];
  int t0 = blockIdx.x*32;
  int tid = threadIdx.x;
  for (int idx=tid; idx<13440; idx+=384){
    int j = idx/384, chh = idx - j*384;
    int t = t0-3+j;
    smc[idx] = (t>=0)? ZX[t*NPROJ + 256 + chh] : (u16)0;
  }
  __syncthreads();
  int ch = tid;
  float w0=cw[ch*4], w1=cw[ch*4+1], w2=cw[ch*4+2], w3=cw[ch*4+3], bb=cb[ch];
  for (int i=0;i<32;i++){
    float acc = w0*h2f(smc[i*384+ch]) + w1*h2f(smc[(i+1)*384+ch])
              + w2*h2f(smc[(i+2)*384+ch]) + w3*h2f(smc[(i+3)*384+ch]) + bb;
    XB[(t0+i)*CCH + ch] = f2h(siluf_(acc));
  }
}

// ---------------- K3b: dt softplus + per-chunk cumsum (wave-parallel) -------
__global__ __launch_bounds__(256) void k_dtcum(const u16* __restrict__ ZX, const float* __restrict__ dtb,
                                               const float* __restrict__ Alog, float* __restrict__ DT,
                                               float* __restrict__ CUM, float* __restrict__ CDEC){
  int g = blockIdx.x*4 + (threadIdx.x>>6);
  int lane = threadIdx.x&63;
  int c = g>>2, h = g&3;
  float A = -__expf(Alog[h]);
  float bias = dtb[h];
  int t0 = c*CKL + lane*2;
  float x0 = h2f(ZX[t0*NPROJ + 640 + h]);
  float x1 = h2f(ZX[(t0+1)*NPROJ + 640 + h]);
  float d0 = softplusf_(x0+bias), d1 = softplusf_(x1+bias);
  DT[t0*4+h] = d0; DT[(t0+1)*4+h] = d1;
  float e0 = d0*A, e1 = d1*A;
  float s = e0+e1;
  #pragma unroll
  for (int off=1; off<64; off<<=1){
    float v = __shfl_up(s, off, 64);
    if (lane>=off) s += v;
  }
  CUM[t0*4+h] = s - e1;
  CUM[(t0+1)*4+h] = s;
  float tot = __shfl(s, 63, 64);
  if (lane==0) CDEC[c*4+h] = __expf(tot);
}

// ---------------- K4: per (chunk,head) — 54272 B LDS (3 blocks/CU) ----------
// Layout: [0,9216) Cs -> BdeT -> Mh(low); [9216,18432) Bsm -> Mh(high);
//         [18432,27136) Xsh[64][136] fp16, cum_s packed in pad cols 128..135.
__global__ __launch_bounds__(256) void k_chunk(const u16* __restrict__ XB, const float* __restrict__ DT,
                                               const float* __restrict__ CUM, const float* __restrict__ Dp,
                                               u16* __restrict__ YA, u16* __restrict__ ST){
  __shared__ u16 sh[27136];
  u16* Cs   = sh;           // [128][72]
  u16* Bsm  = sh + 9216;    // [128][72]
  u16* BdeT = sh;           // [64][136] overlays Cs after CB
  u16* Mh   = sh;           // [128][136] overlays Cs+Bsm after S
  u16* Xsh  = sh + 18432;   // [64][136]

  int bid = blockIdx.x; int c = bid>>2, h = bid&3;
  int tid = threadIdx.x, lane = tid&63, wid = tid>>6;
  int lm = lane&15, lq = lane>>4;

  // stage C/B (vector) and xdt (transpose); cum packed in Xsh pad
  for (int idx=tid; idx<1024; idx+=256){
    int t = idx>>3, b8 = idx&7;
    const u16* row = XB + (c*CKL+t)*CCH;
    *(uint4*)&Cs[t*72 + b8*8]  = *(const uint4*)(row + 320 + b8*8);
    *(uint4*)&Bsm[t*72 + b8*8] = *(const uint4*)(row + 256 + b8*8);
  }
  for (int idx=tid; idx<8192; idx+=256){
    int t = idx>>6, n = idx&63;
    float xv = h2f(XB[(c*CKL+t)*CCH + h*64 + n]) * DT[(c*CKL+t)*4 + h];
    Xsh[n*136 + t] = f2h(xv);
  }
  if (tid<128) ((float*)(Xsh + (tid>>1)*136 + 128))[tid&1] = CUM[(c*CKL+tid)*4 + h];
  __syncthreads();
  #define CUMS(t) (((const float*)(Xsh + ((t)>>1)*136 + 128))[(t)&1])

  // ---- CB = C·B^T (triangular tiles only) ----
  f32x4 cbac[2][8] = {};
  for (int kt=0; kt<2; kt++){
    half8 af0 = *(const half8*)&Cs[(wid*32+ 0+lm)*72 + kt*32 + lq*8];
    half8 af1 = *(const half8*)&Cs[(wid*32+16+lm)*72 + kt*32 + lq*8];
    #pragma unroll
    for (int nt=0;nt<8;nt++){
      if (nt <= wid*2+1){
        half8 bfv = *(const half8*)&Bsm[(nt*16+lm)*72 + kt*32 + lq*8];
        if (nt <= wid*2)
          cbac[0][nt] = __builtin_amdgcn_mfma_f32_16x16x32_f16(af0, bfv, cbac[0][nt], 0,0,0);
        cbac[1][nt] = __builtin_amdgcn_mfma_f32_16x16x32_f16(af1, bfv, cbac[1][nt], 0,0,0);
      }
    }
  }
  __syncthreads();   // CB reads of Cs done -> safe to overwrite with BdeT

  // ---- BdeT[n][s] = B[s][n]*exp(cum_last - cum_s), into Cs region ----
  {
    float cl = CUMS(127);
    for (int idx=tid; idx<8192; idx+=256){
      int s = idx&127, n = idx>>7;
      float de = __expf(cl - CUMS(s));
      BdeT[n*136+s] = f2h(h2f(Bsm[s*72+n]) * de);
    }
  }
  __syncthreads();

  // ---- S = xdt^T @ BdeT^T ----
  f32x4 sa[4] = {};
  for (int kt=0; kt<4; kt++){
    half8 aa = *(const half8*)&Xsh[(wid*16+lm)*136 + kt*32 + lq*8];
    #pragma unroll
    for (int nt=0;nt<4;nt++){
      half8 bfv = *(const half8*)&BdeT[(nt*16+lm)*136 + kt*32 + lq*8];
      sa[nt] = __builtin_amdgcn_mfma_f32_16x16x32_f16(aa, bfv, sa[nt], 0,0,0);
    }
  }
  #pragma unroll
  for (int nt=0;nt<4;nt++){
    int n = nt*16 + lm;
    #pragma unroll
    for (int r=0;r<4;r++){
      int p = wid*16 + lq*4 + r;
      ST[((c*4+h)*64 + p)*64 + n] = f2h(sa[nt][r]);
    }
  }
  __syncthreads();   // S reads of BdeT done -> safe to overwrite with Mh

  // ---- M build (wave-private rows; only tiles this wave's Y_intra reads) ---
  #pragma unroll
  for (int mt=0;mt<2;mt++){
    int tb = wid*32 + mt*16;
    int diag = wid*2 + mt;
    int hi = wid*2 + 1;     // last column tile this wave reads (kt<=wid)
    #pragma unroll
    for (int nt=0;nt<8;nt++){
      if (nt > hi) break;
      int s = nt*16 + lm;
      if (nt > diag){
        #pragma unroll
        for (int r=0;r<4;r++) Mh[(tb+lq*4+r)*136+s] = 0;
      } else if (nt == diag){
        #pragma unroll
        for (int r=0;r<4;r++){
          int t = tb + lq*4 + r;
          float m = (s<=t)? cbac[mt][nt][r]*__expf(CUMS(t)-CUMS(s)) : 0.f;
          Mh[t*136+s] = f2h(m);
        }
      } else {
        #pragma unroll
        for (int r=0;r<4;r++){
          int t = tb + lq*4 + r;
          Mh[t*136+s] = f2h(cbac[mt][nt][r]*__expf(CUMS(t)-CUMS(s)));
        }
      }
    }
  }
  // no barrier: M rows are written and read by the same wave

  // ---- Y_intra = M @ xdt (K-tiles up to diagonal) + D*xh epilogue ----
  f32x4 ya[2][4] = {};
  for (int kt=0; kt<=wid; kt++){
    half8 af[2], bfv[4];
    #pragma unroll
    for (int mt=0;mt<2;mt++) af[mt] = *(const half8*)&Mh[(wid*32+mt*16+lm)*136 + kt*32 + lq*8];
    #pragma unroll
    for (int nt=0;nt<4;nt++) bfv[nt] = *(const half8*)&Xsh[(nt*16+lm)*136 + kt*32 + lq*8];
    #pragma unroll
    for (int mt=0;mt<2;mt++)
      #pragma unroll
      for (int nt=0;nt<4;nt++)
        ya[mt][nt] = __builtin_amdgcn_mfma_f32_16x16x32_f16(af[mt], bfv[nt], ya[mt][nt], 0,0,0);
  }
  float dval = Dp[h];
  #pragma unroll
  for (int mt=0;mt<2;mt++){
    #pragma unroll
    for (int nt=0;nt<4;nt++){
      int p = nt*16 + lm;
      #pragma unroll
      for (int r=0;r<4;r++){
        int t = wid*32 + mt*16 + lq*4 + r;
        float xhv = h2f(XB[(c*CKL+t)*CCH + (h<<6) + p]);
        YA[((c*CKL+t)<<8) + (h<<6) + p] = f2h(ya[mt][nt][r] + dval*xhv);
      }
    }
  }
  #undef CUMS
}

// ---------------- K5: chunk-state scan (fp16 streams, fp32 accum) -----------
__global__ void k_scan(const u16* __restrict__ ST, u16* __restrict__ HP, const float* __restrict__ CDEC){
  int g = blockIdx.x*256 + threadIdx.x;
  int h = g>>12;
  float hp = 0.f;
  #pragma unroll 8
  for (int c=0;c<NCHK;c++){
    float dec = CDEC[(c<<2)+h];
    float sv = h2f(ST[g + (c<<14)]);
    HP[g + (c<<14)] = f2h(hp);
    hp = dec*hp + sv;
  }
}

// ---------------- K6: YB = exp(cum[t,h]) * C·H^T  (fp16 MFMA, all heads) ----
__global__ __launch_bounds__(256) void k_inter(const u16* __restrict__ XB, const float* __restrict__ CUM,
                                               const u16* __restrict__ HP, u16* __restrict__ YB){
  __shared__ u16 Cs[128*72];
  __shared__ u16 Hs[4*64*72];
  __shared__ float ex_s[4*128];
  int c = blockIdx.x;
  int tid = threadIdx.x, lane = tid&63, wid = tid>>6;
  int lm = lane&15, lq = lane>>4;
  for (int idx=tid; idx<1024; idx+=256){
    int t = idx>>3, b8 = idx&7;
    *(uint4*)&Cs[t*72 + b8*8] = *(const uint4*)(XB + (c*CKL+t)*CCH + 320 + b8*8);
  }
  for (int idx=tid; idx<2048; idx+=256){
    int h = idx>>9, p = (idx>>3)&63, b8 = idx&7;
    *(uint4*)&Hs[(h*64+p)*72 + b8*8] = *(const uint4*)(HP + ((c*4+h)*64+p)*64 + b8*8);
  }
  for (int idx=tid; idx<512; idx+=256){
    int h = idx>>7, t = idx&127;
    ex_s[h*128+t] = __expf(CUM[(c*CKL+t)*4+h]);
  }
  __syncthreads();
  int h = wid;
  const u16* Hh = &Hs[h*64*72];
  f32x4 acc[8][4] = {};
  for (int kt=0; kt<2; kt++){
    half8 af[8], bfv[4];
    #pragma unroll
    for (int mt=0;mt<8;mt++) af[mt] = *(const half8*)&Cs[(mt*16+lm)*72 + kt*32 + lq*8];
    #pragma unroll
    for (int nt=0;nt<4;nt++) bfv[nt] = *(const half8*)&Hh[(nt*16+lm)*72 + kt*32 + lq*8];
    #pragma unroll
    for (int mt=0;mt<8;mt++)
      #pragma unroll
      for (int nt=0;nt<4;nt++)
        acc[mt][nt] = __builtin_amdgcn_mfma_f32_16x16x32_f16(af[mt], bfv[nt], acc[mt][nt], 0,0,0);
  }
  #pragma unroll
  for (int mt=0;mt<8;mt++){
    #pragma unroll
    for (int r=0;r<4;r++){
      int t = mt*16 + lq*4 + r;
      float e = ex_s[h*128+t];
      u16* dst = &YB[((c*CKL+t)<<8) + (h<<6)];
      #pragma unroll
      for (int nt=0;nt<4;nt++){
        int p = nt*16 + lm;
        dst[p] = f2h(e*acc[mt][nt][r]);
      }
    }
  }
}

// ---------------- K7a: YH = fp16( rmsnorm((ya+yb)*silu(z)) * normw ) --------
__global__ __launch_bounds__(256) void k_ynorm(const u16* __restrict__ YA, const u16* __restrict__ YB,
                                               const u16* __restrict__ ZX, const float* __restrict__ nw,
                                               u16* __restrict__ YH){
  int t = blockIdx.x*4 + (threadIdx.x>>6);
  int lane = threadIdx.x&63;
  float a[4], b[4], z[4], u[4];
  up4(*(const uint2*)(YA + t*DIN + lane*4), a);
  up4(*(const uint2*)(YB + t*DIN + lane*4), b);
  up4(*(const uint2*)(ZX + t*NPROJ + lane*4), z);
  float4 w = *(const float4*)(nw + lane*4);
  float ss = 0.f;
  #pragma unroll
  for (int j=0;j<4;j++){ u[j] = (a[j]+b[j])*siluf_(z[j]); ss += u[j]*u[j]; }
  #pragma unroll
  for (int off=32; off; off>>=1) ss += __shfl_xor(ss, off, 64);
  float sc = rsqrtf(ss*(1.f/DIN)+1e-6f);
  float o[4] = { u[0]*sc*w.x, u[1]*sc*w.y, u[2]*sc*w.z, u[3]*sc*w.w };
  *(uint2*)(YH + t*DIN + lane*4) = pk4(o);
}

// ---------------- K7b: out GEMM + gate scatter (write run0, acc after) ------
__global__ __launch_bounds__(256) void k_gout_mfma(const u16* __restrict__ YH, const u16* __restrict__ WoT,
                                                   const float* __restrict__ G, float* __restrict__ GACC, int run){
  __shared__ u16 Ys[128*136];
  __shared__ u16 Ws[128*136];
  int t0 = blockIdx.x*128;
  int tid = threadIdx.x, lane = tid&63, wid = tid>>6;
  int lm = lane&15, lq = lane>>4;
  f32x4 acc[2][8] = {};
  for (int kb=0; kb<2; kb++){
    __syncthreads();
    for (int ch=tid; ch<2048; ch+=256){
      int row = ch>>4, c8 = ch&15;
      *(uint4*)&Ys[row*136 + c8*8] = *(const uint4*)(YH + (t0+row)*DIN + kb*128 + c8*8);
      *(uint4*)&Ws[row*136 + c8*8] = *(const uint4*)(WoT + row*DIN + kb*128 + c8*8);
    }
    __syncthreads();
    for (int kt=0; kt<4; kt++){
      half8 af[2], bfv[8];
      #pragma unroll
      for (int mt=0;mt<2;mt++) af[mt] = *(const half8*)&Ys[(wid*32+mt*16+lm)*136 + kt*32 + lq*8];
      #pragma unroll
      for (int nt=0;nt<8;nt++) bfv[nt] = *(const half8*)&Ws[(nt*16+lm)*136 + kt*32 + lq*8];
      #pragma unroll
      for (int mt=0;mt<2;mt++)
        #pragma unroll
        for (int nt=0;nt<8;nt++)
          acc[mt][nt] = __builtin_amdgcn_mfma_f32_16x16x32_f16(af[mt], bfv[nt], acc[mt][nt], 0,0,0);
    }
  }
  #pragma unroll
  for (int mt=0;mt<2;mt++){
    #pragma unroll
    for (int r=0;r<4;r++){
      int t = t0 + wid*32 + mt*16 + lq*4 + r;
      int sp = seq2sp(t, run);
      float g = G[run*LSEQ + sp];
      float* dst = &GACC[sp*CDIM];
      if (run==0){
        #pragma unroll
        for (int nt=0;nt<8;nt++) dst[nt*16+lm] = g*acc[mt][nt][r];
      } else {
        #pragma unroll
        for (int nt=0;nt<8;nt++) dst[nt*16+lm] += g*acc[mt][nt][r];
      }
    }
  }
}

// ---------------- K8: depthwise 3x3x3 conv, LDS-tiled -----------------------
__global__ __launch_bounds__(256) void k_dwconv(const float* __restrict__ XN, const float* __restrict__ w,
                                                const float* __restrict__ b, float* __restrict__ LC1){
  __shared__ float sm[3*34*40];
  int cc = blockIdx.x>>5, d = blockIdx.x&31;
  int tid = threadIdx.x;
  for (int i=tid; i<4080; i+=256) sm[i] = 0.f;
  __syncthreads();
  #pragma unroll
  for (int p=0;p<3;p++){
    int dz = d-1+p;
    if ((unsigned)dz<=31u){
      for (int idx=tid; idx<1024; idx+=256){
        int hh = idx>>5, ww = idx&31;
        sm[p*1360 + (hh+1)*40 + (ww+4)] = XN[cc*LSEQ + (dz<<10) + idx];
      }
    }
  }
  __syncthreads();
  float wreg[27];
  #pragma unroll
  for (int i=0;i<27;i++) wreg[i] = w[cc*27+i];
  float bias = b[cc];
  int h = tid>>3, w0 = (tid&7)*4;
  float4 acc = {bias,bias,bias,bias};
  #pragma unroll
  for (int p=0;p<3;p++){
    #pragma unroll
    for (int dy=0;dy<3;dy++){
      const float* row = &sm[p*1360 + (h+dy)*40 + 4];
      float left  = row[w0-1];
      float4 mid  = *(const float4*)&row[w0];
      float right = row[w0+4];
      float wa=wreg[p*9+dy*3+0], wb=wreg[p*9+dy*3+1], wc=wreg[p*9+dy*3+2];
      acc.x += wa*left  + wb*mid.x + wc*mid.y;
      acc.y += wa*mid.x + wb*mid.y + wc*mid.z;
      acc.z += wa*mid.y + wb*mid.z + wc*mid.w;
      acc.w += wa*mid.z + wb*mid.w + wc*right;
    }
  }
  *(float4*)&LC1[cc*LSEQ + (d<<10) + h*32 + w0] = acc;
}

// ---------------- K9: pointwise 128x128 + silu (fp16 MFMA) ------------------
__global__ __launch_bounds__(256) void k_pw(const float* __restrict__ LC1, const float* __restrict__ pw,
                                            const float* __restrict__ pwb, float* __restrict__ LC2){
  __shared__ u16 Ws[128*136];
  __shared__ u16 Bs[128*136];
  int s0 = blockIdx.x*128;
  int tid = threadIdx.x, lane = tid&63, wid = tid>>6;
  int lm = lane&15, lq = lane>>4;
  for (int idx=tid; idx<16384; idx+=256){
    int o = idx>>7, cc = idx&127;
    Ws[o*136+cc] = f2h(pw[idx]);
  }
  for (int idx=tid; idx<16384; idx+=256){
    int cc = idx>>7, n = idx&127;
    Bs[n*136+cc] = f2h(LC1[cc*LSEQ + s0 + n]);
  }
  __syncthreads();
  f32x4 acc[2][8] = {};
  for (int kt=0; kt<4; kt++){
    half8 af[2], bfv[8];
    #pragma unroll
    for (int mt=0;mt<2;mt++) af[mt] = *(const half8*)&Ws[(wid*32+mt*16+lm)*136 + kt*32 + lq*8];
    #pragma unroll
    for (int nt=0;nt<8;nt++) bfv[nt] = *(const half8*)&Bs[(nt*16+lm)*136 + kt*32 + lq*8];
    #pragma unroll
    for (int mt=0;mt<2;mt++)
      #pragma unroll
      for (int nt=0;nt<8;nt++)
        acc[mt][nt] = __builtin_amdgcn_mfma_f32_16x16x32_f16(af[mt], bfv[nt], acc[mt][nt], 0,0,0);
  }
  #pragma unroll
  for (int mt=0;mt<2;mt++){
    #pragma unroll
    for (int r=0;r<4;r++){
      int o = wid*32 + mt*16 + lq*4 + r;
      float bb = pwb[o];
      float* dst = &LC2[o*LSEQ + s0];
      #pragma unroll
      for (int nt=0;nt<8;nt++){
        int n = nt*16 + lm;
        dst[n] = siluf_(acc[mt][nt][r] + bb);
      }
    }
  }
}

// ---------------- K10: fused = a*g + (1-a)*lc, transpose --------------------
__global__ void k_fuse(const float* __restrict__ GACC, const float* __restrict__ LC2,
                       const float* __restrict__ alpha, float* __restrict__ FUSED){
  __shared__ float tile[64*65];
  int bs = blockIdx.x>>1, bc = blockIdx.x&1;
  int s0 = bs*64, c0 = bc*64;
  int tid = threadIdx.x;
  float a = alpha[0];
  for (int idx=tid; idx<4096; idx+=256){
    int i = idx>>6, j = idx&63;
    tile[i*65+j] = GACC[(s0+i)*CDIM + c0+j];
  }
  __syncthreads();
  for (int idx=tid; idx<4096; idx+=256){
    int j = idx>>6, i = idx&63;
    float g = tile[i*65+j];
    float l = LC2[(c0+j)*LSEQ + s0+i];
    FUSED[(c0+j)*LSEQ + s0+i] = a*g + (1.f-a)*l;
  }
}

// ---------------- K_mean ----------------------------------------------------
__global__ void k_mean(const float* __restrict__ F, float* __restrict__ MEAN){
  __shared__ float red[4];
  int cc = blockIdx.x, tid = threadIdx.x;
  float acc = 0.f;
  for (int s=tid; s<LSEQ; s+=256) acc += F[cc*LSEQ + s];
  #pragma unroll
  for (int off=32; off; off>>=1) acc += __shfl_down(acc, off, 64);
  if ((tid&63)==0) red[tid>>6] = acc;
  __syncthreads();
  if (tid==0) MEAN[cc] = (red[0]+red[1]+red[2]+red[3])*(1.f/LSEQ);
}

// ---------------- K11: channel attention ------------------------------------
__global__ void k_ca(const float* __restrict__ MEAN, const float* __restrict__ w1, const float* __restrict__ b1,
                     const float* __restrict__ w2, const float* __restrict__ b2, float* __restrict__ SIG){
  __shared__ float y1[8];
  int tid = threadIdx.x;
  if (tid<8){
    float acc = b1[tid];
    for (int c=0;c<128;c++) acc += w1[tid*128+c]*MEAN[c];
    y1[tid] = (acc>=0.f)? acc : 0.1f*acc;
  }
  __syncthreads();
  float acc = b2[tid];
  #pragma unroll
  for (int o=0;o<8;o++) acc += w2[tid*8+o]*y1[o];
  SIG[tid] = sigmoidf_(acc);
}

// ---------------- K12: out = x + fused * sigmoid(yc) ------------------------
__global__ void k_final(const float* __restrict__ x, const float* __restrict__ F, const float* __restrict__ SIG,
                        float* __restrict__ out){
  int idx = blockIdx.x*256 + threadIdx.x;
  int cc = idx>>15;
  out[idx] = x[idx] + F[idx]*SIG[cc];
}

extern "C" void kernel_launch(void* const* d_in, const int* in_sizes, int n_in,
                              void* d_out, int out_size, void* d_ws, size_t ws_size,
                              hipStream_t stream){
  (void)in_sizes; (void)n_in; (void)out_size; (void)ws_size;
  const float* x       = (const float*)d_in[0];
  const float* norm_w  = (const float*)d_in[1];
  const float* gate_w  = (const float*)d_in[2];
  const float* gate_b  = (const float*)d_in[3];
  const float* loc_dw_w= (const float*)d_in[28];
  const float* loc_dw_b= (const float*)d_in[29];
  const float* loc_pw_w= (const float*)d_in[30];
  const float* loc_pw_b= (const float*)d_in[31];
  const float* ca_w1   = (const float*)d_in[32];
  const float* ca_b1   = (const float*)d_in[33];
  const float* ca_w2   = (const float*)d_in[34];
  const float* ca_b2   = (const float*)d_in[35];
  const float* alpha   = (const float*)d_in[36];

  float* W     = (float*)d_ws;
  float* XN    = W;                         // 4,194,304
  float* GATES = XN    + 4194304;           //   196,608
  float* GACC  = GATES + 196608;            // 4,194,304
  u16*   ZX    = (u16*)(GACC + 4194304);    // 21,102,592 u16
  u16*   XB    = (u16*)(GACC + 4194304 + 10551296);   // 12,582,912 u16
  float* DT    = GACC + 4194304 + 10551296 + 6291456; // 131,072
  float* CUM   = DT    + 131072;            //   131,072
  float* CDEC  = CUM   + 131072;            //     1,024
  float* STreg = CDEC  + 1024;              // 4,194,304 fl region (ST16 / YH alias)
  float* Y     = STreg + 4194304;           // 8,388,608 fl = YA/YB fp16
  float* LC1   = Y     + 8388608;           // 4,194,304 (HPREV16 alias)
  float* LC2   = LC1   + 4194304;           // 4,194,304
  float* MEAN  = LC2   + 4194304;           //       128
  float* SIG   = MEAN  + 128;               //       128
  u16*   XNT   = (u16*)(SIG + 128);         // 4,194,304 u16
  u16*   WinT  = XNT + 4194304;             //    98,304 u16
  u16*   WoT   = WinT + 98304;              //    32,768 u16
  u16*   ST16  = (u16*)STreg;               // 4,194,304 u16
  u16*   YH    = (u16*)STreg;               // alias (ST dead after k_inter)
  u16*   YA    = (u16*)Y;                   // 8,388,608 u16
  u16*   YB    = YA + 8388608;              // 8,388,608 u16
  u16*   HP16  = (u16*)LC1;                 // 4,194,304 u16

  k_xn   <<<128,256,0,stream>>>(x, norm_w, XN);
  k_gates<<<128,256,0,stream>>>(XN, gate_w, gate_b, GATES);

  for (int r=0;r<6;r++){
    int m = r>>1;
    const float* Win   = (const float*)d_in[4 + m*8 + 0];
    const float* convw = (const float*)d_in[4 + m*8 + 1];
    const float* convb = (const float*)d_in[4 + m*8 + 2];
    const float* dtb   = (const float*)d_in[4 + m*8 + 3];
    const float* Alog  = (const float*)d_in[4 + m*8 + 4];
    const float* Dp    = (const float*)d_in[4 + m*8 + 5];
    const float* nw2   = (const float*)d_in[4 + m*8 + 6];
    const float* Wout  = (const float*)d_in[4 + m*8 + 7];
    if ((r&1)==0){
      k_permute<<<1024,256,0,stream>>>(XN, XNT, m);
      k_prepw  <<<384,256,0,stream>>>(Win, WinT);
      k_prewo  <<<128,256,0,stream>>>(Wout, WoT);
    }
    k_gin_mfma<<<dim3(6,256),256,0,stream>>>(XNT, WinT, ZX, r&1);
    k_conv    <<<1024,384,0,stream>>>(ZX, convw, convb, XB);
    k_dtcum   <<<256,256,0,stream>>>(ZX, dtb, Alog, DT, CUM, CDEC);
    k_chunk   <<<1024,256,0,stream>>>(XB, DT, CUM, Dp, YA, ST16);
    k_scan    <<<64,256,0,stream>>>(ST16, HP16, CDEC);
    k_inter   <<<256,256,0,stream>>>(XB, CUM, HP16, YB);
    k_ynorm   <<<8192,256,0,stream>>>(YA, YB, ZX, nw2, YH);
    k_gout_mfma<<<256,256,0,stream>>>(YH, WoT, GATES, GACC, r);
  }

  k_dwconv<<<4096,256,0,stream>>>(XN, loc_dw_w, loc_dw_b, LC1);
  k_pw    <<<256,256,0,stream>>>(LC1, loc_pw_w, loc_pw_b, LC2);
  k_fuse  <<<1024,256,0,stream>>>(GACC, LC2, alpha, LC1);
  k_mean  <<<128,256,0,stream>>>(LC1, MEAN);
  k_ca    <<<1,128,0,stream>>>(MEAN, ca_w1, ca_b1, ca_w2, ca_b2, SIG);
  k_final <<<16384,256,0,stream>>>(x, LC1, SIG, (float*)d_out);
}